// Round 1
// baseline (1496.579 us; speedup 1.0000x reference)
//
#include <hip/hip_runtime.h>
#include <math.h>

#define B_    32
#define KOBJ  100
#define NS_   16
#define NK_   8
#define EMB_  1024
#define FEAT_ 2052
#define HID_  1024
#define OUT_  3000
#define COMB_ 512

// ---------------- bb centres ----------------
__global__ void centres_kernel(const float* __restrict__ image, float* __restrict__ cent) {
  int i = blockIdx.x * blockDim.x + threadIdx.x;
  if (i >= B_ * KOBJ) return;
  const float* bb = image + (size_t)i * FEAT_ + (FEAT_ - 4);
  cent[i * 2 + 0] = 0.5f * (bb[0] + bb[2]);
  cent[i * 2 + 1] = 0.5f * (bb[1] + bb[3]);
}

// ---------------- generic tiled f32 GEMM ----------------
// C[M,N] = op(A[M,K] @ B[K,N] + bias)
// CAT:   A = [A (M x K1) | A2 (rows/KOBJ x (K-K1))] concat along K
// CONVB: B element (k,n) = Bm[((n/OPM)*K + k)*OPM + (n%OPM)]  (conv_w native layout)
template <bool RELU, bool BIAS, bool CONVB, bool CAT>
__global__ __launch_bounds__(256) void gemm_f32(
    const float* __restrict__ A, const float* __restrict__ A2,
    const float* __restrict__ Bm, const float* __restrict__ bias,
    float* __restrict__ C, int M, int N, int K, int K1, int OPM) {
  __shared__ float As[16][64];
  __shared__ float Bs[16][68];
  int tid = threadIdx.x;
  int m0 = blockIdx.y * 64, n0 = blockIdx.x * 64;
  int ar = tid >> 2, ak = (tid & 3) << 2;
  int br = tid >> 4, bn = (tid & 15) << 2;
  int tm = (tid >> 4) << 2, tn = (tid & 15) << 2;
  float acc[4][4] = {};
  for (int k0 = 0; k0 < K; k0 += 16) {
    // ---- stage A tile (As[k][m]) ----
    {
      int row = m0 + ar, kg = k0 + ak;
      float4 v = make_float4(0.f, 0.f, 0.f, 0.f);
      if (row < M) {
        if (CAT) {
          if (kg + 3 < K) {
            if (kg >= K1) v = *(const float4*)(A2 + (size_t)(row / KOBJ) * (K - K1) + (kg - K1));
            else          v = *(const float4*)(A + (size_t)row * K1 + kg);
          } else {
            float t[4];
            for (int i = 0; i < 4; ++i) {
              int kk = kg + i;
              t[i] = (kk < K) ? (kk >= K1 ? A2[(size_t)(row / KOBJ) * (K - K1) + kk - K1]
                                          : A[(size_t)row * K1 + kk])
                              : 0.f;
            }
            v = make_float4(t[0], t[1], t[2], t[3]);
          }
        } else {
          if (kg + 3 < K) {
            v = *(const float4*)(A + (size_t)row * K + kg);
          } else {
            float t[4];
            for (int i = 0; i < 4; ++i) {
              int kk = kg + i;
              t[i] = (kk < K) ? A[(size_t)row * K + kk] : 0.f;
            }
            v = make_float4(t[0], t[1], t[2], t[3]);
          }
        }
      }
      As[ak + 0][ar] = v.x; As[ak + 1][ar] = v.y;
      As[ak + 2][ar] = v.z; As[ak + 3][ar] = v.w;
    }
    // ---- stage B tile (Bs[k][n]) ----
    {
      int kg = k0 + br, ng = n0 + bn;
      float4 v = make_float4(0.f, 0.f, 0.f, 0.f);
      if (kg < K) {
        if (CONVB) {
          if (ng + 3 < N) {
            int mB = ng / OPM, o = ng % OPM;
            v = *(const float4*)(Bm + ((size_t)mB * K + kg) * OPM + o);
          } else {
            float t[4];
            for (int i = 0; i < 4; ++i) {
              int nn = ng + i;
              t[i] = (nn < N) ? Bm[((size_t)(nn / OPM) * K + kg) * OPM + (nn % OPM)] : 0.f;
            }
            v = make_float4(t[0], t[1], t[2], t[3]);
          }
        } else {
          if (ng + 3 < N) {
            v = *(const float4*)(Bm + (size_t)kg * N + ng);
          } else {
            float t[4];
            for (int i = 0; i < 4; ++i) {
              int nn = ng + i;
              t[i] = (nn < N) ? Bm[(size_t)kg * N + nn] : 0.f;
            }
            v = make_float4(t[0], t[1], t[2], t[3]);
          }
        }
      }
      Bs[br][bn + 0] = v.x; Bs[br][bn + 1] = v.y;
      Bs[br][bn + 2] = v.z; Bs[br][bn + 3] = v.w;
    }
    __syncthreads();
#pragma unroll
    for (int kk = 0; kk < 16; ++kk) {
      float4 a4 = *(const float4*)&As[kk][tm];
      float4 b4 = *(const float4*)&Bs[kk][tn];
      float a[4] = {a4.x, a4.y, a4.z, a4.w};
      float b[4] = {b4.x, b4.y, b4.z, b4.w};
#pragma unroll
      for (int i = 0; i < 4; ++i)
#pragma unroll
        for (int j = 0; j < 4; ++j) acc[i][j] = fmaf(a[i], b[j], acc[i][j]);
    }
    __syncthreads();
  }
#pragma unroll
  for (int i = 0; i < 4; ++i) {
    int mg = m0 + tm + i;
    if (mg >= M) continue;
#pragma unroll
    for (int j = 0; j < 4; ++j) {
      int ng = n0 + tn + j;
      if (ng >= N) continue;
      float v = acc[i][j];
      if (BIAS) v += bias[ng];
      if (RELU) v = fmaxf(v, 0.f);
      C[(size_t)mg * N + ng] = v;
    }
  }
}

// ---------------- adj = h2 @ h2^T per batch ----------------
__global__ __launch_bounds__(256) void adj_kernel(const float* __restrict__ h2,
                                                  float* __restrict__ adj) {
  __shared__ float Rk[16][COMB_ + 1];
  __shared__ float Rl[16][COMB_ + 1];
  int b = blockIdx.z, k0 = blockIdx.y * 16, l0 = blockIdx.x * 16;
  int tid = threadIdx.y * 16 + threadIdx.x;
  for (int e = tid; e < 16 * COMB_; e += 256) {
    int r = e >> 9, f = e & (COMB_ - 1);
    Rk[r][f] = (k0 + r < KOBJ) ? h2[((size_t)b * KOBJ + k0 + r) * COMB_ + f] : 0.f;
    Rl[r][f] = (l0 + r < KOBJ) ? h2[((size_t)b * KOBJ + l0 + r) * COMB_ + f] : 0.f;
  }
  __syncthreads();
  int i = threadIdx.y, j = threadIdx.x;
  float acc = 0.f;
  for (int f = 0; f < COMB_; ++f) acc = fmaf(Rk[i][f], Rl[j][f], acc);
  int kg = k0 + i, lg = l0 + j;
  if (kg < KOBJ && lg < KOBJ) adj[((size_t)b * KOBJ + kg) * KOBJ + lg] = acc;
}

// ---------------- top-k + softmax + gaussian kernel weights ----------------
__global__ __launch_bounds__(256) void topk_weights_kernel(
    const float* __restrict__ adj, const float* __restrict__ cent,
    const float* __restrict__ mr1, const float* __restrict__ mt1,
    const float* __restrict__ pr1, const float* __restrict__ pt1,
    const float* __restrict__ mr2, const float* __restrict__ mt2,
    const float* __restrict__ pr2, const float* __restrict__ pt2,
    int* __restrict__ topi, float* __restrict__ c1, float* __restrict__ c2) {
  int row = blockIdx.x * 4 + (threadIdx.x >> 6);  // one wave per row, 4 waves/block
  int lane = threadIdx.x & 63;
  int b = row / KOBJ, k = row % KOBJ;
  const float* ar = adj + (size_t)row * KOBJ;
  float v0 = (lane < KOBJ) ? ar[lane] : -INFINITY;
  float v1 = (lane + 64 < KOBJ) ? ar[lane + 64] : -INFINITY;
  int i0 = lane, i1 = lane + 64;
  float tv[NS_];
  int ti[NS_];
#pragma unroll
  for (int s = 0; s < NS_; ++s) {
    bool p0 = (v0 > v1) || (v0 == v1 && i0 < i1);  // jax tie-break: smaller index
    float bv = p0 ? v0 : v1;
    int bi = p0 ? i0 : i1;
#pragma unroll
    for (int off = 32; off > 0; off >>= 1) {
      float ov = __shfl_xor(bv, off);
      int oi = __shfl_xor(bi, off);
      if (ov > bv || (ov == bv && oi < bi)) { bv = ov; bi = oi; }
    }
    tv[s] = bv; ti[s] = bi;
    if (bi == i0) v0 = -INFINITY;
    if (bi == i1) v1 = -INFINITY;
  }
  float mx = tv[0], sum = 0.f, av[NS_];
#pragma unroll
  for (int s = 0; s < NS_; ++s) { av[s] = expf(tv[s] - mx); sum += av[s]; }
  if (lane < NS_) {
    int j = ti[lane];
    topi[(size_t)row * NS_ + lane] = j;
    float cx = cent[(b * KOBJ + k) * 2 + 0], cy = cent[(b * KOBJ + k) * 2 + 1];
    float dx = cx - cent[(b * KOBJ + j) * 2 + 0];
    float dy = cy - cent[(b * KOBJ + j) * 2 + 1];
    float rho = sqrtf(dx * dx + dy * dy);
    float th = atan2f(dx, dy);  // reference: arctan2(d[...,0], d[...,1])
    float w1[NK_], w2[NK_], s1 = 0.f, s2 = 0.f;
#pragma unroll
    for (int m = 0; m < NK_; ++m) {
      {
        float pr = pr1[m], pt = pt1[m], dr = rho - mr1[m];
        float wr = expf(-0.5f * dr * dr / (1e-14f + pr * pr));
        float fa = fabsf(th - mt1[m]);
        float sa = fabsf(6.283185307179586f - fa);
        float da = fminf(fa, sa);
        float wt = expf(-0.5f * da * da / (1e-14f + pt * pt));
        float w = wr * wt;
        if (w != w) w = 0.f;
        w1[m] = w; s1 += w;
      }
      {
        float pr = pr2[m], pt = pt2[m], dr = rho - mr2[m];
        float wr = expf(-0.5f * dr * dr / (1e-14f + pr * pr));
        float fa = fabsf(th - mt2[m]);
        float sa = fabsf(6.283185307179586f - fa);
        float da = fminf(fa, sa);
        float wt = expf(-0.5f * da * da / (1e-14f + pt * pt));
        float w = wr * wt;
        if (w != w) w = 0.f;
        w2[m] = w; s2 += w;
      }
    }
    float as = av[lane] / sum;
#pragma unroll
    for (int m = 0; m < NK_; ++m) {
      c1[((size_t)row * NS_ + lane) * NK_ + m] = as * (w1[m] / s1);
      c2[((size_t)row * NS_ + lane) * NK_ + m] = w2[m] / s2;
    }
  }
}

// ---------------- gather-combine: out[row,n] = relu(sum_s c[row,s,m(n)] * proj[b, idx[row,s], n]) ----
__global__ __launch_bounds__(256) void combine_kernel(
    const float* __restrict__ proj, const float* __restrict__ coeff,
    const int* __restrict__ topi, float* __restrict__ out, int N, int mshift) {
  int row = blockIdx.y;
  int b = row / KOBJ;
  __shared__ int ids[NS_];
  __shared__ float cs[NS_ * NK_];
  int tid = threadIdx.x;
  if (tid < NS_) ids[tid] = topi[(size_t)row * NS_ + tid];
  else if (tid >= 32 && tid < 32 + NS_ * NK_) cs[tid - 32] = coeff[(size_t)row * NS_ * NK_ + (tid - 32)];
  __syncthreads();
  int n = blockIdx.x * 256 + tid;
  if (n >= N) return;
  int m = n >> mshift;
  float acc = 0.f;
#pragma unroll
  for (int s = 0; s < NS_; ++s)
    acc = fmaf(cs[s * NK_ + m], proj[((size_t)b * KOBJ + ids[s]) * N + n], acc);
  out[(size_t)row * N + n] = fmaxf(acc, 0.f);
}

// ---------------- max over k, then hh = relu(qenc) * g2max ----------------
__global__ void reduce_hh_kernel(const float* __restrict__ g2, const float* __restrict__ qenc,
                                 float* __restrict__ hh) {
  int i = blockIdx.x * blockDim.x + threadIdx.x;
  if (i >= B_ * HID_) return;
  int b = i >> 10, n = i & (HID_ - 1);
  const float* p = g2 + (size_t)b * KOBJ * HID_ + n;
  float mx = -INFINITY;
  for (int k = 0; k < KOBJ; ++k) mx = fmaxf(mx, p[(size_t)k * HID_]);
  hh[i] = fmaxf(qenc[i], 0.f) * mx;
}

extern "C" void kernel_launch(void* const* d_in, const int* in_sizes, int n_in,
                              void* d_out, int out_size, void* d_ws, size_t ws_size,
                              hipStream_t stream) {
  const float* question = (const float*)d_in[0];
  const float* image    = (const float*)d_in[1];
  const float* W_lproj  = (const float*)d_in[3];
  const float* b_lproj  = (const float*)d_in[4];
  const float* W_e1     = (const float*)d_in[5];
  const float* b_e1     = (const float*)d_in[6];
  const float* W_e2     = (const float*)d_in[7];
  const float* b_e2     = (const float*)d_in[8];
  const float* conv_w1  = (const float*)d_in[9];
  const float* mr1 = (const float*)d_in[10];
  const float* mt1 = (const float*)d_in[11];
  const float* pr1 = (const float*)d_in[12];
  const float* pt1 = (const float*)d_in[13];
  const float* conv_w2  = (const float*)d_in[14];
  const float* mr2 = (const float*)d_in[15];
  const float* mt2 = (const float*)d_in[16];
  const float* pr2 = (const float*)d_in[17];
  const float* pt2 = (const float*)d_in[18];
  const float* W_o1 = (const float*)d_in[19];
  const float* b_o1 = (const float*)d_in[20];
  const float* W_o2 = (const float*)d_in[21];
  const float* b_o2 = (const float*)d_in[22];

  float* out = (float*)d_out;
  float* logits = out;               // [32,3000]
  float* adj = out + B_ * OUT_;      // [32,100,100]

  float* ws = (float*)d_ws;
  size_t off = 0;
  auto alloc = [&](size_t n) { float* p = ws + off; off += (n + 63) & ~((size_t)63); return p; };
  float* qenc  = alloc((size_t)B_ * HID_);
  float* h1    = alloc((size_t)B_ * KOBJ * COMB_);
  float* h2    = alloc((size_t)B_ * KOBJ * COMB_);
  float* cent  = alloc((size_t)B_ * KOBJ * 2);
  int*   topi  = (int*)alloc((size_t)B_ * KOBJ * NS_);
  float* c1    = alloc((size_t)B_ * KOBJ * NS_ * NK_);
  float* c2    = alloc((size_t)B_ * KOBJ * NS_ * NK_);
  float* proj1 = alloc((size_t)B_ * KOBJ * 2 * HID_);
  float* g1    = alloc((size_t)B_ * KOBJ * 2 * HID_);
  float* proj2 = alloc((size_t)B_ * KOBJ * HID_);
  float* g2    = alloc((size_t)B_ * KOBJ * HID_);
  float* hh    = alloc((size_t)B_ * HID_);
  float* h1o   = alloc((size_t)B_ * OUT_);
  (void)ws_size; (void)in_sizes; (void)n_in; (void)out_size;

  dim3 blk(256);
  auto ggrid = [](int M, int N) { return dim3((N + 63) / 64, (M + 63) / 64); };

  // 1. centres
  centres_kernel<<<dim3((B_ * KOBJ + 255) / 256), blk, 0, stream>>>(image, cent);
  // 2. qenc = question @ W_lproj + b_lproj (no relu; raw kept for later)
  gemm_f32<false, true, false, false><<<ggrid(B_, HID_), blk, 0, stream>>>(
      question, nullptr, W_lproj, b_lproj, qenc, B_, HID_, EMB_, 0, 0);
  // 3. h1 = relu([image|qenc] @ W_e1 + b_e1)
  gemm_f32<true, true, false, true><<<ggrid(B_ * KOBJ, COMB_), blk, 0, stream>>>(
      image, qenc, W_e1, b_e1, h1, B_ * KOBJ, COMB_, FEAT_ + HID_, FEAT_, 0);
  // 4. h2 = relu(h1 @ W_e2 + b_e2)
  gemm_f32<true, true, false, false><<<ggrid(B_ * KOBJ, COMB_), blk, 0, stream>>>(
      h1, nullptr, W_e2, b_e2, h2, B_ * KOBJ, COMB_, COMB_, 0, 0);
  // 5. adj = h2 @ h2^T per batch -> straight into d_out
  adj_kernel<<<dim3(7, 7, B_), dim3(16, 16), 0, stream>>>(h2, adj);
  // 6. top-16 + softmax + gaussian weights for both layers
  topk_weights_kernel<<<dim3(B_ * KOBJ / 4), blk, 0, stream>>>(
      adj, cent, mr1, mt1, pr1, pt1, mr2, mt2, pr2, pt2, topi, c1, c2);
  // 7. proj1 = image @ conv_w1 (native conv layout)
  gemm_f32<false, false, true, false><<<ggrid(B_ * KOBJ, 2 * HID_), blk, 0, stream>>>(
      image, nullptr, conv_w1, nullptr, proj1, B_ * KOBJ, 2 * HID_, FEAT_, 0, 2 * HID_ / NK_);
  // 8. g1 = relu(gather-combine(proj1))
  combine_kernel<<<dim3(2 * HID_ / 256, B_ * KOBJ), blk, 0, stream>>>(
      proj1, c1, topi, g1, 2 * HID_, 8);
  // 9. proj2 = g1 @ conv_w2
  gemm_f32<false, false, true, false><<<ggrid(B_ * KOBJ, HID_), blk, 0, stream>>>(
      g1, nullptr, conv_w2, nullptr, proj2, B_ * KOBJ, HID_, 2 * HID_, 0, HID_ / NK_);
  // 10. g2 = relu(gather-combine(proj2))
  combine_kernel<<<dim3(HID_ / 256, B_ * KOBJ), blk, 0, stream>>>(
      proj2, c2, topi, g2, HID_, 7);
  // 11. g2max over k; hh = relu(qenc) * g2max
  reduce_hh_kernel<<<dim3((B_ * HID_ + 255) / 256), blk, 0, stream>>>(g2, qenc, hh);
  // 12. h1o = relu(hh @ W_o1 + b_o1)
  gemm_f32<true, true, false, false><<<ggrid(B_, OUT_), blk, 0, stream>>>(
      hh, nullptr, W_o1, b_o1, h1o, B_, OUT_, HID_, 0, 0);
  // 13. logits = h1o @ W_o2 + b_o2 -> d_out
  gemm_f32<false, true, false, false><<<ggrid(B_, OUT_), blk, 0, stream>>>(
      h1o, nullptr, W_o2, b_o2, logits, B_, OUT_, OUT_, 0, 0);
}

// Round 2
// 956.306 us; speedup vs baseline: 1.5650x; 1.5650x over previous
//
#include <hip/hip_runtime.h>
#include <math.h>
#include <stdint.h>

#define B_    32
#define KOBJ  100
#define NS_   16
#define NK_   8
#define EMB_  1024
#define FEAT_ 2052
#define HID_  1024
#define OUT_  3000
#define COMB_ 512

#define KP1   2112   // FEAT_ padded to 64 for proj1
#define KP2   2048   // 2*HID_, already multiple of 64

typedef __attribute__((ext_vector_type(8))) short s16x8;
typedef __attribute__((ext_vector_type(4))) float f32x4;

__device__ inline short f2bf(float f) {
  uint32_t u = __builtin_bit_cast(uint32_t, f);
  u = (u + 0x7fff + ((u >> 16) & 1)) >> 16;  // RNE
  return (short)u;
}

__device__ inline void gload_lds16(const void* g, void* l) {
  __builtin_amdgcn_global_load_lds(
      (const __attribute__((address_space(1))) void*)g,
      (__attribute__((address_space(3))) void*)l, 16, 0, 0);
}

// ---------------- bb centres ----------------
__global__ void centres_kernel(const float* __restrict__ image, float* __restrict__ cent) {
  int i = blockIdx.x * blockDim.x + threadIdx.x;
  if (i >= B_ * KOBJ) return;
  const float* bb = image + (size_t)i * FEAT_ + (FEAT_ - 4);
  cent[i * 2 + 0] = 0.5f * (bb[0] + bb[2]);
  cent[i * 2 + 1] = 0.5f * (bb[1] + bb[3]);
}

// ---------------- f32 -> bf16 row-major convert with K padding ----------------
__global__ void cvt_pad_rows(const float* __restrict__ in, short* __restrict__ out,
                             int K, int Kp, int total) {
  int idx = blockIdx.x * 256 + threadIdx.x;
  if (idx >= total) return;
  int row = idx / (Kp / 8), c8 = (idx % (Kp / 8)) * 8;
  s16x8 v;
#pragma unroll
  for (int i = 0; i < 8; ++i) {
    int k = c8 + i;
    v[i] = (k < K) ? f2bf(in[(size_t)row * K + k]) : (short)0;
  }
  *(s16x8*)(out + (size_t)row * Kp + c8) = v;
}

// ---------------- transpose-convert weights to Bt[n][kp] bf16 ----------------
// CONV: in element (k,n) = in[((n/OPM)*K + k)*OPM + (n%OPM)]; else in[k*N + n]
template <bool CONV>
__global__ __launch_bounds__(256) void transpose_bf16(
    const float* __restrict__ in, short* __restrict__ out,
    int K, int N, int Kp, int OPM) {
  __shared__ float s[64][65];
  int k0 = blockIdx.x * 64, n0 = blockIdx.y * 64;
  int t = threadIdx.x;
  int r = t >> 2, cb = (t & 3) << 4;
  int kg = k0 + r;
#pragma unroll
  for (int i = 0; i < 16; ++i) {
    int n = n0 + cb + i;
    float v = 0.f;
    if (kg < K) v = CONV ? in[((size_t)(n / OPM) * K + kg) * OPM + (n % OPM)]
                         : in[(size_t)kg * N + n];
    s[r][cb + i] = v;
  }
  __syncthreads();
  int nl = t >> 2, kc = (t & 3) << 4;
  s16x8 a, b;
#pragma unroll
  for (int i = 0; i < 8; ++i) a[i] = f2bf(s[kc + i][nl]);
#pragma unroll
  for (int i = 0; i < 8; ++i) b[i] = f2bf(s[kc + 8 + i][nl]);
  short* o = out + (size_t)(n0 + nl) * Kp + k0 + kc;
  *(s16x8*)o = a;
  *(s16x8*)(o + 8) = b;
}

// ---------------- bf16 MFMA GEMM: C[M][N] = A[M][Kp] @ Bt[N][Kp]^T ----------------
// 256 threads = 4 waves in 2x2; wave tile (BM/2)x(BN/2); 16x16x32 bf16 MFMA.
// LDS: As/Bs rows of 128B (BK=64), XOR-swizzled (byte ^= (row&7)<<4) with
// pre-swizzled global source + linear global_load_lds dest (rule #21).
template <int BM, int BN, bool RELU, bool BIAS>
__global__ __launch_bounds__(256) void gemm_mfma(
    const short* __restrict__ A, const short* __restrict__ Bt,
    const float* __restrict__ bias, float* __restrict__ C,
    int M, int N, int Kp) {
  constexpr int FM = BM / 32, FN = BN / 32;
  constexpr int ACH = BM / 8;  // 1KB chunks in A tile
  constexpr int BCH = BN / 8;
  __shared__ short As[BM * 64];
  __shared__ short Bs[BN * 64];
  int tid = threadIdx.x;
  int wave = tid >> 6, lane = tid & 63;
  int wr = wave >> 1, wc = wave & 1;
  int r16 = lane & 15, kg = lane >> 4;
  int m0 = blockIdx.y * BM, n0 = blockIdx.x * BN;
  f32x4 acc[FM][FN] = {};

  for (int k0 = 0; k0 < Kp; k0 += 64) {
    __syncthreads();
    for (int c = wave; c < ACH + BCH; c += 4) {
      bool isA = c < ACH;
      int cc = isA ? c : c - ACH;
      int Lb = cc * 1024 + lane * 16;
      int row = Lb >> 7, within = Lb & 127;
      int off = within ^ ((row & 7) << 4);
      const short* gsrc = (isA ? A + (size_t)(m0 + row) * Kp
                               : Bt + (size_t)(n0 + row) * Kp) + k0 + (off >> 1);
      char* ldst = (char*)(isA ? (void*)As : (void*)Bs) + cc * 1024;
      gload_lds16(gsrc, ldst);
    }
    __syncthreads();  // compiler drains vmcnt before barrier
#pragma unroll
    for (int kk = 0; kk < 2; ++kk) {
      int woff = kk * 64 + kg * 16;
      s16x8 af[FM], bfr[FN];
#pragma unroll
      for (int f = 0; f < FM; ++f) {
        int row = wr * (BM / 2) + f * 16 + r16;
        af[f] = *(const s16x8*)((const char*)As + row * 128 + (woff ^ ((row & 7) << 4)));
      }
#pragma unroll
      for (int g = 0; g < FN; ++g) {
        int row = wc * (BN / 2) + g * 16 + r16;
        bfr[g] = *(const s16x8*)((const char*)Bs + row * 128 + (woff ^ ((row & 7) << 4)));
      }
#pragma unroll
      for (int f = 0; f < FM; ++f)
#pragma unroll
        for (int g = 0; g < FN; ++g)
          acc[f][g] = __builtin_amdgcn_mfma_f32_16x16x32_bf16(af[f], bfr[g], acc[f][g], 0, 0, 0);
    }
  }
#pragma unroll
  for (int f = 0; f < FM; ++f)
#pragma unroll
    for (int g = 0; g < FN; ++g)
#pragma unroll
      for (int r = 0; r < 4; ++r) {
        int m = m0 + wr * (BM / 2) + f * 16 + (lane >> 4) * 4 + r;
        int n = n0 + wc * (BN / 2) + g * 16 + r16;
        float v = acc[f][g][r];
        if (BIAS) v += bias[n];
        if (RELU) v = fmaxf(v, 0.f);
        C[(size_t)m * N + n] = v;
      }
}

// ---------------- generic tiled f32 GEMM (adj path + tiny GEMMs) ----------------
template <bool RELU, bool BIAS, bool CAT>
__global__ __launch_bounds__(256) void gemm_f32(
    const float* __restrict__ A, const float* __restrict__ A2,
    const float* __restrict__ Bm, const float* __restrict__ bias,
    float* __restrict__ C, int M, int N, int K, int K1) {
  __shared__ float As[16][64];
  __shared__ float Bs[16][68];
  int tid = threadIdx.x;
  int m0 = blockIdx.y * 64, n0 = blockIdx.x * 64;
  int ar = tid >> 2, ak = (tid & 3) << 2;
  int br = tid >> 4, bn = (tid & 15) << 2;
  int tm = (tid >> 4) << 2, tn = (tid & 15) << 2;
  float acc[4][4] = {};
  for (int k0 = 0; k0 < K; k0 += 16) {
    {
      int row = m0 + ar, kgl = k0 + ak;
      float4 v = make_float4(0.f, 0.f, 0.f, 0.f);
      if (row < M) {
        if (CAT) {
          if (kgl + 3 < K) {
            if (kgl >= K1) v = *(const float4*)(A2 + (size_t)(row / KOBJ) * (K - K1) + (kgl - K1));
            else           v = *(const float4*)(A + (size_t)row * K1 + kgl);
          } else {
            float t[4];
            for (int i = 0; i < 4; ++i) {
              int kk = kgl + i;
              t[i] = (kk < K) ? (kk >= K1 ? A2[(size_t)(row / KOBJ) * (K - K1) + kk - K1]
                                          : A[(size_t)row * K1 + kk]) : 0.f;
            }
            v = make_float4(t[0], t[1], t[2], t[3]);
          }
        } else {
          if (kgl + 3 < K) v = *(const float4*)(A + (size_t)row * K + kgl);
          else {
            float t[4];
            for (int i = 0; i < 4; ++i) {
              int kk = kgl + i;
              t[i] = (kk < K) ? A[(size_t)row * K + kk] : 0.f;
            }
            v = make_float4(t[0], t[1], t[2], t[3]);
          }
        }
      }
      As[ak + 0][ar] = v.x; As[ak + 1][ar] = v.y;
      As[ak + 2][ar] = v.z; As[ak + 3][ar] = v.w;
    }
    {
      int kgl = k0 + br, ng = n0 + bn;
      float4 v = make_float4(0.f, 0.f, 0.f, 0.f);
      if (kgl < K) {
        if (ng + 3 < N) v = *(const float4*)(Bm + (size_t)kgl * N + ng);
        else {
          float t[4];
          for (int i = 0; i < 4; ++i) {
            int nn = ng + i;
            t[i] = (nn < N) ? Bm[(size_t)kgl * N + nn] : 0.f;
          }
          v = make_float4(t[0], t[1], t[2], t[3]);
        }
      }
      Bs[br][bn + 0] = v.x; Bs[br][bn + 1] = v.y;
      Bs[br][bn + 2] = v.z; Bs[br][bn + 3] = v.w;
    }
    __syncthreads();
#pragma unroll
    for (int kk = 0; kk < 16; ++kk) {
      float4 a4 = *(const float4*)&As[kk][tm];
      float4 b4 = *(const float4*)&Bs[kk][tn];
      float a[4] = {a4.x, a4.y, a4.z, a4.w};
      float b[4] = {b4.x, b4.y, b4.z, b4.w};
#pragma unroll
      for (int i = 0; i < 4; ++i)
#pragma unroll
        for (int j = 0; j < 4; ++j) acc[i][j] = fmaf(a[i], b[j], acc[i][j]);
    }
    __syncthreads();
  }
#pragma unroll
  for (int i = 0; i < 4; ++i) {
    int mg = m0 + tm + i;
    if (mg >= M) continue;
#pragma unroll
    for (int j = 0; j < 4; ++j) {
      int ng = n0 + tn + j;
      if (ng >= N) continue;
      float v = acc[i][j];
      if (BIAS) v += bias[ng];
      if (RELU) v = fmaxf(v, 0.f);
      C[(size_t)mg * N + ng] = v;
    }
  }
}

// ---------------- adj = h2 @ h2^T per batch ----------------
__global__ __launch_bounds__(256) void adj_kernel(const float* __restrict__ h2,
                                                  float* __restrict__ adj) {
  __shared__ float Rk[16][COMB_ + 1];
  __shared__ float Rl[16][COMB_ + 1];
  int b = blockIdx.z, k0 = blockIdx.y * 16, l0 = blockIdx.x * 16;
  int tid = threadIdx.y * 16 + threadIdx.x;
  for (int e = tid; e < 16 * COMB_; e += 256) {
    int r = e >> 9, f = e & (COMB_ - 1);
    Rk[r][f] = (k0 + r < KOBJ) ? h2[((size_t)b * KOBJ + k0 + r) * COMB_ + f] : 0.f;
    Rl[r][f] = (l0 + r < KOBJ) ? h2[((size_t)b * KOBJ + l0 + r) * COMB_ + f] : 0.f;
  }
  __syncthreads();
  int i = threadIdx.y, j = threadIdx.x;
  float acc = 0.f;
  for (int f = 0; f < COMB_; ++f) acc = fmaf(Rk[i][f], Rl[j][f], acc);
  int kg = k0 + i, lg = l0 + j;
  if (kg < KOBJ && lg < KOBJ) adj[((size_t)b * KOBJ + kg) * KOBJ + lg] = acc;
}

// ---------------- top-k + softmax + gaussian kernel weights ----------------
__global__ __launch_bounds__(256) void topk_weights_kernel(
    const float* __restrict__ adj, const float* __restrict__ cent,
    const float* __restrict__ mr1, const float* __restrict__ mt1,
    const float* __restrict__ pr1, const float* __restrict__ pt1,
    const float* __restrict__ mr2, const float* __restrict__ mt2,
    const float* __restrict__ pr2, const float* __restrict__ pt2,
    int* __restrict__ topi, float* __restrict__ c1, float* __restrict__ c2) {
  int row = blockIdx.x * 4 + (threadIdx.x >> 6);
  int lane = threadIdx.x & 63;
  int b = row / KOBJ, k = row % KOBJ;
  const float* ar = adj + (size_t)row * KOBJ;
  float v0 = (lane < KOBJ) ? ar[lane] : -INFINITY;
  float v1 = (lane + 64 < KOBJ) ? ar[lane + 64] : -INFINITY;
  int i0 = lane, i1 = lane + 64;
  float tv[NS_];
  int ti[NS_];
#pragma unroll
  for (int s = 0; s < NS_; ++s) {
    bool p0 = (v0 > v1) || (v0 == v1 && i0 < i1);
    float bv = p0 ? v0 : v1;
    int bi = p0 ? i0 : i1;
#pragma unroll
    for (int off = 32; off > 0; off >>= 1) {
      float ov = __shfl_xor(bv, off);
      int oi = __shfl_xor(bi, off);
      if (ov > bv || (ov == bv && oi < bi)) { bv = ov; bi = oi; }
    }
    tv[s] = bv; ti[s] = bi;
    if (bi == i0) v0 = -INFINITY;
    if (bi == i1) v1 = -INFINITY;
  }
  float mx = tv[0], sum = 0.f, av[NS_];
#pragma unroll
  for (int s = 0; s < NS_; ++s) { av[s] = expf(tv[s] - mx); sum += av[s]; }
  if (lane < NS_) {
    int j = ti[lane];
    topi[(size_t)row * NS_ + lane] = j;
    float cx = cent[(b * KOBJ + k) * 2 + 0], cy = cent[(b * KOBJ + k) * 2 + 1];
    float dx = cx - cent[(b * KOBJ + j) * 2 + 0];
    float dy = cy - cent[(b * KOBJ + j) * 2 + 1];
    float rho = sqrtf(dx * dx + dy * dy);
    float th = atan2f(dx, dy);
    float w1[NK_], w2[NK_], s1 = 0.f, s2 = 0.f;
#pragma unroll
    for (int m = 0; m < NK_; ++m) {
      {
        float pr = pr1[m], pt = pt1[m], dr = rho - mr1[m];
        float wr = expf(-0.5f * dr * dr / (1e-14f + pr * pr));
        float fa = fabsf(th - mt1[m]);
        float sa = fabsf(6.283185307179586f - fa);
        float da = fminf(fa, sa);
        float wt = expf(-0.5f * da * da / (1e-14f + pt * pt));
        float w = wr * wt;
        if (w != w) w = 0.f;
        w1[m] = w; s1 += w;
      }
      {
        float pr = pr2[m], pt = pt2[m], dr = rho - mr2[m];
        float wr = expf(-0.5f * dr * dr / (1e-14f + pr * pr));
        float fa = fabsf(th - mt2[m]);
        float sa = fabsf(6.283185307179586f - fa);
        float da = fminf(fa, sa);
        float wt = expf(-0.5f * da * da / (1e-14f + pt * pt));
        float w = wr * wt;
        if (w != w) w = 0.f;
        w2[m] = w; s2 += w;
      }
    }
    float as = av[lane] / sum;
#pragma unroll
    for (int m = 0; m < NK_; ++m) {
      c1[((size_t)row * NS_ + lane) * NK_ + m] = as * (w1[m] / s1);
      c2[((size_t)row * NS_ + lane) * NK_ + m] = w2[m] / s2;
    }
  }
}

// ---------------- gather-combine ----------------
// out[row,n] = relu(sum_s c[row,s,m(n)] * proj[b, idx[row,s], n]); optional bf16 out
template <bool BF16OUT>
__global__ __launch_bounds__(256) void combine_kernel(
    const float* __restrict__ proj, const float* __restrict__ coeff,
    const int* __restrict__ topi, float* __restrict__ outf, short* __restrict__ outb,
    int N, int mshift) {
  int row = blockIdx.y;
  int b = row / KOBJ;
  __shared__ int ids[NS_];
  __shared__ float cs[NS_ * NK_];
  int tid = threadIdx.x;
  if (tid < NS_) ids[tid] = topi[(size_t)row * NS_ + tid];
  else if (tid >= 32 && tid < 32 + NS_ * NK_) cs[tid - 32] = coeff[(size_t)row * NS_ * NK_ + (tid - 32)];
  __syncthreads();
  int n = blockIdx.x * 256 + tid;
  if (n >= N) return;
  int m = n >> mshift;
  float acc = 0.f;
#pragma unroll
  for (int s = 0; s < NS_; ++s)
    acc = fmaf(cs[s * NK_ + m], proj[((size_t)b * KOBJ + ids[s]) * N + n], acc);
  acc = fmaxf(acc, 0.f);
  if (BF16OUT) outb[(size_t)row * N + n] = f2bf(acc);
  else         outf[(size_t)row * N + n] = acc;
}

// ---------------- max over k, then hh = relu(qenc) * g2max ----------------
__global__ void reduce_hh_kernel(const float* __restrict__ g2, const float* __restrict__ qenc,
                                 float* __restrict__ hh) {
  int i = blockIdx.x * blockDim.x + threadIdx.x;
  if (i >= B_ * HID_) return;
  int b = i >> 10, n = i & (HID_ - 1);
  const float* p = g2 + (size_t)b * KOBJ * HID_ + n;
  float mx = -INFINITY;
  for (int k = 0; k < KOBJ; ++k) mx = fmaxf(mx, p[(size_t)k * HID_]);
  hh[i] = fmaxf(qenc[i], 0.f) * mx;
}

extern "C" void kernel_launch(void* const* d_in, const int* in_sizes, int n_in,
                              void* d_out, int out_size, void* d_ws, size_t ws_size,
                              hipStream_t stream) {
  const float* question = (const float*)d_in[0];
  const float* image    = (const float*)d_in[1];
  const float* W_lproj  = (const float*)d_in[3];
  const float* b_lproj  = (const float*)d_in[4];
  const float* W_e1     = (const float*)d_in[5];
  const float* b_e1     = (const float*)d_in[6];
  const float* W_e2     = (const float*)d_in[7];
  const float* b_e2     = (const float*)d_in[8];
  const float* conv_w1  = (const float*)d_in[9];
  const float* mr1 = (const float*)d_in[10];
  const float* mt1 = (const float*)d_in[11];
  const float* pr1 = (const float*)d_in[12];
  const float* pt1 = (const float*)d_in[13];
  const float* conv_w2  = (const float*)d_in[14];
  const float* mr2 = (const float*)d_in[15];
  const float* mt2 = (const float*)d_in[16];
  const float* pr2 = (const float*)d_in[17];
  const float* pt2 = (const float*)d_in[18];
  const float* W_o1 = (const float*)d_in[19];
  const float* b_o1 = (const float*)d_in[20];
  const float* W_o2 = (const float*)d_in[21];
  const float* b_o2 = (const float*)d_in[22];

  float* out = (float*)d_out;
  float* logits = out;               // [32,3000]
  float* adj = out + B_ * OUT_;      // [32,100,100]

  char* ws = (char*)d_ws;
  size_t off = 0;
  auto alloc = [&](size_t bytes) { char* p = ws + off; off += (bytes + 255) & ~((size_t)255); return p; };
  float* qenc  = (float*)alloc((size_t)B_ * HID_ * 4);
  float* h1    = (float*)alloc((size_t)B_ * KOBJ * COMB_ * 4);
  float* h2    = (float*)alloc((size_t)B_ * KOBJ * COMB_ * 4);
  float* cent  = (float*)alloc((size_t)B_ * KOBJ * 2 * 4);
  int*   topi  = (int*)alloc((size_t)B_ * KOBJ * NS_ * 4);
  float* c1    = (float*)alloc((size_t)B_ * KOBJ * NS_ * NK_ * 4);
  float* c2    = (float*)alloc((size_t)B_ * KOBJ * NS_ * NK_ * 4);
  float* proj1 = (float*)alloc((size_t)B_ * KOBJ * 2 * HID_ * 4);
  float* proj2 = (float*)alloc((size_t)B_ * KOBJ * HID_ * 4);
  float* g2    = (float*)alloc((size_t)B_ * KOBJ * HID_ * 4);
  float* hh    = (float*)alloc((size_t)B_ * HID_ * 4);
  float* h1o   = (float*)alloc((size_t)B_ * OUT_ * 4);
  short* imgb  = (short*)alloc((size_t)B_ * KOBJ * KP1 * 2);
  short* cw1t  = (short*)alloc((size_t)(2 * HID_) * KP1 * 2);
  short* cw2t  = (short*)alloc((size_t)HID_ * KP2 * 2);
  short* g1b   = (short*)alloc((size_t)B_ * KOBJ * KP2 * 2);
  (void)ws_size; (void)in_sizes; (void)n_in; (void)out_size;

  dim3 blk(256);
  auto ggrid = [](int M, int N) { return dim3((N + 63) / 64, (M + 63) / 64); };

  // conversions (no deps)
  centres_kernel<<<dim3((B_ * KOBJ + 255) / 256), blk, 0, stream>>>(image, cent);
  {
    int total = B_ * KOBJ * (KP1 / 8);
    cvt_pad_rows<<<dim3((total + 255) / 256), blk, 0, stream>>>(image, imgb, FEAT_, KP1, total);
  }
  transpose_bf16<true><<<dim3(KP1 / 64, (2 * HID_) / 64), blk, 0, stream>>>(
      conv_w1, cw1t, FEAT_, 2 * HID_, KP1, 2 * HID_ / NK_);
  transpose_bf16<true><<<dim3(KP2 / 64, HID_ / 64), blk, 0, stream>>>(
      conv_w2, cw2t, 2 * HID_, HID_, KP2, HID_ / NK_);

  // f32 path (feeds adj output — precision-critical)
  gemm_f32<false, true, false><<<ggrid(B_, HID_), blk, 0, stream>>>(
      question, nullptr, W_lproj, b_lproj, qenc, B_, HID_, EMB_, 0);
  gemm_f32<true, true, true><<<ggrid(B_ * KOBJ, COMB_), blk, 0, stream>>>(
      image, qenc, W_e1, b_e1, h1, B_ * KOBJ, COMB_, FEAT_ + HID_, FEAT_);
  gemm_f32<true, true, false><<<ggrid(B_ * KOBJ, COMB_), blk, 0, stream>>>(
      h1, nullptr, W_e2, b_e2, h2, B_ * KOBJ, COMB_, COMB_, 0);
  adj_kernel<<<dim3(7, 7, B_), dim3(16, 16), 0, stream>>>(h2, adj);
  topk_weights_kernel<<<dim3(B_ * KOBJ / 4), blk, 0, stream>>>(
      adj, cent, mr1, mt1, pr1, pt1, mr2, mt2, pr2, pt2, topi, c1, c2);

  // conv path: bf16 MFMA GEMMs
  gemm_mfma<128, 128, false, false><<<dim3(2 * HID_ / 128, B_ * KOBJ / 128), blk, 0, stream>>>(
      imgb, cw1t, nullptr, proj1, B_ * KOBJ, 2 * HID_, KP1);
  combine_kernel<true><<<dim3(2 * HID_ / 256, B_ * KOBJ), blk, 0, stream>>>(
      proj1, c1, topi, nullptr, g1b, 2 * HID_, 8);
  gemm_mfma<128, 64, false, false><<<dim3(HID_ / 64, B_ * KOBJ / 128), blk, 0, stream>>>(
      g1b, cw2t, nullptr, proj2, B_ * KOBJ, HID_, KP2);
  combine_kernel<false><<<dim3(HID_ / 256, B_ * KOBJ), blk, 0, stream>>>(
      proj2, c2, topi, g2, nullptr, HID_, 7);

  // tail
  reduce_hh_kernel<<<dim3((B_ * HID_ + 255) / 256), blk, 0, stream>>>(g2, qenc, hh);
  gemm_f32<true, true, false><<<ggrid(B_, OUT_), blk, 0, stream>>>(
      hh, nullptr, W_o1, b_o1, h1o, B_, OUT_, HID_, 0);
  gemm_f32<false, true, false><<<ggrid(B_, OUT_), blk, 0, stream>>>(
      h1o, nullptr, W_o2, b_o2, logits, B_, OUT_, OUT_, 0);
}

// Round 3
// 615.320 us; speedup vs baseline: 2.4322x; 1.5542x over previous
//
#include <hip/hip_runtime.h>
#include <math.h>
#include <stdint.h>

#define B_    32
#define KOBJ  100
#define NS_   16
#define NK_   8
#define EMB_  1024
#define FEAT_ 2052
#define HID_  1024
#define OUT_  3000
#define COMB_ 512

#define KP1   2112   // FEAT_ padded to 64 for proj1
#define KP2   2048   // 2*HID_
#define KCAT  3136   // FEAT_+HID_=3076 padded to 64
#define NO_P  3072   // OUT_ padded to 128 (B-rows for o1/o2)
#define KO2   3008   // OUT_ padded to 64 (K of o2)

typedef __attribute__((ext_vector_type(8))) short s16x8;
typedef __attribute__((ext_vector_type(4))) float f32x4;

__device__ inline short f2bf(float f) {
  uint32_t u = __builtin_bit_cast(uint32_t, f);
  u = (u + 0x7fff + ((u >> 16) & 1)) >> 16;  // RNE
  return (short)u;
}
__device__ inline float bf2f(short s) {
  uint32_t u = ((uint32_t)(uint16_t)s) << 16;
  return __builtin_bit_cast(float, u);
}
__device__ inline void gload_lds16(const void* g, void* l) {
  __builtin_amdgcn_global_load_lds(
      (const __attribute__((address_space(1))) void*)g,
      (__attribute__((address_space(3))) void*)l, 16, 0, 0);
}

// ---------------- bb centres ----------------
__global__ void centres_kernel(const float* __restrict__ image, float* __restrict__ cent) {
  int i = blockIdx.x * blockDim.x + threadIdx.x;
  if (i >= B_ * KOBJ) return;
  const float* bb = image + (size_t)i * FEAT_ + (FEAT_ - 4);
  cent[i * 2 + 0] = 0.5f * (bb[0] + bb[2]);
  cent[i * 2 + 1] = 0.5f * (bb[1] + bb[3]);
}

// ---------------- f32 -> bf16 row-major convert with K padding (optional hi/lo split) ----
template <bool SPLIT>
__global__ void cvt_pad_rows(const float* __restrict__ in, short* __restrict__ outh,
                             short* __restrict__ outl, int K, int Kp, int total) {
  int idx = blockIdx.x * 256 + threadIdx.x;
  if (idx >= total) return;
  int row = idx / (Kp / 8), c8 = (idx % (Kp / 8)) * 8;
  s16x8 vh, vl;
#pragma unroll
  for (int i = 0; i < 8; ++i) {
    int k = c8 + i;
    float f = (k < K) ? in[(size_t)row * K + k] : 0.f;
    short h = f2bf(f);
    vh[i] = h;
    if (SPLIT) vl[i] = f2bf(f - bf2f(h));
  }
  *(s16x8*)(outh + (size_t)row * Kp + c8) = vh;
  if (SPLIT) *(s16x8*)(outl + (size_t)row * Kp + c8) = vl;
}

// ---------------- transpose-convert weights to Bt[n][kp] bf16 (optional split) ----------
// CONV: in element (k,n) = in[((n/OPM)*K + k)*OPM + (n%OPM)]; else in[k*N + n]
template <bool CONV, bool SPLIT>
__global__ __launch_bounds__(256) void transpose_bf16(
    const float* __restrict__ in, short* __restrict__ outh, short* __restrict__ outl,
    int K, int N, int Kp, int OPM) {
  __shared__ float s[64][65];
  int k0 = blockIdx.x * 64, n0 = blockIdx.y * 64;
  int t = threadIdx.x;
  int r = t >> 2, cb = (t & 3) << 4;
  int kg = k0 + r;
#pragma unroll
  for (int i = 0; i < 16; ++i) {
    int n = n0 + cb + i;
    float v = 0.f;
    if (kg < K && n < N) v = CONV ? in[((size_t)(n / OPM) * K + kg) * OPM + (n % OPM)]
                               : in[(size_t)kg * N + n];
    s[r][cb + i] = v;
  }
  __syncthreads();
  int nl = t >> 2, kc = (t & 3) << 4;
#pragma unroll
  for (int half = 0; half < 2; ++half) {
    s16x8 vh, vl;
#pragma unroll
    for (int i = 0; i < 8; ++i) {
      float f = s[kc + half * 8 + i][nl];
      short h = f2bf(f);
      vh[i] = h;
      if (SPLIT) vl[i] = f2bf(f - bf2f(h));
    }
    short* o = outh + (size_t)(n0 + nl) * Kp + k0 + kc + half * 8;
    *(s16x8*)o = vh;
    if (SPLIT) *(s16x8*)(outl + (size_t)(n0 + nl) * Kp + k0 + kc + half * 8) = vl;
  }
}

// ---------------- build Acat = [image | qenc(bcast) | 0pad] as hi/lo bf16 ----------------
__global__ void build_acat(const float* __restrict__ image, const float* __restrict__ qenc,
                           short* __restrict__ h, short* __restrict__ l) {
  int idx = blockIdx.x * 256 + threadIdx.x;
  const int CH = KCAT / 8;
  if (idx >= B_ * KOBJ * CH) return;
  int row = idx / CH, c8 = (idx % CH) * 8;
  s16x8 vh, vl;
#pragma unroll
  for (int i = 0; i < 8; ++i) {
    int col = c8 + i;
    float f = 0.f;
    if (col < FEAT_) f = image[(size_t)row * FEAT_ + col];
    else if (col < FEAT_ + HID_) f = qenc[(size_t)(row / KOBJ) * HID_ + (col - FEAT_)];
    short hh = f2bf(f);
    vh[i] = hh;
    vl[i] = f2bf(f - bf2f(hh));
  }
  *(s16x8*)(h + (size_t)row * KCAT + c8) = vh;
  *(s16x8*)(l + (size_t)row * KCAT + c8) = vl;
}

// ---------------- unified MFMA GEMM ----------------
// C[M][N] (+bias, relu) = A[M][Kp] @ Bt[N][Kp]^T, bf16 MFMA.
// SPLIT: A,B given as hi/lo pairs -> 3-product split-f32 (~fp32 accuracy).
// Waves: WR x WC grid (WR*WC==4). OMODE: 0=f32 out, 1=bf16 hi/lo pair, 2=bf16.
// Writes columns [0,Nw); value zeroed (and bias skipped) for n>=N.
template <int BM, int BN, int WR, int WC, bool SPLIT, bool RELU, bool BIAS, int OMODE>
__global__ __launch_bounds__(256) void gemm_mx(
    const short* __restrict__ Ah, const short* __restrict__ Al,
    const short* __restrict__ Bh, const short* __restrict__ Bl,
    const float* __restrict__ bias,
    float* __restrict__ Cf, short* __restrict__ Ch, short* __restrict__ Cl,
    int M, int N, int Kp, int ldc, int Nw) {
  constexpr int WM = BM / WR, WN = BN / WC;
  constexpr int FM = WM / 16, FN = WN / 16;
  constexpr int ACH = BM / 8, BCH = BN / 8;
  constexpr int NCH = (ACH + BCH) * (SPLIT ? 2 : 1);
  __shared__ short Ash[BM * 64];
  __shared__ short Bsh[BN * 64];
  __shared__ short Asl[SPLIT ? BM * 64 : 64];
  __shared__ short Bsl[SPLIT ? BN * 64 : 64];
  int tid = threadIdx.x, wave = tid >> 6, lane = tid & 63;
  int wr = wave / WC, wc = wave % WC;
  int r16 = lane & 15, kq = lane >> 4;
  int m0 = blockIdx.y * BM, n0 = blockIdx.x * BN;
  f32x4 acc[FM][FN] = {};

  for (int k0 = 0; k0 < Kp; k0 += 64) {
    __syncthreads();
    for (int c = wave; c < NCH; c += 4) {
      int cc = c;
      const short* g;
      char* l;
      bool isA;
      if (cc < ACH) { isA = true; g = Ah; l = (char*)Ash; }
      else if (SPLIT && cc < 2 * ACH) { cc -= ACH; isA = true; g = Al; l = (char*)Asl; }
      else {
        cc -= SPLIT ? 2 * ACH : ACH;
        if (cc < BCH) { isA = false; g = Bh; l = (char*)Bsh; }
        else { cc -= BCH; isA = false; g = Bl; l = (char*)Bsl; }
      }
      int Lb = cc * 1024 + lane * 16;
      int row = Lb >> 7;
      int off = (Lb & 127) ^ ((row & 7) << 4);
      const short* gsrc = g + (size_t)((isA ? m0 : n0) + row) * Kp + k0 + (off >> 1);
      gload_lds16(gsrc, l + cc * 1024);
    }
    __syncthreads();  // compiler drains vmcnt before barrier
#pragma unroll
    for (int kk = 0; kk < 2; ++kk) {
      int woff = kk * 64 + kq * 16;
      s16x8 ah[FM], al[FM], bh[FN], bl[FN];
#pragma unroll
      for (int f = 0; f < FM; ++f) {
        int row = wr * WM + f * 16 + r16;
        int o = woff ^ ((row & 7) << 4);
        ah[f] = *(const s16x8*)((const char*)Ash + row * 128 + o);
        if (SPLIT) al[f] = *(const s16x8*)((const char*)Asl + row * 128 + o);
      }
#pragma unroll
      for (int gg = 0; gg < FN; ++gg) {
        int row = wc * WN + gg * 16 + r16;
        int o = woff ^ ((row & 7) << 4);
        bh[gg] = *(const s16x8*)((const char*)Bsh + row * 128 + o);
        if (SPLIT) bl[gg] = *(const s16x8*)((const char*)Bsl + row * 128 + o);
      }
#pragma unroll
      for (int f = 0; f < FM; ++f)
#pragma unroll
        for (int gg = 0; gg < FN; ++gg) {
          acc[f][gg] = __builtin_amdgcn_mfma_f32_16x16x32_bf16(ah[f], bh[gg], acc[f][gg], 0, 0, 0);
          if (SPLIT) {
            acc[f][gg] = __builtin_amdgcn_mfma_f32_16x16x32_bf16(ah[f], bl[gg], acc[f][gg], 0, 0, 0);
            acc[f][gg] = __builtin_amdgcn_mfma_f32_16x16x32_bf16(al[f], bh[gg], acc[f][gg], 0, 0, 0);
          }
        }
    }
  }
#pragma unroll
  for (int f = 0; f < FM; ++f)
#pragma unroll
    for (int gg = 0; gg < FN; ++gg)
#pragma unroll
      for (int r = 0; r < 4; ++r) {
        int m = m0 + wr * WM + f * 16 + (lane >> 4) * 4 + r;
        int n = n0 + wc * WN + gg * 16 + r16;
        if (m >= M || n >= Nw) continue;
        float v = (n < N) ? acc[f][gg][r] : 0.f;
        if (BIAS && n < N) v += bias[n];
        if (RELU) v = fmaxf(v, 0.f);
        size_t idx = (size_t)m * ldc + n;
        if (OMODE == 0) Cf[idx] = v;
        else if (OMODE == 1) {
          short h = f2bf(v);
          Ch[idx] = h;
          Cl[idx] = f2bf(v - bf2f(h));
        } else {
          Ch[idx] = f2bf(v);
        }
      }
}

// ---------------- adj = h2 @ h2^T per batch (f32) ----------------
__global__ __launch_bounds__(256) void adj_kernel(const float* __restrict__ h2,
                                                  float* __restrict__ adj) {
  __shared__ float Rk[16][COMB_ + 1];
  __shared__ float Rl[16][COMB_ + 1];
  int b = blockIdx.z, k0 = blockIdx.y * 16, l0 = blockIdx.x * 16;
  int tid = threadIdx.y * 16 + threadIdx.x;
  for (int e = tid; e < 16 * COMB_; e += 256) {
    int r = e >> 9, f = e & (COMB_ - 1);
    Rk[r][f] = (k0 + r < KOBJ) ? h2[((size_t)b * KOBJ + k0 + r) * COMB_ + f] : 0.f;
    Rl[r][f] = (l0 + r < KOBJ) ? h2[((size_t)b * KOBJ + l0 + r) * COMB_ + f] : 0.f;
  }
  __syncthreads();
  int i = threadIdx.y, j = threadIdx.x;
  float acc = 0.f;
  for (int f = 0; f < COMB_; ++f) acc = fmaf(Rk[i][f], Rl[j][f], acc);
  int kg = k0 + i, lg = l0 + j;
  if (kg < KOBJ && lg < KOBJ) adj[((size_t)b * KOBJ + kg) * KOBJ + lg] = acc;
}

// ---------------- top-k + softmax + gaussian kernel weights ----------------
__global__ __launch_bounds__(256) void topk_weights_kernel(
    const float* __restrict__ adj, const float* __restrict__ cent,
    const float* __restrict__ mr1, const float* __restrict__ mt1,
    const float* __restrict__ pr1, const float* __restrict__ pt1,
    const float* __restrict__ mr2, const float* __restrict__ mt2,
    const float* __restrict__ pr2, const float* __restrict__ pt2,
    int* __restrict__ topi, float* __restrict__ c1, float* __restrict__ c2) {
  int row = blockIdx.x * 4 + (threadIdx.x >> 6);
  int lane = threadIdx.x & 63;
  int b = row / KOBJ, k = row % KOBJ;
  const float* ar = adj + (size_t)row * KOBJ;
  float v0 = (lane < KOBJ) ? ar[lane] : -INFINITY;
  float v1 = (lane + 64 < KOBJ) ? ar[lane + 64] : -INFINITY;
  int i0 = lane, i1 = lane + 64;
  float tv[NS_];
  int ti[NS_];
#pragma unroll
  for (int s = 0; s < NS_; ++s) {
    bool p0 = (v0 > v1) || (v0 == v1 && i0 < i1);
    float bv = p0 ? v0 : v1;
    int bi = p0 ? i0 : i1;
#pragma unroll
    for (int off = 32; off > 0; off >>= 1) {
      float ov = __shfl_xor(bv, off);
      int oi = __shfl_xor(bi, off);
      if (ov > bv || (ov == bv && oi < bi)) { bv = ov; bi = oi; }
    }
    tv[s] = bv; ti[s] = bi;
    if (bi == i0) v0 = -INFINITY;
    if (bi == i1) v1 = -INFINITY;
  }
  float mx = tv[0], sum = 0.f, av[NS_];
#pragma unroll
  for (int s = 0; s < NS_; ++s) { av[s] = expf(tv[s] - mx); sum += av[s]; }
  if (lane < NS_) {
    int j = ti[lane];
    topi[(size_t)row * NS_ + lane] = j;
    float cx = cent[(b * KOBJ + k) * 2 + 0], cy = cent[(b * KOBJ + k) * 2 + 1];
    float dx = cx - cent[(b * KOBJ + j) * 2 + 0];
    float dy = cy - cent[(b * KOBJ + j) * 2 + 1];
    float rho = sqrtf(dx * dx + dy * dy);
    float th = atan2f(dx, dy);
    float w1[NK_], w2[NK_], s1 = 0.f, s2 = 0.f;
#pragma unroll
    for (int m = 0; m < NK_; ++m) {
      {
        float pr = pr1[m], pt = pt1[m], dr = rho - mr1[m];
        float wr = expf(-0.5f * dr * dr / (1e-14f + pr * pr));
        float fa = fabsf(th - mt1[m]);
        float sa = fabsf(6.283185307179586f - fa);
        float da = fminf(fa, sa);
        float wt = expf(-0.5f * da * da / (1e-14f + pt * pt));
        float w = wr * wt;
        if (w != w) w = 0.f;
        w1[m] = w; s1 += w;
      }
      {
        float pr = pr2[m], pt = pt2[m], dr = rho - mr2[m];
        float wr = expf(-0.5f * dr * dr / (1e-14f + pr * pr));
        float fa = fabsf(th - mt2[m]);
        float sa = fabsf(6.283185307179586f - fa);
        float da = fminf(fa, sa);
        float wt = expf(-0.5f * da * da / (1e-14f + pt * pt));
        float w = wr * wt;
        if (w != w) w = 0.f;
        w2[m] = w; s2 += w;
      }
    }
    float as = av[lane] / sum;
#pragma unroll
    for (int m = 0; m < NK_; ++m) {
      c1[((size_t)row * NS_ + lane) * NK_ + m] = as * (w1[m] / s1);
      c2[((size_t)row * NS_ + lane) * NK_ + m] = w2[m] / s2;
    }
  }
}

// ---------------- gather-combine ----------------
template <bool BF16OUT>
__global__ __launch_bounds__(256) void combine_kernel(
    const float* __restrict__ proj, const float* __restrict__ coeff,
    const int* __restrict__ topi, float* __restrict__ outf, short* __restrict__ outb,
    int N, int mshift) {
  int row = blockIdx.y;
  int b = row / KOBJ;
  __shared__ int ids[NS_];
  __shared__ float cs[NS_ * NK_];
  int tid = threadIdx.x;
  if (tid < NS_) ids[tid] = topi[(size_t)row * NS_ + tid];
  else if (tid >= 32 && tid < 32 + NS_ * NK_) cs[tid - 32] = coeff[(size_t)row * NS_ * NK_ + (tid - 32)];
  __syncthreads();
  int n = blockIdx.x * 256 + tid;
  if (n >= N) return;
  int m = n >> mshift;
  float acc = 0.f;
#pragma unroll
  for (int s = 0; s < NS_; ++s)
    acc = fmaf(cs[s * NK_ + m], proj[((size_t)b * KOBJ + ids[s]) * N + n], acc);
  acc = fmaxf(acc, 0.f);
  if (BF16OUT) outb[(size_t)row * N + n] = f2bf(acc);
  else         outf[(size_t)row * N + n] = acc;
}

// ---------------- max over k, then hh = relu(qenc) * g2max (bf16 out) ----------------
__global__ void reduce_hh_kernel(const float* __restrict__ g2, const float* __restrict__ qenc,
                                 short* __restrict__ hhb) {
  int i = blockIdx.x * blockDim.x + threadIdx.x;
  if (i >= B_ * HID_) return;
  int b = i >> 10, n = i & (HID_ - 1);
  const float* p = g2 + (size_t)b * KOBJ * HID_ + n;
  float mx = -INFINITY;
  for (int k = 0; k < KOBJ; ++k) mx = fmaxf(mx, p[(size_t)k * HID_]);
  hhb[i] = f2bf(fmaxf(qenc[i], 0.f) * mx);
}

extern "C" void kernel_launch(void* const* d_in, const int* in_sizes, int n_in,
                              void* d_out, int out_size, void* d_ws, size_t ws_size,
                              hipStream_t stream) {
  const float* question = (const float*)d_in[0];
  const float* image    = (const float*)d_in[1];
  const float* W_lproj  = (const float*)d_in[3];
  const float* b_lproj  = (const float*)d_in[4];
  const float* W_e1     = (const float*)d_in[5];
  const float* b_e1     = (const float*)d_in[6];
  const float* W_e2     = (const float*)d_in[7];
  const float* b_e2     = (const float*)d_in[8];
  const float* conv_w1  = (const float*)d_in[9];
  const float* mr1 = (const float*)d_in[10];
  const float* mt1 = (const float*)d_in[11];
  const float* pr1 = (const float*)d_in[12];
  const float* pt1 = (const float*)d_in[13];
  const float* conv_w2  = (const float*)d_in[14];
  const float* mr2 = (const float*)d_in[15];
  const float* mt2 = (const float*)d_in[16];
  const float* pr2 = (const float*)d_in[17];
  const float* pt2 = (const float*)d_in[18];
  const float* W_o1 = (const float*)d_in[19];
  const float* b_o1 = (const float*)d_in[20];
  const float* W_o2 = (const float*)d_in[21];
  const float* b_o2 = (const float*)d_in[22];

  float* out = (float*)d_out;
  float* logits = out;               // [32,3000]
  float* adj = out + B_ * OUT_;      // [32,100,100]

  char* ws = (char*)d_ws;
  size_t off = 0;
  auto alloc = [&](size_t bytes) { char* p = ws + off; off += (bytes + 255) & ~((size_t)255); return p; };
  float* qenc  = (float*)alloc((size_t)B_ * HID_ * 4);
  short* qh    = (short*)alloc((size_t)B_ * EMB_ * 2);
  short* ql    = (short*)alloc((size_t)B_ * EMB_ * 2);
  short* wlph  = (short*)alloc((size_t)EMB_ * HID_ * 2);
  short* wlpl  = (short*)alloc((size_t)EMB_ * HID_ * 2);
  short* we1h  = (short*)alloc((size_t)COMB_ * KCAT * 2);
  short* we1l  = (short*)alloc((size_t)COMB_ * KCAT * 2);
  short* we2h  = (short*)alloc((size_t)COMB_ * COMB_ * 2);
  short* we2l  = (short*)alloc((size_t)COMB_ * COMB_ * 2);
  short* h1h   = (short*)alloc((size_t)B_ * KOBJ * COMB_ * 2);
  short* h1l   = (short*)alloc((size_t)B_ * KOBJ * COMB_ * 2);
  float* h2    = (float*)alloc((size_t)B_ * KOBJ * COMB_ * 4);
  float* cent  = (float*)alloc((size_t)B_ * KOBJ * 2 * 4);
  int*   topi  = (int*)alloc((size_t)B_ * KOBJ * NS_ * 4);
  float* c1    = (float*)alloc((size_t)B_ * KOBJ * NS_ * NK_ * 4);
  float* c2    = (float*)alloc((size_t)B_ * KOBJ * NS_ * NK_ * 4);
  short* imgb  = (short*)alloc((size_t)B_ * KOBJ * KP1 * 2);
  short* cw1t  = (short*)alloc((size_t)(2 * HID_) * KP1 * 2);
  short* cw2t  = (short*)alloc((size_t)HID_ * KP2 * 2);
  short* g1b   = (short*)alloc((size_t)B_ * KOBJ * KP2 * 2);
  float* g2    = (float*)alloc((size_t)B_ * KOBJ * HID_ * 4);
  short* hhb   = (short*)alloc((size_t)B_ * HID_ * 2);
  short* wo1t  = (short*)alloc((size_t)NO_P * HID_ * 2);
  short* wo2t  = (short*)alloc((size_t)NO_P * KO2 * 2);
  short* h1ob  = (short*)alloc((size_t)B_ * KO2 * 2);
  // union region: acat hi/lo (alive until e1) aliases proj1+proj2 (written after e1)
  size_t acat_b = (size_t)B_ * KOBJ * KCAT * 2;
  char*  U     = alloc(2 * acat_b > (size_t)B_ * KOBJ * (2 * HID_ + HID_) * 4
                           ? 2 * acat_b : (size_t)B_ * KOBJ * (2 * HID_ + HID_) * 4);
  short* acath = (short*)U;
  short* acatl = (short*)(U + acat_b);
  float* proj1 = (float*)U;
  float* proj2 = (float*)(U + (size_t)B_ * KOBJ * 2 * HID_ * 4);
  (void)ws_size; (void)in_sizes; (void)n_in; (void)out_size;

  dim3 blk(256);

  // ---- independent prep ----
  centres_kernel<<<dim3((B_ * KOBJ + 255) / 256), blk, 0, stream>>>(image, cent);
  {
    int total = B_ * KOBJ * (KP1 / 8);
    cvt_pad_rows<false><<<dim3((total + 255) / 256), blk, 0, stream>>>(image, imgb, nullptr, FEAT_, KP1, total);
  }
  {
    int total = B_ * (EMB_ / 8);
    cvt_pad_rows<true><<<dim3((total + 255) / 256), blk, 0, stream>>>(question, qh, ql, EMB_, EMB_, total);
  }
  transpose_bf16<false, true><<<dim3(EMB_ / 64, HID_ / 64), blk, 0, stream>>>(
      W_lproj, wlph, wlpl, EMB_, HID_, EMB_, 0);
  transpose_bf16<false, true><<<dim3(KCAT / 64, COMB_ / 64), blk, 0, stream>>>(
      W_e1, we1h, we1l, FEAT_ + HID_, COMB_, KCAT, 0);
  transpose_bf16<false, true><<<dim3(COMB_ / 64, COMB_ / 64), blk, 0, stream>>>(
      W_e2, we2h, we2l, COMB_, COMB_, COMB_, 0);
  transpose_bf16<true, false><<<dim3(KP1 / 64, (2 * HID_) / 64), blk, 0, stream>>>(
      conv_w1, cw1t, nullptr, FEAT_, 2 * HID_, KP1, 2 * HID_ / NK_);
  transpose_bf16<true, false><<<dim3(KP2 / 64, HID_ / 64), blk, 0, stream>>>(
      conv_w2, cw2t, nullptr, 2 * HID_, HID_, KP2, HID_ / NK_);
  transpose_bf16<false, false><<<dim3(HID_ / 64, NO_P / 64), blk, 0, stream>>>(
      W_o1, wo1t, nullptr, HID_, OUT_, HID_, 0);
  transpose_bf16<false, false><<<dim3(KO2 / 64, NO_P / 64), blk, 0, stream>>>(
      W_o2, wo2t, nullptr, OUT_, OUT_, KO2, 0);

  // ---- qenc (split, f32 out) ----
  gemm_mx<32, 64, 2, 2, true, false, true, 0><<<dim3(HID_ / 64, 1), blk, 0, stream>>>(
      qh, ql, wlph, wlpl, b_lproj, qenc, nullptr, nullptr, B_, HID_, EMB_, HID_, HID_);
  // ---- Acat build ----
  build_acat<<<dim3((B_ * KOBJ * (KCAT / 8) + 255) / 256), blk, 0, stream>>>(image, qenc, acath, acatl);
  // ---- e1 (split, bf16 hi/lo out) ----
  gemm_mx<128, 64, 2, 2, true, true, true, 1><<<dim3(COMB_ / 64, B_ * KOBJ / 128), blk, 0, stream>>>(
      acath, acatl, we1h, we1l, b_e1, nullptr, h1h, h1l, B_ * KOBJ, COMB_, KCAT, COMB_, COMB_);
  // ---- e2 (split, f32 out) ----
  gemm_mx<128, 64, 2, 2, true, true, true, 0><<<dim3(COMB_ / 64, B_ * KOBJ / 128), blk, 0, stream>>>(
      h1h, h1l, we2h, we2l, b_e2, h2, nullptr, nullptr, B_ * KOBJ, COMB_, COMB_, COMB_, COMB_);
  // ---- adj + topk ----
  adj_kernel<<<dim3(7, 7, B_), dim3(16, 16), 0, stream>>>(h2, adj);
  topk_weights_kernel<<<dim3(B_ * KOBJ / 4), blk, 0, stream>>>(
      adj, cent, mr1, mt1, pr1, pt1, mr2, mt2, pr2, pt2, topi, c1, c2);
  // ---- conv path ----
  gemm_mx<128, 128, 2, 2, false, false, false, 0><<<dim3(2 * HID_ / 128, B_ * KOBJ / 128), blk, 0, stream>>>(
      imgb, nullptr, cw1t, nullptr, nullptr, proj1, nullptr, nullptr, B_ * KOBJ, 2 * HID_, KP1, 2 * HID_, 2 * HID_);
  combine_kernel<true><<<dim3(2 * HID_ / 256, B_ * KOBJ), blk, 0, stream>>>(
      proj1, c1, topi, nullptr, g1b, 2 * HID_, 8);
  gemm_mx<128, 64, 2, 2, false, false, false, 0><<<dim3(HID_ / 64, B_ * KOBJ / 128), blk, 0, stream>>>(
      g1b, nullptr, cw2t, nullptr, nullptr, proj2, nullptr, nullptr, B_ * KOBJ, HID_, KP2, HID_, HID_);
  combine_kernel<false><<<dim3(HID_ / 256, B_ * KOBJ), blk, 0, stream>>>(
      proj2, c2, topi, g2, nullptr, HID_, 7);
  // ---- tail ----
  reduce_hh_kernel<<<dim3((B_ * HID_ + 255) / 256), blk, 0, stream>>>(g2, qenc, hhb);
  gemm_mx<32, 128, 1, 4, false, true, true, 2><<<dim3(NO_P / 128, 1), blk, 0, stream>>>(
      hhb, nullptr, wo1t, nullptr, b_o1, nullptr, h1ob, nullptr, B_, OUT_, HID_, KO2, KO2);
  gemm_mx<32, 128, 1, 4, false, false, true, 0><<<dim3(NO_P / 128, 1), blk, 0, stream>>>(
      h1ob, nullptr, wo2t, nullptr, b_o2, logits, nullptr, nullptr, B_, OUT_, KO2, OUT_, OUT_);
}

// Round 4
// 513.352 us; speedup vs baseline: 2.9153x; 1.1986x over previous
//
#include <hip/hip_runtime.h>
#include <math.h>
#include <stdint.h>

#define B_    32
#define KOBJ  100
#define NS_   16
#define NK_   8
#define EMB_  1024
#define FEAT_ 2052
#define HID_  1024
#define OUT_  3000
#define COMB_ 512

#define KP1   2112   // FEAT_ padded to 64 (image rows / We1a rows)
#define KP2   2048   // 2*HID_
#define NO_P  3072   // OUT_ padded to 128 (N of o1/o2)
#define KO2   3008   // OUT_ padded to 64 (K of o2)

typedef __attribute__((ext_vector_type(8))) short s16x8;
typedef __attribute__((ext_vector_type(4))) float f32x4;

__device__ inline short f2bf(float f) {
  uint32_t u = __builtin_bit_cast(uint32_t, f);
  u = (u + 0x7fff + ((u >> 16) & 1)) >> 16;  // RNE
  return (short)u;
}
__device__ inline float bf2f(short s) {
  uint32_t u = ((uint32_t)(uint16_t)s) << 16;
  return __builtin_bit_cast(float, u);
}
__device__ inline void gload_lds16(const void* g, void* l) {
  __builtin_amdgcn_global_load_lds(
      (const __attribute__((address_space(1))) void*)g,
      (__attribute__((address_space(3))) void*)l, 16, 0, 0);
}
// XCD-aware bijective remap (m204): consecutive wg cluster on one XCD
__device__ inline int xcd_remap(int fid, int nwg) {
  int q = nwg >> 3, r = nwg & 7;
  int x = fid & 7, l = fid >> 3;
  return (x < r ? x * (q + 1) : r * (q + 1) + (x - r) * q) + l;
}

// ---------------- bb centres ----------------
__global__ void centres_kernel(const float* __restrict__ image, float* __restrict__ cent) {
  int i = blockIdx.x * blockDim.x + threadIdx.x;
  if (i >= B_ * KOBJ) return;
  const float* bb = image + (size_t)i * FEAT_ + (FEAT_ - 4);
  cent[i * 2 + 0] = 0.5f * (bb[0] + bb[2]);
  cent[i * 2 + 1] = 0.5f * (bb[1] + bb[3]);
}

// ---------------- f32 -> bf16 row-major convert with K padding (optional hi/lo split) ----
template <bool SPLIT>
__global__ void cvt_pad_rows(const float* __restrict__ in, short* __restrict__ outh,
                             short* __restrict__ outl, int K, int Kp, int total) {
  int idx = blockIdx.x * 256 + threadIdx.x;
  if (idx >= total) return;
  int row = idx / (Kp / 8), c8 = (idx % (Kp / 8)) * 8;
  s16x8 vh, vl;
#pragma unroll
  for (int i = 0; i < 8; ++i) {
    int k = c8 + i;
    float f = (k < K) ? in[(size_t)row * K + k] : 0.f;
    short h = f2bf(f);
    vh[i] = h;
    if (SPLIT) vl[i] = f2bf(f - bf2f(h));
  }
  *(s16x8*)(outh + (size_t)row * Kp + c8) = vh;
  if (SPLIT) *(s16x8*)(outl + (size_t)row * Kp + c8) = vl;
}

// ---------------- transpose-convert weights to Bt[n][kp] bf16 (optional split) ----------
// CONV: in element (k,n) = in[((n/OPM)*K + k)*OPM + (n%OPM)]; else in[k*N + n]
template <bool CONV, bool SPLIT>
__global__ __launch_bounds__(256) void transpose_bf16(
    const float* __restrict__ in, short* __restrict__ outh, short* __restrict__ outl,
    int K, int N, int Kp, int OPM) {
  __shared__ float s[64][65];
  int k0 = blockIdx.x * 64, n0 = blockIdx.y * 64;
  int t = threadIdx.x;
  int r = t >> 2, cb = (t & 3) << 4;
  int kg = k0 + r;
#pragma unroll
  for (int i = 0; i < 16; ++i) {
    int n = n0 + cb + i;
    float v = 0.f;
    if (kg < K && n < N) v = CONV ? in[((size_t)(n / OPM) * K + kg) * OPM + (n % OPM)]
                               : in[(size_t)kg * N + n];
    s[r][cb + i] = v;
  }
  __syncthreads();
  int nl = t >> 2, kc = (t & 3) << 4;
#pragma unroll
  for (int half = 0; half < 2; ++half) {
    s16x8 vh, vl;
#pragma unroll
    for (int i = 0; i < 8; ++i) {
      float f = s[kc + half * 8 + i][nl];
      short h = f2bf(f);
      vh[i] = h;
      if (SPLIT) vl[i] = f2bf(f - bf2f(h));
    }
    short* o = outh + (size_t)(n0 + nl) * Kp + k0 + kc + half * 8;
    *(s16x8*)o = vh;
    if (SPLIT) *(s16x8*)(outl + (size_t)(n0 + nl) * Kp + k0 + kc + half * 8) = vl;
  }
}

// ---------------- unified MFMA GEMM ----------------
// C[M][N] = A[M][Kp] @ Bt[N][Kp]^T, bf16 MFMA, WR x WC waves.
// SPLIT: hi/lo 3-product split-f32. SPLITK: blockIdx.z k-chunks of KS -> f32
// partials in part[z][M][ldc] (bias/relu/omode applied later by reduce_split).
// OMODE: 0=f32, 1=bf16 hi/lo pair, 2=bf16. Writes cols [0,Nw), zero for n>=N.
template <int BM, int BN, int WR, int WC, bool SPLIT, bool RELU, bool BIAS, int OMODE, bool SPLITK>
__global__ __launch_bounds__(WR * WC * 64) void gemm_mx(
    const short* __restrict__ Ah, const short* __restrict__ Al,
    const short* __restrict__ Bh, const short* __restrict__ Bl,
    const float* __restrict__ bias,
    float* __restrict__ Cf, short* __restrict__ Ch, short* __restrict__ Cl,
    float* __restrict__ part, int KS,
    int M, int N, int Kp, int ldc, int Nw) {
  constexpr int NWV = WR * WC;
  constexpr int WM = BM / WR, WN = BN / WC;
  constexpr int FM = WM / 16, FN = WN / 16;
  constexpr int ACH = BM / 8, BCH = BN / 8;
  constexpr int NCH = (ACH + BCH) * (SPLIT ? 2 : 1);
  __shared__ short Ash[BM * 64];
  __shared__ short Bsh[BN * 64];
  __shared__ short Asl[SPLIT ? BM * 64 : 64];
  __shared__ short Bsl[SPLIT ? BN * 64 : 64];
  int tid = threadIdx.x, wave = tid >> 6, lane = tid & 63;
  int wr = wave / WC, wc = wave % WC;
  int r16 = lane & 15, kq = lane >> 4;
  int gx = gridDim.x, gy = gridDim.y, gz = gridDim.z;
  int fid = (blockIdx.z * gy + blockIdx.y) * gx + blockIdx.x;
  int wg = xcd_remap(fid, gx * gy * gz);
  int bx = wg % gx, byz = wg / gx;
  int by = byz % gy, bz = byz / gy;
  int m0 = by * BM, n0 = bx * BN;
  int kb = SPLITK ? bz * KS : 0;
  int ke = SPLITK ? (kb + KS < Kp ? kb + KS : Kp) : Kp;
  f32x4 acc[FM][FN] = {};

  for (int k0 = kb; k0 < ke; k0 += 64) {
    __syncthreads();
    for (int c = wave; c < NCH; c += NWV) {
      int cc = c;
      const short* g;
      char* l;
      bool isA;
      if (cc < ACH) { isA = true; g = Ah; l = (char*)Ash; }
      else if (SPLIT && cc < 2 * ACH) { cc -= ACH; isA = true; g = Al; l = (char*)Asl; }
      else {
        cc -= SPLIT ? 2 * ACH : ACH;
        if (cc < BCH) { isA = false; g = Bh; l = (char*)Bsh; }
        else { cc -= BCH; isA = false; g = Bl; l = (char*)Bsl; }
      }
      int Lb = cc * 1024 + lane * 16;
      int row = Lb >> 7;
      int off = (Lb & 127) ^ ((row & 7) << 4);
      const short* gsrc = g + (size_t)((isA ? m0 : n0) + row) * Kp + k0 + (off >> 1);
      gload_lds16(gsrc, l + cc * 1024);
    }
    __syncthreads();  // compiler drains vmcnt before barrier
#pragma unroll
    for (int kk = 0; kk < 2; ++kk) {
      int woff = kk * 64 + kq * 16;
      s16x8 ah[FM], al[FM], bh[FN], bl[FN];
#pragma unroll
      for (int f = 0; f < FM; ++f) {
        int row = wr * WM + f * 16 + r16;
        int o = woff ^ ((row & 7) << 4);
        ah[f] = *(const s16x8*)((const char*)Ash + row * 128 + o);
        if (SPLIT) al[f] = *(const s16x8*)((const char*)Asl + row * 128 + o);
      }
#pragma unroll
      for (int gg = 0; gg < FN; ++gg) {
        int row = wc * WN + gg * 16 + r16;
        int o = woff ^ ((row & 7) << 4);
        bh[gg] = *(const s16x8*)((const char*)Bsh + row * 128 + o);
        if (SPLIT) bl[gg] = *(const s16x8*)((const char*)Bsl + row * 128 + o);
      }
#pragma unroll
      for (int f = 0; f < FM; ++f)
#pragma unroll
        for (int gg = 0; gg < FN; ++gg) {
          acc[f][gg] = __builtin_amdgcn_mfma_f32_16x16x32_bf16(ah[f], bh[gg], acc[f][gg], 0, 0, 0);
          if (SPLIT) {
            acc[f][gg] = __builtin_amdgcn_mfma_f32_16x16x32_bf16(ah[f], bl[gg], acc[f][gg], 0, 0, 0);
            acc[f][gg] = __builtin_amdgcn_mfma_f32_16x16x32_bf16(al[f], bh[gg], acc[f][gg], 0, 0, 0);
          }
        }
    }
  }
#pragma unroll
  for (int f = 0; f < FM; ++f)
#pragma unroll
    for (int gg = 0; gg < FN; ++gg)
#pragma unroll
      for (int r = 0; r < 4; ++r) {
        int m = m0 + wr * WM + f * 16 + (lane >> 4) * 4 + r;
        int n = n0 + wc * WN + gg * 16 + r16;
        if (m >= M || n >= Nw) continue;
        float v = (n < N) ? acc[f][gg][r] : 0.f;
        size_t idx = (size_t)m * ldc + n;
        if (SPLITK) {
          part[(size_t)bz * M * ldc + idx] = v;
        } else {
          if (BIAS && n < N) v += bias[n];
          if (RELU) v = fmaxf(v, 0.f);
          if (OMODE == 0) Cf[idx] = v;
          else if (OMODE == 1) {
            short h = f2bf(v);
            Ch[idx] = h;
            Cl[idx] = f2bf(v - bf2f(h));
          } else {
            Ch[idx] = f2bf(v);
          }
        }
      }
}

// ---------------- split-K reduce: out = op(sum_z part[z] (+bcast) (+bias)) ----------------
template <int OMODE, bool RELU, bool BIAS, bool BCAST>
__global__ void reduce_split(const float* __restrict__ part, int SK, size_t pstride,
                             const float* __restrict__ bias, const float* __restrict__ bcast,
                             int bcols, float* __restrict__ Cf, short* __restrict__ Ch,
                             short* __restrict__ Cl, int M, int N, int ldIn, int ldOut) {
  int idx = blockIdx.x * 256 + threadIdx.x;
  if (idx >= M * ldIn) return;
  int m = idx / ldIn, n = idx - m * ldIn;
  if (n >= ldOut) return;
  float v = 0.f;
  for (int s = 0; s < SK; ++s) v += part[(size_t)s * pstride + idx];
  if (n < N) {
    if (BCAST) v += bcast[(size_t)(m / KOBJ) * bcols + n];
    if (BIAS) v += bias[n];
  }
  if (RELU) v = fmaxf(v, 0.f);
  size_t o = (size_t)m * ldOut + n;
  if (OMODE == 0) Cf[o] = v;
  else if (OMODE == 1) {
    short h = f2bf(v);
    Ch[o] = h;
    Cl[o] = f2bf(v - bf2f(h));
  } else {
    Ch[o] = f2bf(v);
  }
}

// ---------------- adj = h2 @ h2^T per batch (f32) ----------------
__global__ __launch_bounds__(256) void adj_kernel(const float* __restrict__ h2,
                                                  float* __restrict__ adj) {
  __shared__ float Rk[16][COMB_ + 1];
  __shared__ float Rl[16][COMB_ + 1];
  int b = blockIdx.z, k0 = blockIdx.y * 16, l0 = blockIdx.x * 16;
  int tid = threadIdx.y * 16 + threadIdx.x;
  for (int e = tid; e < 16 * COMB_; e += 256) {
    int r = e >> 9, f = e & (COMB_ - 1);
    Rk[r][f] = (k0 + r < KOBJ) ? h2[((size_t)b * KOBJ + k0 + r) * COMB_ + f] : 0.f;
    Rl[r][f] = (l0 + r < KOBJ) ? h2[((size_t)b * KOBJ + l0 + r) * COMB_ + f] : 0.f;
  }
  __syncthreads();
  int i = threadIdx.y, j = threadIdx.x;
  float acc = 0.f;
  for (int f = 0; f < COMB_; ++f) acc = fmaf(Rk[i][f], Rl[j][f], acc);
  int kg = k0 + i, lg = l0 + j;
  if (kg < KOBJ && lg < KOBJ) adj[((size_t)b * KOBJ + kg) * KOBJ + lg] = acc;
}

// ---------------- top-k + softmax + gaussian kernel weights ----------------
__global__ __launch_bounds__(256) void topk_weights_kernel(
    const float* __restrict__ adj, const float* __restrict__ cent,
    const float* __restrict__ mr1, const float* __restrict__ mt1,
    const float* __restrict__ pr1, const float* __restrict__ pt1,
    const float* __restrict__ mr2, const float* __restrict__ mt2,
    const float* __restrict__ pr2, const float* __restrict__ pt2,
    int* __restrict__ topi, float* __restrict__ c1, float* __restrict__ c2) {
  int row = blockIdx.x * 4 + (threadIdx.x >> 6);
  int lane = threadIdx.x & 63;
  int b = row / KOBJ, k = row % KOBJ;
  const float* ar = adj + (size_t)row * KOBJ;
  float v0 = (lane < KOBJ) ? ar[lane] : -INFINITY;
  float v1 = (lane + 64 < KOBJ) ? ar[lane + 64] : -INFINITY;
  int i0 = lane, i1 = lane + 64;
  float tv[NS_];
  int ti[NS_];
#pragma unroll
  for (int s = 0; s < NS_; ++s) {
    bool p0 = (v0 > v1) || (v0 == v1 && i0 < i1);
    float bv = p0 ? v0 : v1;
    int bi = p0 ? i0 : i1;
#pragma unroll
    for (int off = 32; off > 0; off >>= 1) {
      float ov = __shfl_xor(bv, off);
      int oi = __shfl_xor(bi, off);
      if (ov > bv || (ov == bv && oi < bi)) { bv = ov; bi = oi; }
    }
    tv[s] = bv; ti[s] = bi;
    if (bi == i0) v0 = -INFINITY;
    if (bi == i1) v1 = -INFINITY;
  }
  float mx = tv[0], sum = 0.f, av[NS_];
#pragma unroll
  for (int s = 0; s < NS_; ++s) { av[s] = expf(tv[s] - mx); sum += av[s]; }
  if (lane < NS_) {
    int j = ti[lane];
    topi[(size_t)row * NS_ + lane] = j;
    float cx = cent[(b * KOBJ + k) * 2 + 0], cy = cent[(b * KOBJ + k) * 2 + 1];
    float dx = cx - cent[(b * KOBJ + j) * 2 + 0];
    float dy = cy - cent[(b * KOBJ + j) * 2 + 1];
    float rho = sqrtf(dx * dx + dy * dy);
    float th = atan2f(dx, dy);
    float w1[NK_], w2[NK_], s1 = 0.f, s2 = 0.f;
#pragma unroll
    for (int m = 0; m < NK_; ++m) {
      {
        float pr = pr1[m], pt = pt1[m], dr = rho - mr1[m];
        float wr = expf(-0.5f * dr * dr / (1e-14f + pr * pr));
        float fa = fabsf(th - mt1[m]);
        float sa = fabsf(6.283185307179586f - fa);
        float da = fminf(fa, sa);
        float wt = expf(-0.5f * da * da / (1e-14f + pt * pt));
        float w = wr * wt;
        if (w != w) w = 0.f;
        w1[m] = w; s1 += w;
      }
      {
        float pr = pr2[m], pt = pt2[m], dr = rho - mr2[m];
        float wr = expf(-0.5f * dr * dr / (1e-14f + pr * pr));
        float fa = fabsf(th - mt2[m]);
        float sa = fabsf(6.283185307179586f - fa);
        float da = fminf(fa, sa);
        float wt = expf(-0.5f * da * da / (1e-14f + pt * pt));
        float w = wr * wt;
        if (w != w) w = 0.f;
        w2[m] = w; s2 += w;
      }
    }
    float as = av[lane] / sum;
#pragma unroll
    for (int m = 0; m < NK_; ++m) {
      c1[((size_t)row * NS_ + lane) * NK_ + m] = as * (w1[m] / s1);
      c2[((size_t)row * NS_ + lane) * NK_ + m] = w2[m] / s2;
    }
  }
}

// ---------------- gather-combine (bf16 proj in) ----------------
template <bool BF16OUT>
__global__ __launch_bounds__(256) void combine_kernel(
    const short* __restrict__ proj, const float* __restrict__ coeff,
    const int* __restrict__ topi, float* __restrict__ outf, short* __restrict__ outb,
    int N, int mshift) {
  int gx = gridDim.x;
  int fid = blockIdx.y * gx + blockIdx.x;
  int wg = xcd_remap(fid, gx * (int)gridDim.y);
  int nb = wg % gx, row = wg / gx;
  int b = row / KOBJ;
  __shared__ int ids[NS_];
  __shared__ float cs[NS_ * NK_];
  int tid = threadIdx.x;
  if (tid < NS_) ids[tid] = topi[(size_t)row * NS_ + tid];
  else if (tid >= 32 && tid < 32 + NS_ * NK_) cs[tid - 32] = coeff[(size_t)row * NS_ * NK_ + (tid - 32)];
  __syncthreads();
  int n = nb * 256 + tid;
  if (n >= N) return;
  int m = n >> mshift;
  float acc = 0.f;
#pragma unroll
  for (int s = 0; s < NS_; ++s)
    acc = fmaf(cs[s * NK_ + m], bf2f(proj[((size_t)b * KOBJ + ids[s]) * N + n]), acc);
  acc = fmaxf(acc, 0.f);
  if (BF16OUT) outb[(size_t)row * N + n] = f2bf(acc);
  else         outf[(size_t)row * N + n] = acc;
}

// ---------------- max over k, then hh = relu(qenc) * g2max (bf16 out) ----------------
__global__ void reduce_hh_kernel(const float* __restrict__ g2, const float* __restrict__ qenc,
                                 short* __restrict__ hhb) {
  int i = blockIdx.x * blockDim.x + threadIdx.x;
  if (i >= B_ * HID_) return;
  int b = i >> 10, n = i & (HID_ - 1);
  const float* p = g2 + (size_t)b * KOBJ * HID_ + n;
  float mx = -INFINITY;
  for (int k = 0; k < KOBJ; ++k) mx = fmaxf(mx, p[(size_t)k * HID_]);
  hhb[i] = f2bf(fmaxf(qenc[i], 0.f) * mx);
}

extern "C" void kernel_launch(void* const* d_in, const int* in_sizes, int n_in,
                              void* d_out, int out_size, void* d_ws, size_t ws_size,
                              hipStream_t stream) {
  const float* question = (const float*)d_in[0];
  const float* image    = (const float*)d_in[1];
  const float* W_lproj  = (const float*)d_in[3];
  const float* b_lproj  = (const float*)d_in[4];
  const float* W_e1     = (const float*)d_in[5];
  const float* b_e1     = (const float*)d_in[6];
  const float* W_e2     = (const float*)d_in[7];
  const float* b_e2     = (const float*)d_in[8];
  const float* conv_w1  = (const float*)d_in[9];
  const float* mr1 = (const float*)d_in[10];
  const float* mt1 = (const float*)d_in[11];
  const float* pr1 = (const float*)d_in[12];
  const float* pt1 = (const float*)d_in[13];
  const float* conv_w2  = (const float*)d_in[14];
  const float* mr2 = (const float*)d_in[15];
  const float* mt2 = (const float*)d_in[16];
  const float* pr2 = (const float*)d_in[17];
  const float* pt2 = (const float*)d_in[18];
  const float* W_o1 = (const float*)d_in[19];
  const float* b_o1 = (const float*)d_in[20];
  const float* W_o2 = (const float*)d_in[21];
  const float* b_o2 = (const float*)d_in[22];

  float* out = (float*)d_out;
  float* logits = out;               // [32,3000]
  float* adj = out + B_ * OUT_;      // [32,100,100]

  char* ws = (char*)d_ws;
  size_t off = 0;
  auto alloc = [&](size_t bytes) { char* p = ws + off; off += (bytes + 255) & ~((size_t)255); return p; };
  float* qenc  = (float*)alloc((size_t)B_ * HID_ * 4);
  short* qh    = (short*)alloc((size_t)B_ * EMB_ * 2);
  short* ql    = (short*)alloc((size_t)B_ * EMB_ * 2);
  short* qeh   = (short*)alloc((size_t)B_ * HID_ * 2);
  short* qel   = (short*)alloc((size_t)B_ * HID_ * 2);
  short* wlph  = (short*)alloc((size_t)EMB_ * HID_ * 2);
  short* wlpl  = (short*)alloc((size_t)EMB_ * HID_ * 2);
  short* we1ah = (short*)alloc((size_t)COMB_ * KP1 * 2);
  short* we1al = (short*)alloc((size_t)COMB_ * KP1 * 2);
  short* we1bh = (short*)alloc((size_t)COMB_ * HID_ * 2);
  short* we1bl = (short*)alloc((size_t)COMB_ * HID_ * 2);
  short* we2h  = (short*)alloc((size_t)COMB_ * COMB_ * 2);
  short* we2l  = (short*)alloc((size_t)COMB_ * COMB_ * 2);
  float* q1    = (float*)alloc((size_t)B_ * COMB_ * 4);
  short* h1h   = (short*)alloc((size_t)B_ * KOBJ * COMB_ * 2);
  short* h1l   = (short*)alloc((size_t)B_ * KOBJ * COMB_ * 2);
  float* h2    = (float*)alloc((size_t)B_ * KOBJ * COMB_ * 4);
  float* cent  = (float*)alloc((size_t)B_ * KOBJ * 2 * 4);
  int*   topi  = (int*)alloc((size_t)B_ * KOBJ * NS_ * 4);
  float* c1    = (float*)alloc((size_t)B_ * KOBJ * NS_ * NK_ * 4);
  float* c2    = (float*)alloc((size_t)B_ * KOBJ * NS_ * NK_ * 4);
  short* imgb  = (short*)alloc((size_t)B_ * KOBJ * KP1 * 2);
  short* imgl  = (short*)alloc((size_t)B_ * KOBJ * KP1 * 2);
  short* cw1t  = (short*)alloc((size_t)(2 * HID_) * KP1 * 2);
  short* cw2t  = (short*)alloc((size_t)HID_ * KP2 * 2);
  short* proj1b = (short*)alloc((size_t)B_ * KOBJ * 2 * HID_ * 2);
  short* g1b   = (short*)alloc((size_t)B_ * KOBJ * KP2 * 2);
  short* proj2b = (short*)alloc((size_t)B_ * KOBJ * HID_ * 2);
  float* g2    = (float*)alloc((size_t)B_ * KOBJ * HID_ * 4);
  short* hhb   = (short*)alloc((size_t)B_ * HID_ * 2);
  short* wo1t  = (short*)alloc((size_t)NO_P * HID_ * 2);
  short* wo2t  = (short*)alloc((size_t)NO_P * KO2 * 2);
  short* h1ob  = (short*)alloc((size_t)B_ * KO2 * 2);
  float* partE = (float*)alloc((size_t)4 * B_ * KOBJ * COMB_ * 4);  // 26.2 MB, max over users
  (void)ws_size; (void)in_sizes; (void)n_in; (void)out_size;

  dim3 blk(256), blk512(512);

  // ---- independent prep ----
  centres_kernel<<<dim3((B_ * KOBJ + 255) / 256), blk, 0, stream>>>(image, cent);
  {
    int total = B_ * KOBJ * (KP1 / 8);
    cvt_pad_rows<true><<<dim3((total + 255) / 256), blk, 0, stream>>>(image, imgb, imgl, FEAT_, KP1, total);
  }
  {
    int total = B_ * (EMB_ / 8);
    cvt_pad_rows<true><<<dim3((total + 255) / 256), blk, 0, stream>>>(question, qh, ql, EMB_, EMB_, total);
  }
  transpose_bf16<false, true><<<dim3(EMB_ / 64, HID_ / 64), blk, 0, stream>>>(
      W_lproj, wlph, wlpl, EMB_, HID_, EMB_, 0);
  transpose_bf16<false, true><<<dim3(KP1 / 64, COMB_ / 64), blk, 0, stream>>>(
      W_e1, we1ah, we1al, FEAT_, COMB_, KP1, 0);
  transpose_bf16<false, true><<<dim3(HID_ / 64, COMB_ / 64), blk, 0, stream>>>(
      W_e1 + (size_t)FEAT_ * COMB_, we1bh, we1bl, HID_, COMB_, HID_, 0);
  transpose_bf16<false, true><<<dim3(COMB_ / 64, COMB_ / 64), blk, 0, stream>>>(
      W_e2, we2h, we2l, COMB_, COMB_, COMB_, 0);
  transpose_bf16<true, false><<<dim3(KP1 / 64, (2 * HID_) / 64), blk, 0, stream>>>(
      conv_w1, cw1t, nullptr, FEAT_, 2 * HID_, KP1, 2 * HID_ / NK_);
  transpose_bf16<true, false><<<dim3(KP2 / 64, HID_ / 64), blk, 0, stream>>>(
      conv_w2, cw2t, nullptr, 2 * HID_, HID_, KP2, HID_ / NK_);
  transpose_bf16<false, false><<<dim3(HID_ / 64, NO_P / 64), blk, 0, stream>>>(
      W_o1, wo1t, nullptr, HID_, OUT_, HID_, 0);
  transpose_bf16<false, false><<<dim3(KO2 / 64, NO_P / 64), blk, 0, stream>>>(
      W_o2, wo2t, nullptr, OUT_, OUT_, KO2, 0);

  // ---- qenc = question @ W_lproj + b (split, f32) ----
  gemm_mx<32, 64, 2, 2, true, false, true, 0, false><<<dim3(HID_ / 64, 1, 1), blk, 0, stream>>>(
      qh, ql, wlph, wlpl, b_lproj, qenc, nullptr, nullptr, nullptr, 0, B_, HID_, EMB_, HID_, HID_);
  // ---- split qenc for q1 ----
  {
    int total = B_ * (HID_ / 8);
    cvt_pad_rows<true><<<dim3((total + 255) / 256), blk, 0, stream>>>(qenc, qeh, qel, HID_, HID_, total);
  }
  // ---- q1 = qenc @ We1[2052:] (split, no bias) ----
  gemm_mx<32, 64, 2, 2, true, false, false, 0, false><<<dim3(COMB_ / 64, 1, 1), blk, 0, stream>>>(
      qeh, qel, we1bh, we1bl, nullptr, q1, nullptr, nullptr, nullptr, 0, B_, COMB_, HID_, COMB_, COMB_);
  // ---- e1 image part: split-K partials (z=4, KS=576) ----
  gemm_mx<128, 64, 4, 2, true, false, false, 0, true><<<dim3(COMB_ / 64, B_ * KOBJ / 128, 4), blk512, 0, stream>>>(
      imgb, imgl, we1ah, we1al, nullptr, nullptr, nullptr, nullptr, partE, 576,
      B_ * KOBJ, COMB_, KP1, COMB_, COMB_);
  // ---- h1 = relu(sum + q1[bcast] + b_e1), bf16 hi/lo ----
  reduce_split<1, true, true, true><<<dim3(B_ * KOBJ * COMB_ / 256), blk, 0, stream>>>(
      partE, 4, (size_t)B_ * KOBJ * COMB_, b_e1, q1, COMB_, nullptr, h1h, h1l,
      B_ * KOBJ, COMB_, COMB_, COMB_);
  // ---- e2: split-K partials (z=2, KS=256) ----
  gemm_mx<128, 64, 4, 2, true, false, false, 0, true><<<dim3(COMB_ / 64, B_ * KOBJ / 128, 2), blk512, 0, stream>>>(
      h1h, h1l, we2h, we2l, nullptr, nullptr, nullptr, nullptr, partE, 256,
      B_ * KOBJ, COMB_, COMB_, COMB_, COMB_);
  reduce_split<0, true, true, false><<<dim3(B_ * KOBJ * COMB_ / 256), blk, 0, stream>>>(
      partE, 2, (size_t)B_ * KOBJ * COMB_, b_e2, nullptr, 0, h2, nullptr, nullptr,
      B_ * KOBJ, COMB_, COMB_, COMB_);
  // ---- adj + topk ----
  adj_kernel<<<dim3(7, 7, B_), dim3(16, 16), 0, stream>>>(h2, adj);
  topk_weights_kernel<<<dim3(B_ * KOBJ / 4), blk, 0, stream>>>(
      adj, cent, mr1, mt1, pr1, pt1, mr2, mt2, pr2, pt2, topi, c1, c2);
  // ---- conv path ----
  gemm_mx<128, 128, 2, 4, false, false, false, 2, false><<<dim3(2 * HID_ / 128, B_ * KOBJ / 128, 1), blk512, 0, stream>>>(
      imgb, nullptr, cw1t, nullptr, nullptr, nullptr, proj1b, nullptr, nullptr, 0,
      B_ * KOBJ, 2 * HID_, KP1, 2 * HID_, 2 * HID_);
  combine_kernel<true><<<dim3(2 * HID_ / 256, B_ * KOBJ), blk, 0, stream>>>(
      proj1b, c1, topi, nullptr, g1b, 2 * HID_, 8);
  gemm_mx<128, 64, 2, 4, false, false, false, 2, false><<<dim3(HID_ / 64, B_ * KOBJ / 128, 1), blk512, 0, stream>>>(
      g1b, nullptr, cw2t, nullptr, nullptr, nullptr, proj2b, nullptr, nullptr, 0,
      B_ * KOBJ, HID_, KP2, HID_, HID_);
  combine_kernel<false><<<dim3(HID_ / 256, B_ * KOBJ), blk, 0, stream>>>(
      proj2b, c2, topi, g2, nullptr, HID_, 7);
  // ---- tail ----
  reduce_hh_kernel<<<dim3((B_ * HID_ + 255) / 256), blk, 0, stream>>>(g2, qenc, hhb);
  // o1: split-K z=8, KS=128
  gemm_mx<32, 128, 1, 4, false, false, false, 0, true><<<dim3(NO_P / 128, 1, 8), blk, 0, stream>>>(
      hhb, nullptr, wo1t, nullptr, nullptr, nullptr, nullptr, nullptr, partE, 128,
      B_, OUT_, HID_, KO2, KO2);
  reduce_split<2, true, true, false><<<dim3((B_ * KO2 + 255) / 256), blk, 0, stream>>>(
      partE, 8, (size_t)B_ * KO2, b_o1, nullptr, 0, nullptr, h1ob, nullptr,
      B_, OUT_, KO2, KO2);
  // o2: split-K z=8, KS=384
  gemm_mx<32, 128, 1, 4, false, false, false, 0, true><<<dim3(NO_P / 128, 1, 8), blk, 0, stream>>>(
      h1ob, nullptr, wo2t, nullptr, nullptr, nullptr, nullptr, nullptr, partE, 384,
      B_, OUT_, KO2, KO2, KO2);
  reduce_split<0, false, true, false><<<dim3((B_ * KO2 + 255) / 256), blk, 0, stream>>>(
      partE, 8, (size_t)B_ * KO2, b_o2, nullptr, 0, logits, nullptr, nullptr,
      B_, OUT_, KO2, OUT_);
}

// Round 5
// 451.421 us; speedup vs baseline: 3.3153x; 1.1372x over previous
//
#include <hip/hip_runtime.h>
#include <math.h>
#include <stdint.h>

#define B_    32
#define KOBJ  100
#define NS_   16
#define NK_   8
#define EMB_  1024
#define FEAT_ 2052
#define HID_  1024
#define OUT_  3000
#define COMB_ 512

#define KP1   2112   // FEAT_ padded to 64 (image rows / We1a rows)
#define KP2   2048   // 2*HID_
#define NO_P  3072   // OUT_ padded to 128 (N of o1/o2)
#define KO2   3008   // OUT_ padded to 64 (K of o2)

typedef __attribute__((ext_vector_type(8))) short s16x8;
typedef __attribute__((ext_vector_type(4))) float f32x4;

__device__ inline short f2bf(float f) {
  uint32_t u = __builtin_bit_cast(uint32_t, f);
  u = (u + 0x7fff + ((u >> 16) & 1)) >> 16;  // RNE
  return (short)u;
}
__device__ inline float bf2f(short s) {
  uint32_t u = ((uint32_t)(uint16_t)s) << 16;
  return __builtin_bit_cast(float, u);
}
__device__ inline void gload_lds16(const void* g, void* l) {
  __builtin_amdgcn_global_load_lds(
      (const __attribute__((address_space(1))) void*)g,
      (__attribute__((address_space(3))) void*)l, 16, 0, 0);
}
// XCD-aware bijective remap (m204): consecutive wg cluster on one XCD
__device__ inline int xcd_remap(int fid, int nwg) {
  int q = nwg >> 3, r = nwg & 7;
  int x = fid & 7, l = fid >> 3;
  return (x < r ? x * (q + 1) : r * (q + 1) + (x - r) * q) + l;
}

// ---------------- bb centres ----------------
__global__ void centres_kernel(const float* __restrict__ image, float* __restrict__ cent) {
  int i = blockIdx.x * blockDim.x + threadIdx.x;
  if (i >= B_ * KOBJ) return;
  const float* bb = image + (size_t)i * FEAT_ + (FEAT_ - 4);
  cent[i * 2 + 0] = 0.5f * (bb[0] + bb[2]);
  cent[i * 2 + 1] = 0.5f * (bb[1] + bb[3]);
}

// ---------------- f32 -> bf16 row-major convert with K padding (optional hi/lo split) ----
template <bool SPLIT>
__global__ void cvt_pad_rows(const float* __restrict__ in, short* __restrict__ outh,
                             short* __restrict__ outl, int K, int Kp, int total) {
  int idx = blockIdx.x * 256 + threadIdx.x;
  if (idx >= total) return;
  int row = idx / (Kp / 8), c8 = (idx % (Kp / 8)) * 8;
  s16x8 vh, vl;
#pragma unroll
  for (int i = 0; i < 8; ++i) {
    int k = c8 + i;
    float f = (k < K) ? in[(size_t)row * K + k] : 0.f;
    short h = f2bf(f);
    vh[i] = h;
    if (SPLIT) vl[i] = f2bf(f - bf2f(h));
  }
  *(s16x8*)(outh + (size_t)row * Kp + c8) = vh;
  if (SPLIT) *(s16x8*)(outl + (size_t)row * Kp + c8) = vl;
}

// ---------------- transpose-convert weights to Bt[n][kp] bf16 (optional split) ----------
// CONV: in element (k,n) = in[((n/OPM)*K + k)*OPM + (n%OPM)]; else in[k*N + n]
template <bool CONV, bool SPLIT>
__global__ __launch_bounds__(256) void transpose_bf16(
    const float* __restrict__ in, short* __restrict__ outh, short* __restrict__ outl,
    int K, int N, int Kp, int OPM) {
  __shared__ float s[64][65];
  int k0 = blockIdx.x * 64, n0 = blockIdx.y * 64;
  int t = threadIdx.x;
  int r = t >> 2, cb = (t & 3) << 4;
  int kg = k0 + r;
#pragma unroll
  for (int i = 0; i < 16; ++i) {
    int n = n0 + cb + i;
    float v = 0.f;
    if (kg < K && n < N) v = CONV ? in[((size_t)(n / OPM) * K + kg) * OPM + (n % OPM)]
                               : in[(size_t)kg * N + n];
    s[r][cb + i] = v;
  }
  __syncthreads();
  int nl = t >> 2, kc = (t & 3) << 4;
#pragma unroll
  for (int half = 0; half < 2; ++half) {
    s16x8 vh, vl;
#pragma unroll
    for (int i = 0; i < 8; ++i) {
      float f = s[kc + half * 8 + i][nl];
      short h = f2bf(f);
      vh[i] = h;
      if (SPLIT) vl[i] = f2bf(f - bf2f(h));
    }
    short* o = outh + (size_t)(n0 + nl) * Kp + k0 + kc + half * 8;
    *(s16x8*)o = vh;
    if (SPLIT) *(s16x8*)(outl + (size_t)(n0 + nl) * Kp + k0 + kc + half * 8) = vl;
  }
}

// ---------------- unified MFMA GEMM ----------------
// C[M][N] = A[M][Kp] @ Bt[N][Kp]^T, bf16 MFMA, WR x WC waves.
// SPLIT: hi/lo 3-product split-f32. SPLITK: blockIdx.z k-chunks of KS -> f32
// partials in part[z][M][ldc] (bias/relu/omode applied later by reduce_split).
// OMODE: 0=f32, 1=bf16 hi/lo pair, 2=bf16. Writes cols [0,Nw), zero for n>=N.
template <int BM, int BN, int WR, int WC, bool SPLIT, bool RELU, bool BIAS, int OMODE, bool SPLITK>
__global__ __launch_bounds__(WR * WC * 64) void gemm_mx(
    const short* __restrict__ Ah, const short* __restrict__ Al,
    const short* __restrict__ Bh, const short* __restrict__ Bl,
    const float* __restrict__ bias,
    float* __restrict__ Cf, short* __restrict__ Ch, short* __restrict__ Cl,
    float* __restrict__ part, int KS,
    int M, int N, int Kp, int ldc, int Nw) {
  constexpr int NWV = WR * WC;
  constexpr int WM = BM / WR, WN = BN / WC;
  constexpr int FM = WM / 16, FN = WN / 16;
  constexpr int ACH = BM / 8, BCH = BN / 8;
  constexpr int NCH = (ACH + BCH) * (SPLIT ? 2 : 1);
  __shared__ short Ash[BM * 64];
  __shared__ short Bsh[BN * 64];
  __shared__ short Asl[SPLIT ? BM * 64 : 64];
  __shared__ short Bsl[SPLIT ? BN * 64 : 64];
  int tid = threadIdx.x, wave = tid >> 6, lane = tid & 63;
  int wr = wave / WC, wc = wave % WC;
  int r16 = lane & 15, kq = lane >> 4;
  int gx = gridDim.x, gy = gridDim.y, gz = gridDim.z;
  int fid = (blockIdx.z * gy + blockIdx.y) * gx + blockIdx.x;
  int wg = xcd_remap(fid, gx * gy * gz);
  int bx = wg % gx, byz = wg / gx;
  int by = byz % gy, bz = byz / gy;
  int m0 = by * BM, n0 = bx * BN;
  int kb = SPLITK ? bz * KS : 0;
  int ke = SPLITK ? (kb + KS < Kp ? kb + KS : Kp) : Kp;
  f32x4 acc[FM][FN] = {};

  for (int k0 = kb; k0 < ke; k0 += 64) {
    __syncthreads();
    for (int c = wave; c < NCH; c += NWV) {
      int cc = c;
      const short* g;
      char* l;
      bool isA;
      if (cc < ACH) { isA = true; g = Ah; l = (char*)Ash; }
      else if (SPLIT && cc < 2 * ACH) { cc -= ACH; isA = true; g = Al; l = (char*)Asl; }
      else {
        cc -= SPLIT ? 2 * ACH : ACH;
        if (cc < BCH) { isA = false; g = Bh; l = (char*)Bsh; }
        else { cc -= BCH; isA = false; g = Bl; l = (char*)Bsl; }
      }
      int Lb = cc * 1024 + lane * 16;
      int row = Lb >> 7;
      int off = (Lb & 127) ^ ((row & 7) << 4);
      const short* gsrc = g + (size_t)((isA ? m0 : n0) + row) * Kp + k0 + (off >> 1);
      gload_lds16(gsrc, l + cc * 1024);
    }
    __syncthreads();  // compiler drains vmcnt before barrier
#pragma unroll
    for (int kk = 0; kk < 2; ++kk) {
      int woff = kk * 64 + kq * 16;
      s16x8 ah[FM], al[FM], bh[FN], bl[FN];
#pragma unroll
      for (int f = 0; f < FM; ++f) {
        int row = wr * WM + f * 16 + r16;
        int o = woff ^ ((row & 7) << 4);
        ah[f] = *(const s16x8*)((const char*)Ash + row * 128 + o);
        if (SPLIT) al[f] = *(const s16x8*)((const char*)Asl + row * 128 + o);
      }
#pragma unroll
      for (int gg = 0; gg < FN; ++gg) {
        int row = wc * WN + gg * 16 + r16;
        int o = woff ^ ((row & 7) << 4);
        bh[gg] = *(const s16x8*)((const char*)Bsh + row * 128 + o);
        if (SPLIT) bl[gg] = *(const s16x8*)((const char*)Bsl + row * 128 + o);
      }
#pragma unroll
      for (int f = 0; f < FM; ++f)
#pragma unroll
        for (int gg = 0; gg < FN; ++gg) {
          acc[f][gg] = __builtin_amdgcn_mfma_f32_16x16x32_bf16(ah[f], bh[gg], acc[f][gg], 0, 0, 0);
          if (SPLIT) {
            acc[f][gg] = __builtin_amdgcn_mfma_f32_16x16x32_bf16(ah[f], bl[gg], acc[f][gg], 0, 0, 0);
            acc[f][gg] = __builtin_amdgcn_mfma_f32_16x16x32_bf16(al[f], bh[gg], acc[f][gg], 0, 0, 0);
          }
        }
    }
  }
#pragma unroll
  for (int f = 0; f < FM; ++f)
#pragma unroll
    for (int gg = 0; gg < FN; ++gg)
#pragma unroll
      for (int r = 0; r < 4; ++r) {
        int m = m0 + wr * WM + f * 16 + (lane >> 4) * 4 + r;
        int n = n0 + wc * WN + gg * 16 + r16;
        if (m >= M || n >= Nw) continue;
        float v = (n < N) ? acc[f][gg][r] : 0.f;
        size_t idx = (size_t)m * ldc + n;
        if (SPLITK) {
          part[(size_t)bz * M * ldc + idx] = v;
        } else {
          if (BIAS && n < N) v += bias[n];
          if (RELU) v = fmaxf(v, 0.f);
          if (OMODE == 0) Cf[idx] = v;
          else if (OMODE == 1) {
            short h = f2bf(v);
            Ch[idx] = h;
            Cl[idx] = f2bf(v - bf2f(h));
          } else {
            Ch[idx] = f2bf(v);
          }
        }
      }
}

// ---------------- split-K reduce: out = op(sum_z part[z] (+bcast) (+bias)) ----------------
template <int OMODE, bool RELU, bool BIAS, bool BCAST>
__global__ void reduce_split(const float* __restrict__ part, int SK, size_t pstride,
                             const float* __restrict__ bias, const float* __restrict__ bcast,
                             int bcols, float* __restrict__ Cf, short* __restrict__ Ch,
                             short* __restrict__ Cl, int M, int N, int ldIn, int ldOut) {
  int idx = blockIdx.x * 256 + threadIdx.x;
  if (idx >= M * ldIn) return;
  int m = idx / ldIn, n = idx - m * ldIn;
  if (n >= ldOut) return;
  float v = 0.f;
  for (int s = 0; s < SK; ++s) v += part[(size_t)s * pstride + idx];
  if (n < N) {
    if (BCAST) v += bcast[(size_t)(m / KOBJ) * bcols + n];
    if (BIAS) v += bias[n];
  }
  if (RELU) v = fmaxf(v, 0.f);
  size_t o = (size_t)m * ldOut + n;
  if (OMODE == 0) Cf[o] = v;
  else if (OMODE == 1) {
    short h = f2bf(v);
    Ch[o] = h;
    Cl[o] = f2bf(v - bf2f(h));
  } else {
    Ch[o] = f2bf(v);
  }
}

// ---------------- adj[b] = h2[b] @ h2[b]^T, split-bf16 MFMA, one block/batch ----------------
// 8 waves (2x4), BM=BN=128 (covers 100), BK=64. A==B -> stage once (hi+lo = 32 KB).
// Rows 100..127 read into the next batch's data (alloc padded at the end); they only
// feed acc elements with m>=100 or n>=100, which are never written.
__global__ __launch_bounds__(512) void adj_mfma(const short* __restrict__ Hh,
                                                const short* __restrict__ Hl,
                                                float* __restrict__ adj) {
  __shared__ short Ash[128 * 64];
  __shared__ short Asl[128 * 64];
  int tid = threadIdx.x, wave = tid >> 6, lane = tid & 63;
  int wr = wave >> 2, wc = wave & 3;        // 2x4 wave grid: WM=64, WN=32
  int r16 = lane & 15, kq = lane >> 4;
  int b = blockIdx.x;
  const short* baseh = Hh + (size_t)b * KOBJ * COMB_;
  const short* basel = Hl + (size_t)b * KOBJ * COMB_;
  f32x4 acc[4][2] = {};
  for (int k0 = 0; k0 < COMB_; k0 += 64) {
    __syncthreads();
    for (int c = wave; c < 32; c += 8) {    // 16 hi chunks + 16 lo chunks, 1 KB each
      int cc = c & 15;
      bool hi = c < 16;
      int Lb = cc * 1024 + lane * 16;
      int row = Lb >> 7;
      int off = (Lb & 127) ^ ((row & 7) << 4);
      const short* gsrc = (hi ? baseh : basel) + (size_t)row * COMB_ + k0 + (off >> 1);
      gload_lds16(gsrc, (char*)(hi ? Ash : Asl) + cc * 1024);
    }
    __syncthreads();
#pragma unroll
    for (int kk = 0; kk < 2; ++kk) {
      int woff = kk * 64 + kq * 16;
      s16x8 ah[4], al[4], bh[2], bl[2];
#pragma unroll
      for (int f = 0; f < 4; ++f) {
        int row = wr * 64 + f * 16 + r16;
        int o = woff ^ ((row & 7) << 4);
        ah[f] = *(const s16x8*)((const char*)Ash + row * 128 + o);
        al[f] = *(const s16x8*)((const char*)Asl + row * 128 + o);
      }
#pragma unroll
      for (int g = 0; g < 2; ++g) {
        int row = wc * 32 + g * 16 + r16;
        int o = woff ^ ((row & 7) << 4);
        bh[g] = *(const s16x8*)((const char*)Ash + row * 128 + o);
        bl[g] = *(const s16x8*)((const char*)Asl + row * 128 + o);
      }
#pragma unroll
      for (int f = 0; f < 4; ++f)
#pragma unroll
        for (int g = 0; g < 2; ++g) {
          acc[f][g] = __builtin_amdgcn_mfma_f32_16x16x32_bf16(ah[f], bh[g], acc[f][g], 0, 0, 0);
          acc[f][g] = __builtin_amdgcn_mfma_f32_16x16x32_bf16(ah[f], bl[g], acc[f][g], 0, 0, 0);
          acc[f][g] = __builtin_amdgcn_mfma_f32_16x16x32_bf16(al[f], bh[g], acc[f][g], 0, 0, 0);
        }
    }
  }
#pragma unroll
  for (int f = 0; f < 4; ++f)
#pragma unroll
    for (int g = 0; g < 2; ++g)
#pragma unroll
      for (int r = 0; r < 4; ++r) {
        int m = wr * 64 + f * 16 + (lane >> 4) * 4 + r;
        int n = wc * 32 + g * 16 + r16;
        if (m < KOBJ && n < KOBJ)
          adj[((size_t)b * KOBJ + m) * KOBJ + n] = acc[f][g][r];
      }
}

// ---------------- top-k + softmax + gaussian kernel weights ----------------
__global__ __launch_bounds__(256) void topk_weights_kernel(
    const float* __restrict__ adj, const float* __restrict__ cent,
    const float* __restrict__ mr1, const float* __restrict__ mt1,
    const float* __restrict__ pr1, const float* __restrict__ pt1,
    const float* __restrict__ mr2, const float* __restrict__ mt2,
    const float* __restrict__ pr2, const float* __restrict__ pt2,
    int* __restrict__ topi, float* __restrict__ c1, float* __restrict__ c2) {
  int row = blockIdx.x * 4 + (threadIdx.x >> 6);
  int lane = threadIdx.x & 63;
  int b = row / KOBJ, k = row % KOBJ;
  const float* ar = adj + (size_t)row * KOBJ;
  float v0 = (lane < KOBJ) ? ar[lane] : -INFINITY;
  float v1 = (lane + 64 < KOBJ) ? ar[lane + 64] : -INFINITY;
  int i0 = lane, i1 = lane + 64;
  float tv[NS_];
  int ti[NS_];
#pragma unroll
  for (int s = 0; s < NS_; ++s) {
    bool p0 = (v0 > v1) || (v0 == v1 && i0 < i1);
    float bv = p0 ? v0 : v1;
    int bi = p0 ? i0 : i1;
#pragma unroll
    for (int off = 32; off > 0; off >>= 1) {
      float ov = __shfl_xor(bv, off);
      int oi = __shfl_xor(bi, off);
      if (ov > bv || (ov == bv && oi < bi)) { bv = ov; bi = oi; }
    }
    tv[s] = bv; ti[s] = bi;
    if (bi == i0) v0 = -INFINITY;
    if (bi == i1) v1 = -INFINITY;
  }
  float mx = tv[0], sum = 0.f, av[NS_];
#pragma unroll
  for (int s = 0; s < NS_; ++s) { av[s] = expf(tv[s] - mx); sum += av[s]; }
  if (lane < NS_) {
    int j = ti[lane];
    topi[(size_t)row * NS_ + lane] = j;
    float cx = cent[(b * KOBJ + k) * 2 + 0], cy = cent[(b * KOBJ + k) * 2 + 1];
    float dx = cx - cent[(b * KOBJ + j) * 2 + 0];
    float dy = cy - cent[(b * KOBJ + j) * 2 + 1];
    float rho = sqrtf(dx * dx + dy * dy);
    float th = atan2f(dx, dy);
    float w1[NK_], w2[NK_], s1 = 0.f, s2 = 0.f;
#pragma unroll
    for (int m = 0; m < NK_; ++m) {
      {
        float pr = pr1[m], pt = pt1[m], dr = rho - mr1[m];
        float wr = expf(-0.5f * dr * dr / (1e-14f + pr * pr));
        float fa = fabsf(th - mt1[m]);
        float sa = fabsf(6.283185307179586f - fa);
        float da = fminf(fa, sa);
        float wt = expf(-0.5f * da * da / (1e-14f + pt * pt));
        float w = wr * wt;
        if (w != w) w = 0.f;
        w1[m] = w; s1 += w;
      }
      {
        float pr = pr2[m], pt = pt2[m], dr = rho - mr2[m];
        float wr = expf(-0.5f * dr * dr / (1e-14f + pr * pr));
        float fa = fabsf(th - mt2[m]);
        float sa = fabsf(6.283185307179586f - fa);
        float da = fminf(fa, sa);
        float wt = expf(-0.5f * da * da / (1e-14f + pt * pt));
        float w = wr * wt;
        if (w != w) w = 0.f;
        w2[m] = w; s2 += w;
      }
    }
    float as = av[lane] / sum;
#pragma unroll
    for (int m = 0; m < NK_; ++m) {
      c1[((size_t)row * NS_ + lane) * NK_ + m] = as * (w1[m] / s1);
      c2[((size_t)row * NS_ + lane) * NK_ + m] = w2[m] / s2;
    }
  }
}

// ---------------- gather-combine (bf16 proj in) ----------------
template <bool BF16OUT>
__global__ __launch_bounds__(256) void combine_kernel(
    const short* __restrict__ proj, const float* __restrict__ coeff,
    const int* __restrict__ topi, float* __restrict__ outf, short* __restrict__ outb,
    int N, int mshift) {
  int gx = gridDim.x;
  int fid = blockIdx.y * gx + blockIdx.x;
  int wg = xcd_remap(fid, gx * (int)gridDim.y);
  int nb = wg % gx, row = wg / gx;
  int b = row / KOBJ;
  __shared__ int ids[NS_];
  __shared__ float cs[NS_ * NK_];
  int tid = threadIdx.x;
  if (tid < NS_) ids[tid] = topi[(size_t)row * NS_ + tid];
  else if (tid >= 32 && tid < 32 + NS_ * NK_) cs[tid - 32] = coeff[(size_t)row * NS_ * NK_ + (tid - 32)];
  __syncthreads();
  int n = nb * 256 + tid;
  if (n >= N) return;
  int m = n >> mshift;
  float acc = 0.f;
#pragma unroll
  for (int s = 0; s < NS_; ++s)
    acc = fmaf(cs[s * NK_ + m], bf2f(proj[((size_t)b * KOBJ + ids[s]) * N + n]), acc);
  acc = fmaxf(acc, 0.f);
  if (BF16OUT) outb[(size_t)row * N + n] = f2bf(acc);
  else         outf[(size_t)row * N + n] = acc;
}

// ---------------- max over k, then hh = relu(qenc) * g2max (bf16 out) ----------------
__global__ void reduce_hh_kernel(const float* __restrict__ g2, const float* __restrict__ qenc,
                                 short* __restrict__ hhb) {
  int i = blockIdx.x * blockDim.x + threadIdx.x;
  if (i >= B_ * HID_) return;
  int b = i >> 10, n = i & (HID_ - 1);
  const float* p = g2 + (size_t)b * KOBJ * HID_ + n;
  float mx = -INFINITY;
  for (int k = 0; k < KOBJ; ++k) mx = fmaxf(mx, p[(size_t)k * HID_]);
  hhb[i] = f2bf(fmaxf(qenc[i], 0.f) * mx);
}

extern "C" void kernel_launch(void* const* d_in, const int* in_sizes, int n_in,
                              void* d_out, int out_size, void* d_ws, size_t ws_size,
                              hipStream_t stream) {
  const float* question = (const float*)d_in[0];
  const float* image    = (const float*)d_in[1];
  const float* W_lproj  = (const float*)d_in[3];
  const float* b_lproj  = (const float*)d_in[4];
  const float* W_e1     = (const float*)d_in[5];
  const float* b_e1     = (const float*)d_in[6];
  const float* W_e2     = (const float*)d_in[7];
  const float* b_e2     = (const float*)d_in[8];
  const float* conv_w1  = (const float*)d_in[9];
  const float* mr1 = (const float*)d_in[10];
  const float* mt1 = (const float*)d_in[11];
  const float* pr1 = (const float*)d_in[12];
  const float* pt1 = (const float*)d_in[13];
  const float* conv_w2  = (const float*)d_in[14];
  const float* mr2 = (const float*)d_in[15];
  const float* mt2 = (const float*)d_in[16];
  const float* pr2 = (const float*)d_in[17];
  const float* pt2 = (const float*)d_in[18];
  const float* W_o1 = (const float*)d_in[19];
  const float* b_o1 = (const float*)d_in[20];
  const float* W_o2 = (const float*)d_in[21];
  const float* b_o2 = (const float*)d_in[22];

  float* out = (float*)d_out;
  float* logits = out;               // [32,3000]
  float* adj = out + B_ * OUT_;      // [32,100,100]

  char* ws = (char*)d_ws;
  size_t off = 0;
  auto alloc = [&](size_t bytes) { char* p = ws + off; off += (bytes + 255) & ~((size_t)255); return p; };
  float* qenc  = (float*)alloc((size_t)B_ * HID_ * 4);
  short* qh    = (short*)alloc((size_t)B_ * EMB_ * 2);
  short* ql    = (short*)alloc((size_t)B_ * EMB_ * 2);
  short* qeh   = (short*)alloc((size_t)B_ * HID_ * 2);
  short* qel   = (short*)alloc((size_t)B_ * HID_ * 2);
  short* wlph  = (short*)alloc((size_t)EMB_ * HID_ * 2);
  short* wlpl  = (short*)alloc((size_t)EMB_ * HID_ * 2);
  short* we1ah = (short*)alloc((size_t)COMB_ * KP1 * 2);
  short* we1al = (short*)alloc((size_t)COMB_ * KP1 * 2);
  short* we1bh = (short*)alloc((size_t)COMB_ * HID_ * 2);
  short* we1bl = (short*)alloc((size_t)COMB_ * HID_ * 2);
  short* we2h  = (short*)alloc((size_t)COMB_ * COMB_ * 2);
  short* we2l  = (short*)alloc((size_t)COMB_ * COMB_ * 2);
  float* q1    = (float*)alloc((size_t)B_ * COMB_ * 4);
  short* h1h   = (short*)alloc((size_t)B_ * KOBJ * COMB_ * 2);
  short* h1l   = (short*)alloc((size_t)B_ * KOBJ * COMB_ * 2);
  short* h2h   = (short*)alloc((size_t)(B_ * KOBJ + 128) * COMB_ * 2);  // +pad rows for adj over-read
  short* h2l   = (short*)alloc((size_t)(B_ * KOBJ + 128) * COMB_ * 2);
  float* cent  = (float*)alloc((size_t)B_ * KOBJ * 2 * 4);
  int*   topi  = (int*)alloc((size_t)B_ * KOBJ * NS_ * 4);
  float* c1    = (float*)alloc((size_t)B_ * KOBJ * NS_ * NK_ * 4);
  float* c2    = (float*)alloc((size_t)B_ * KOBJ * NS_ * NK_ * 4);
  short* imgb  = (short*)alloc((size_t)B_ * KOBJ * KP1 * 2);
  short* imgl  = (short*)alloc((size_t)B_ * KOBJ * KP1 * 2);
  short* cw1t  = (short*)alloc((size_t)(2 * HID_) * KP1 * 2);
  short* cw2t  = (short*)alloc((size_t)HID_ * KP2 * 2);
  short* proj1b = (short*)alloc((size_t)B_ * KOBJ * 2 * HID_ * 2);
  short* g1b   = (short*)alloc((size_t)B_ * KOBJ * KP2 * 2);
  short* proj2b = (short*)alloc((size_t)B_ * KOBJ * HID_ * 2);
  float* g2    = (float*)alloc((size_t)B_ * KOBJ * HID_ * 4);
  short* hhb   = (short*)alloc((size_t)B_ * HID_ * 2);
  short* wo1t  = (short*)alloc((size_t)NO_P * HID_ * 2);
  short* wo2t  = (short*)alloc((size_t)NO_P * KO2 * 2);
  short* h1ob  = (short*)alloc((size_t)B_ * KO2 * 2);
  float* partE = (float*)alloc((size_t)4 * B_ * KOBJ * COMB_ * 4);  // 26.2 MB, max over users
  (void)ws_size; (void)in_sizes; (void)n_in; (void)out_size;

  dim3 blk(256), blk512(512);

  // ---- independent prep ----
  centres_kernel<<<dim3((B_ * KOBJ + 255) / 256), blk, 0, stream>>>(image, cent);
  {
    int total = B_ * KOBJ * (KP1 / 8);
    cvt_pad_rows<true><<<dim3((total + 255) / 256), blk, 0, stream>>>(image, imgb, imgl, FEAT_, KP1, total);
  }
  {
    int total = B_ * (EMB_ / 8);
    cvt_pad_rows<true><<<dim3((total + 255) / 256), blk, 0, stream>>>(question, qh, ql, EMB_, EMB_, total);
  }
  transpose_bf16<false, true><<<dim3(EMB_ / 64, HID_ / 64), blk, 0, stream>>>(
      W_lproj, wlph, wlpl, EMB_, HID_, EMB_, 0);
  transpose_bf16<false, true><<<dim3(KP1 / 64, COMB_ / 64), blk, 0, stream>>>(
      W_e1, we1ah, we1al, FEAT_, COMB_, KP1, 0);
  transpose_bf16<false, true><<<dim3(HID_ / 64, COMB_ / 64), blk, 0, stream>>>(
      W_e1 + (size_t)FEAT_ * COMB_, we1bh, we1bl, HID_, COMB_, HID_, 0);
  transpose_bf16<false, true><<<dim3(COMB_ / 64, COMB_ / 64), blk, 0, stream>>>(
      W_e2, we2h, we2l, COMB_, COMB_, COMB_, 0);
  transpose_bf16<true, false><<<dim3(KP1 / 64, (2 * HID_) / 64), blk, 0, stream>>>(
      conv_w1, cw1t, nullptr, FEAT_, 2 * HID_, KP1, 2 * HID_ / NK_);
  transpose_bf16<true, false><<<dim3(KP2 / 64, HID_ / 64), blk, 0, stream>>>(
      conv_w2, cw2t, nullptr, 2 * HID_, HID_, KP2, HID_ / NK_);
  transpose_bf16<false, false><<<dim3(HID_ / 64, NO_P / 64), blk, 0, stream>>>(
      W_o1, wo1t, nullptr, HID_, OUT_, HID_, 0);
  transpose_bf16<false, false><<<dim3(KO2 / 64, NO_P / 64), blk, 0, stream>>>(
      W_o2, wo2t, nullptr, OUT_, OUT_, KO2, 0);

  // ---- qenc = question @ W_lproj + b (split, f32) ----
  gemm_mx<32, 64, 2, 2, true, false, true, 0, false><<<dim3(HID_ / 64, 1, 1), blk, 0, stream>>>(
      qh, ql, wlph, wlpl, b_lproj, qenc, nullptr, nullptr, nullptr, 0, B_, HID_, EMB_, HID_, HID_);
  // ---- split qenc for q1 ----
  {
    int total = B_ * (HID_ / 8);
    cvt_pad_rows<true><<<dim3((total + 255) / 256), blk, 0, stream>>>(qenc, qeh, qel, HID_, HID_, total);
  }
  // ---- q1 = qenc @ We1[2052:] (split, no bias) ----
  gemm_mx<32, 64, 2, 2, true, false, false, 0, false><<<dim3(COMB_ / 64, 1, 1), blk, 0, stream>>>(
      qeh, qel, we1bh, we1bl, nullptr, q1, nullptr, nullptr, nullptr, 0, B_, COMB_, HID_, COMB_, COMB_);
  // ---- e1 image part: split-K partials (z=4, KS=576) ----
  gemm_mx<128, 64, 4, 2, true, false, false, 0, true><<<dim3(COMB_ / 64, B_ * KOBJ / 128, 4), blk512, 0, stream>>>(
      imgb, imgl, we1ah, we1al, nullptr, nullptr, nullptr, nullptr, partE, 576,
      B_ * KOBJ, COMB_, KP1, COMB_, COMB_);
  // ---- h1 = relu(sum + q1[bcast] + b_e1), bf16 hi/lo ----
  reduce_split<1, true, true, true><<<dim3(B_ * KOBJ * COMB_ / 256), blk, 0, stream>>>(
      partE, 4, (size_t)B_ * KOBJ * COMB_, b_e1, q1, COMB_, nullptr, h1h, h1l,
      B_ * KOBJ, COMB_, COMB_, COMB_);
  // ---- e2: split-K partials (z=2, KS=256) ----
  gemm_mx<128, 64, 4, 2, true, false, false, 0, true><<<dim3(COMB_ / 64, B_ * KOBJ / 128, 2), blk512, 0, stream>>>(
      h1h, h1l, we2h, we2l, nullptr, nullptr, nullptr, nullptr, partE, 256,
      B_ * KOBJ, COMB_, COMB_, COMB_, COMB_);
  // ---- h2 = relu(sum + b_e2) as bf16 hi/lo (feeds adj MFMA) ----
  reduce_split<1, true, true, false><<<dim3(B_ * KOBJ * COMB_ / 256), blk, 0, stream>>>(
      partE, 2, (size_t)B_ * KOBJ * COMB_, b_e2, nullptr, 0, nullptr, h2h, h2l,
      B_ * KOBJ, COMB_, COMB_, COMB_);
  // ---- adj (split-bf16 MFMA, Gram) + topk ----
  adj_mfma<<<dim3(B_), blk512, 0, stream>>>(h2h, h2l, adj);
  topk_weights_kernel<<<dim3(B_ * KOBJ / 4), blk, 0, stream>>>(
      adj, cent, mr1, mt1, pr1, pt1, mr2, mt2, pr2, pt2, topi, c1, c2);
  // ---- conv path ----
  gemm_mx<128, 128, 2, 4, false, false, false, 2, false><<<dim3(2 * HID_ / 128, B_ * KOBJ / 128, 1), blk512, 0, stream>>>(
      imgb, nullptr, cw1t, nullptr, nullptr, nullptr, proj1b, nullptr, nullptr, 0,
      B_ * KOBJ, 2 * HID_, KP1, 2 * HID_, 2 * HID_);
  combine_kernel<true><<<dim3(2 * HID_ / 256, B_ * KOBJ), blk, 0, stream>>>(
      proj1b, c1, topi, nullptr, g1b, 2 * HID_, 8);
  gemm_mx<128, 64, 2, 4, false, false, false, 2, false><<<dim3(HID_ / 64, B_ * KOBJ / 128, 1), blk512, 0, stream>>>(
      g1b, nullptr, cw2t, nullptr, nullptr, nullptr, proj2b, nullptr, nullptr, 0,
      B_ * KOBJ, HID_, KP2, HID_, HID_);
  combine_kernel<false><<<dim3(HID_ / 256, B_ * KOBJ), blk, 0, stream>>>(
      proj2b, c2, topi, g2, nullptr, HID_, 7);
  // ---- tail ----
  reduce_hh_kernel<<<dim3((B_ * HID_ + 255) / 256), blk, 0, stream>>>(g2, qenc, hhb);
  // o1: split-K z=8, KS=128
  gemm_mx<32, 128, 1, 4, false, false, false, 0, true><<<dim3(NO_P / 128, 1, 8), blk, 0, stream>>>(
      hhb, nullptr, wo1t, nullptr, nullptr, nullptr, nullptr, nullptr, partE, 128,
      B_, OUT_, HID_, KO2, KO2);
  reduce_split<2, true, true, false><<<dim3((B_ * KO2 + 255) / 256), blk, 0, stream>>>(
      partE, 8, (size_t)B_ * KO2, b_o1, nullptr, 0, nullptr, h1ob, nullptr,
      B_, OUT_, KO2, KO2);
  // o2: split-K z=8, KS=384
  gemm_mx<32, 128, 1, 4, false, false, false, 0, true><<<dim3(NO_P / 128, 1, 8), blk, 0, stream>>>(
      h1ob, nullptr, wo2t, nullptr, nullptr, nullptr, nullptr, nullptr, partE, 384,
      B_, OUT_, KO2, KO2, KO2);
  reduce_split<0, false, true, false><<<dim3((B_ * KO2 + 255) / 256), blk, 0, stream>>>(
      partE, 8, (size_t)B_ * KO2, b_o2, nullptr, 0, logits, nullptr, nullptr,
      B_, OUT_, KO2, OUT_);
}

// Round 6
// 394.816 us; speedup vs baseline: 3.7906x; 1.1434x over previous
//
#include <hip/hip_runtime.h>
#include <math.h>
#include <stdint.h>

#define B_    32
#define KOBJ  100
#define NS_   16
#define NK_   8
#define EMB_  1024
#define FEAT_ 2052
#define HID_  1024
#define OUT_  3000
#define COMB_ 512

#define KP1   2112   // FEAT_ padded to 64 (image rows / We1a rows)
#define KP2   2048   // 2*HID_
#define NO_P  3072   // OUT_ padded to 128 (N of o1/o2)
#define KO2   3008   // OUT_ padded to 64 (K of o2)

typedef __attribute__((ext_vector_type(8))) short s16x8;
typedef __attribute__((ext_vector_type(4))) float f32x4;

__device__ inline short f2bf(float f) {
  uint32_t u = __builtin_bit_cast(uint32_t, f);
  u = (u + 0x7fff + ((u >> 16) & 1)) >> 16;  // RNE
  return (short)u;
}
__device__ inline float bf2f(short s) {
  uint32_t u = ((uint32_t)(uint16_t)s) << 16;
  return __builtin_bit_cast(float, u);
}
__device__ inline void gload_lds16(const void* g, void* l) {
  __builtin_amdgcn_global_load_lds(
      (const __attribute__((address_space(1))) void*)g,
      (__attribute__((address_space(3))) void*)l, 16, 0, 0);
}
// XCD-aware bijective remap (m204): consecutive wg cluster on one XCD
__device__ inline int xcd_remap(int fid, int nwg) {
  int q = nwg >> 3, r = nwg & 7;
  int x = fid & 7, l = fid >> 3;
  return (x < r ? x * (q + 1) : r * (q + 1) + (x - r) * q) + l;
}

// ---------------- bb centres ----------------
__global__ void centres_kernel(const float* __restrict__ image, float* __restrict__ cent) {
  int i = blockIdx.x * blockDim.x + threadIdx.x;
  if (i >= B_ * KOBJ) return;
  const float* bb = image + (size_t)i * FEAT_ + (FEAT_ - 4);
  cent[i * 2 + 0] = 0.5f * (bb[0] + bb[2]);
  cent[i * 2 + 1] = 0.5f * (bb[1] + bb[3]);
}

// ---------------- f32 -> bf16 row-major convert with K padding (optional hi/lo split) ----
// Vectorized: interior chunks load 2x float4 (rows are 16B-aligned for all callers).
template <bool SPLIT>
__global__ void cvt_pad_rows(const float* __restrict__ in, short* __restrict__ outh,
                             short* __restrict__ outl, int K, int Kp, int total) {
  int idx = blockIdx.x * 256 + threadIdx.x;
  if (idx >= total) return;
  int row = idx / (Kp / 8), c8 = (idx % (Kp / 8)) * 8;
  float f[8];
  if (c8 + 8 <= K) {
    const float* src = in + (size_t)row * K + c8;
    float4 a = *(const float4*)src;
    float4 b = *(const float4*)(src + 4);
    f[0] = a.x; f[1] = a.y; f[2] = a.z; f[3] = a.w;
    f[4] = b.x; f[5] = b.y; f[6] = b.z; f[7] = b.w;
  } else {
#pragma unroll
    for (int i = 0; i < 8; ++i) {
      int k = c8 + i;
      f[i] = (k < K) ? in[(size_t)row * K + k] : 0.f;
    }
  }
  s16x8 vh, vl;
#pragma unroll
  for (int i = 0; i < 8; ++i) {
    short h = f2bf(f[i]);
    vh[i] = h;
    if (SPLIT) vl[i] = f2bf(f[i] - bf2f(h));
  }
  *(s16x8*)(outh + (size_t)row * Kp + c8) = vh;
  if (SPLIT) *(s16x8*)(outl + (size_t)row * Kp + c8) = vl;
}

// ---------------- transpose-convert weights to Bt[n][kp] bf16 (optional split) ----------
// CONV: in element (k,n) = in[((n/OPM)*K + k)*OPM + (n%OPM)]; else in[k*N + n]
// Read side vectorized: per pass each lane loads one aligned float4 (wave = 4 rows
// x 256B contiguous). CONV tiles are row-contiguous since 64 <= OPM and n0%64==0.
template <bool CONV, bool SPLIT>
__global__ __launch_bounds__(256) void transpose_bf16(
    const float* __restrict__ in, short* __restrict__ outh, short* __restrict__ outl,
    int K, int N, int Kp, int OPM) {
  __shared__ float s[64][65];
  int k0 = blockIdx.x * 64, n0 = blockIdx.y * 64;
  int t = threadIdx.x;
  int rr = t >> 4;             // 0..15
  int c4 = (t & 15) * 4;       // 0..60
  bool fullN = CONV || (n0 + 64 <= N);
#pragma unroll
  for (int p = 0; p < 4; ++p) {
    int row = p * 16 + rr;
    int kg = k0 + row;
    float v0 = 0.f, v1 = 0.f, v2 = 0.f, v3 = 0.f;
    if (kg < K) {
      const float* src = CONV
          ? in + ((size_t)(n0 / OPM) * K + kg) * OPM + (n0 % OPM) + c4
          : in + (size_t)kg * N + n0 + c4;
      if (fullN) {
        float4 v = *(const float4*)src;
        v0 = v.x; v1 = v.y; v2 = v.z; v3 = v.w;
      } else {
        int nb = n0 + c4;
        if (nb + 0 < N) v0 = src[0];
        if (nb + 1 < N) v1 = src[1];
        if (nb + 2 < N) v2 = src[2];
        if (nb + 3 < N) v3 = src[3];
      }
    }
    s[row][c4 + 0] = v0; s[row][c4 + 1] = v1;
    s[row][c4 + 2] = v2; s[row][c4 + 3] = v3;
  }
  __syncthreads();
  int nl = t >> 2, kc = (t & 3) << 4;
#pragma unroll
  for (int half = 0; half < 2; ++half) {
    s16x8 vh, vl;
#pragma unroll
    for (int i = 0; i < 8; ++i) {
      float f = s[kc + half * 8 + i][nl];
      short h = f2bf(f);
      vh[i] = h;
      if (SPLIT) vl[i] = f2bf(f - bf2f(h));
    }
    short* o = outh + (size_t)(n0 + nl) * Kp + k0 + kc + half * 8;
    *(s16x8*)o = vh;
    if (SPLIT) *(s16x8*)(outl + (size_t)(n0 + nl) * Kp + k0 + kc + half * 8) = vl;
  }
}

// ---------------- unified MFMA GEMM ----------------
// C[M][N] = A[M][Kp] @ Bt[N][Kp]^T, bf16 MFMA, WR x WC waves.
// SPLIT: hi/lo 3-product split-f32. SPLITK: blockIdx.z k-chunks of KS -> f32
// partials in part[z][M][ldc] (bias/relu/omode applied later by reduce_split).
// OMODE: 0=f32, 1=bf16 hi/lo pair, 2=bf16. Writes cols [0,Nw), zero for n>=N.
template <int BM, int BN, int WR, int WC, bool SPLIT, bool RELU, bool BIAS, int OMODE, bool SPLITK>
__global__ __launch_bounds__(WR * WC * 64) void gemm_mx(
    const short* __restrict__ Ah, const short* __restrict__ Al,
    const short* __restrict__ Bh, const short* __restrict__ Bl,
    const float* __restrict__ bias,
    float* __restrict__ Cf, short* __restrict__ Ch, short* __restrict__ Cl,
    float* __restrict__ part, int KS,
    int M, int N, int Kp, int ldc, int Nw) {
  constexpr int NWV = WR * WC;
  constexpr int WM = BM / WR, WN = BN / WC;
  constexpr int FM = WM / 16, FN = WN / 16;
  constexpr int ACH = BM / 8, BCH = BN / 8;
  constexpr int NCH = (ACH + BCH) * (SPLIT ? 2 : 1);
  __shared__ short Ash[BM * 64];
  __shared__ short Bsh[BN * 64];
  __shared__ short Asl[SPLIT ? BM * 64 : 64];
  __shared__ short Bsl[SPLIT ? BN * 64 : 64];
  int tid = threadIdx.x, wave = tid >> 6, lane = tid & 63;
  int wr = wave / WC, wc = wave % WC;
  int r16 = lane & 15, kq = lane >> 4;
  int gx = gridDim.x, gy = gridDim.y, gz = gridDim.z;
  int fid = (blockIdx.z * gy + blockIdx.y) * gx + blockIdx.x;
  int wg = xcd_remap(fid, gx * gy * gz);
  int bx = wg % gx, byz = wg / gx;
  int by = byz % gy, bz = byz / gy;
  int m0 = by * BM, n0 = bx * BN;
  int kb = SPLITK ? bz * KS : 0;
  int ke = SPLITK ? (kb + KS < Kp ? kb + KS : Kp) : Kp;
  f32x4 acc[FM][FN] = {};

  for (int k0 = kb; k0 < ke; k0 += 64) {
    __syncthreads();
    for (int c = wave; c < NCH; c += NWV) {
      int cc = c;
      const short* g;
      char* l;
      bool isA;
      if (cc < ACH) { isA = true; g = Ah; l = (char*)Ash; }
      else if (SPLIT && cc < 2 * ACH) { cc -= ACH; isA = true; g = Al; l = (char*)Asl; }
      else {
        cc -= SPLIT ? 2 * ACH : ACH;
        if (cc < BCH) { isA = false; g = Bh; l = (char*)Bsh; }
        else { cc -= BCH; isA = false; g = Bl; l = (char*)Bsl; }
      }
      int Lb = cc * 1024 + lane * 16;
      int row = Lb >> 7;
      int off = (Lb & 127) ^ ((row & 7) << 4);
      const short* gsrc = g + (size_t)((isA ? m0 : n0) + row) * Kp + k0 + (off >> 1);
      gload_lds16(gsrc, l + cc * 1024);
    }
    __syncthreads();  // compiler drains vmcnt before barrier
#pragma unroll
    for (int kk = 0; kk < 2; ++kk) {
      int woff = kk * 64 + kq * 16;
      s16x8 ah[FM], al[FM], bh[FN], bl[FN];
#pragma unroll
      for (int f = 0; f < FM; ++f) {
        int row = wr * WM + f * 16 + r16;
        int o = woff ^ ((row & 7) << 4);
        ah[f] = *(const s16x8*)((const char*)Ash + row * 128 + o);
        if (SPLIT) al[f] = *(const s16x8*)((const char*)Asl + row * 128 + o);
      }
#pragma unroll
      for (int gg = 0; gg < FN; ++gg) {
        int row = wc * WN + gg * 16 + r16;
        int o = woff ^ ((row & 7) << 4);
        bh[gg] = *(const s16x8*)((const char*)Bsh + row * 128 + o);
        if (SPLIT) bl[gg] = *(const s16x8*)((const char*)Bsl + row * 128 + o);
      }
#pragma unroll
      for (int f = 0; f < FM; ++f)
#pragma unroll
        for (int gg = 0; gg < FN; ++gg) {
          acc[f][gg] = __builtin_amdgcn_mfma_f32_16x16x32_bf16(ah[f], bh[gg], acc[f][gg], 0, 0, 0);
          if (SPLIT) {
            acc[f][gg] = __builtin_amdgcn_mfma_f32_16x16x32_bf16(ah[f], bl[gg], acc[f][gg], 0, 0, 0);
            acc[f][gg] = __builtin_amdgcn_mfma_f32_16x16x32_bf16(al[f], bh[gg], acc[f][gg], 0, 0, 0);
          }
        }
    }
  }
#pragma unroll
  for (int f = 0; f < FM; ++f)
#pragma unroll
    for (int gg = 0; gg < FN; ++gg)
#pragma unroll
      for (int r = 0; r < 4; ++r) {
        int m = m0 + wr * WM + f * 16 + (lane >> 4) * 4 + r;
        int n = n0 + wc * WN + gg * 16 + r16;
        if (m >= M || n >= Nw) continue;
        float v = (n < N) ? acc[f][gg][r] : 0.f;
        size_t idx = (size_t)m * ldc + n;
        if (SPLITK) {
          part[(size_t)bz * M * ldc + idx] = v;
        } else {
          if (BIAS && n < N) v += bias[n];
          if (RELU) v = fmaxf(v, 0.f);
          if (OMODE == 0) Cf[idx] = v;
          else if (OMODE == 1) {
            short h = f2bf(v);
            Ch[idx] = h;
            Cl[idx] = f2bf(v - bf2f(h));
          } else {
            Ch[idx] = f2bf(v);
          }
        }
      }
}

// ---------------- split-K reduce: out = op(sum_z part[z] (+bcast) (+bias)) ----------------
template <int OMODE, bool RELU, bool BIAS, bool BCAST>
__global__ void reduce_split(const float* __restrict__ part, int SK, size_t pstride,
                             const float* __restrict__ bias, const float* __restrict__ bcast,
                             int bcols, float* __restrict__ Cf, short* __restrict__ Ch,
                             short* __restrict__ Cl, int M, int N, int ldIn, int ldOut) {
  int idx = blockIdx.x * 256 + threadIdx.x;
  if (idx >= M * ldIn) return;
  int m = idx / ldIn, n = idx - m * ldIn;
  if (n >= ldOut) return;
  float v = 0.f;
  for (int s = 0; s < SK; ++s) v += part[(size_t)s * pstride + idx];
  if (n < N) {
    if (BCAST) v += bcast[(size_t)(m / KOBJ) * bcols + n];
    if (BIAS) v += bias[n];
  }
  if (RELU) v = fmaxf(v, 0.f);
  size_t o = (size_t)m * ldOut + n;
  if (OMODE == 0) Cf[o] = v;
  else if (OMODE == 1) {
    short h = f2bf(v);
    Ch[o] = h;
    Cl[o] = f2bf(v - bf2f(h));
  } else {
    Ch[o] = f2bf(v);
  }
}

// ---------------- adj[b] = h2[b] @ h2[b]^T, split-bf16 MFMA, one block/batch ----------------
__global__ __launch_bounds__(512) void adj_mfma(const short* __restrict__ Hh,
                                                const short* __restrict__ Hl,
                                                float* __restrict__ adj) {
  __shared__ short Ash[128 * 64];
  __shared__ short Asl[128 * 64];
  int tid = threadIdx.x, wave = tid >> 6, lane = tid & 63;
  int wr = wave >> 2, wc = wave & 3;        // 2x4 wave grid: WM=64, WN=32
  int r16 = lane & 15, kq = lane >> 4;
  int b = blockIdx.x;
  const short* baseh = Hh + (size_t)b * KOBJ * COMB_;
  const short* basel = Hl + (size_t)b * KOBJ * COMB_;
  f32x4 acc[4][2] = {};
  for (int k0 = 0; k0 < COMB_; k0 += 64) {
    __syncthreads();
    for (int c = wave; c < 32; c += 8) {    // 16 hi chunks + 16 lo chunks, 1 KB each
      int cc = c & 15;
      bool hi = c < 16;
      int Lb = cc * 1024 + lane * 16;
      int row = Lb >> 7;
      int off = (Lb & 127) ^ ((row & 7) << 4);
      const short* gsrc = (hi ? baseh : basel) + (size_t)row * COMB_ + k0 + (off >> 1);
      gload_lds16(gsrc, (char*)(hi ? Ash : Asl) + cc * 1024);
    }
    __syncthreads();
#pragma unroll
    for (int kk = 0; kk < 2; ++kk) {
      int woff = kk * 64 + kq * 16;
      s16x8 ah[4], al[4], bh[2], bl[2];
#pragma unroll
      for (int f = 0; f < 4; ++f) {
        int row = wr * 64 + f * 16 + r16;
        int o = woff ^ ((row & 7) << 4);
        ah[f] = *(const s16x8*)((const char*)Ash + row * 128 + o);
        al[f] = *(const s16x8*)((const char*)Asl + row * 128 + o);
      }
#pragma unroll
      for (int g = 0; g < 2; ++g) {
        int row = wc * 32 + g * 16 + r16;
        int o = woff ^ ((row & 7) << 4);
        bh[g] = *(const s16x8*)((const char*)Ash + row * 128 + o);
        bl[g] = *(const s16x8*)((const char*)Asl + row * 128 + o);
      }
#pragma unroll
      for (int f = 0; f < 4; ++f)
#pragma unroll
        for (int g = 0; g < 2; ++g) {
          acc[f][g] = __builtin_amdgcn_mfma_f32_16x16x32_bf16(ah[f], bh[g], acc[f][g], 0, 0, 0);
          acc[f][g] = __builtin_amdgcn_mfma_f32_16x16x32_bf16(ah[f], bl[g], acc[f][g], 0, 0, 0);
          acc[f][g] = __builtin_amdgcn_mfma_f32_16x16x32_bf16(al[f], bh[g], acc[f][g], 0, 0, 0);
        }
    }
  }
#pragma unroll
  for (int f = 0; f < 4; ++f)
#pragma unroll
    for (int g = 0; g < 2; ++g)
#pragma unroll
      for (int r = 0; r < 4; ++r) {
        int m = wr * 64 + f * 16 + (lane >> 4) * 4 + r;
        int n = wc * 32 + g * 16 + r16;
        if (m < KOBJ && n < KOBJ)
          adj[((size_t)b * KOBJ + m) * KOBJ + n] = acc[f][g][r];
      }
}

// ---------------- top-k + softmax + gaussian kernel weights ----------------
__global__ __launch_bounds__(256) void topk_weights_kernel(
    const float* __restrict__ adj, const float* __restrict__ cent,
    const float* __restrict__ mr1, const float* __restrict__ mt1,
    const float* __restrict__ pr1, const float* __restrict__ pt1,
    const float* __restrict__ mr2, const float* __restrict__ mt2,
    const float* __restrict__ pr2, const float* __restrict__ pt2,
    int* __restrict__ topi, float* __restrict__ c1, float* __restrict__ c2) {
  int row = blockIdx.x * 4 + (threadIdx.x >> 6);
  int lane = threadIdx.x & 63;
  int b = row / KOBJ, k = row % KOBJ;
  const float* ar = adj + (size_t)row * KOBJ;
  float v0 = (lane < KOBJ) ? ar[lane] : -INFINITY;
  float v1 = (lane + 64 < KOBJ) ? ar[lane + 64] : -INFINITY;
  int i0 = lane, i1 = lane + 64;
  float tv[NS_];
  int ti[NS_];
#pragma unroll
  for (int s = 0; s < NS_; ++s) {
    bool p0 = (v0 > v1) || (v0 == v1 && i0 < i1);
    float bv = p0 ? v0 : v1;
    int bi = p0 ? i0 : i1;
#pragma unroll
    for (int off = 32; off > 0; off >>= 1) {
      float ov = __shfl_xor(bv, off);
      int oi = __shfl_xor(bi, off);
      if (ov > bv || (ov == bv && oi < bi)) { bv = ov; bi = oi; }
    }
    tv[s] = bv; ti[s] = bi;
    if (bi == i0) v0 = -INFINITY;
    if (bi == i1) v1 = -INFINITY;
  }
  float mx = tv[0], sum = 0.f, av[NS_];
#pragma unroll
  for (int s = 0; s < NS_; ++s) { av[s] = expf(tv[s] - mx); sum += av[s]; }
  if (lane < NS_) {
    int j = ti[lane];
    topi[(size_t)row * NS_ + lane] = j;
    float cx = cent[(b * KOBJ + k) * 2 + 0], cy = cent[(b * KOBJ + k) * 2 + 1];
    float dx = cx - cent[(b * KOBJ + j) * 2 + 0];
    float dy = cy - cent[(b * KOBJ + j) * 2 + 1];
    float rho = sqrtf(dx * dx + dy * dy);
    float th = atan2f(dx, dy);
    float w1[NK_], w2[NK_], s1 = 0.f, s2 = 0.f;
#pragma unroll
    for (int m = 0; m < NK_; ++m) {
      {
        float pr = pr1[m], pt = pt1[m], dr = rho - mr1[m];
        float wr = expf(-0.5f * dr * dr / (1e-14f + pr * pr));
        float fa = fabsf(th - mt1[m]);
        float sa = fabsf(6.283185307179586f - fa);
        float da = fminf(fa, sa);
        float wt = expf(-0.5f * da * da / (1e-14f + pt * pt));
        float w = wr * wt;
        if (w != w) w = 0.f;
        w1[m] = w; s1 += w;
      }
      {
        float pr = pr2[m], pt = pt2[m], dr = rho - mr2[m];
        float wr = expf(-0.5f * dr * dr / (1e-14f + pr * pr));
        float fa = fabsf(th - mt2[m]);
        float sa = fabsf(6.283185307179586f - fa);
        float da = fminf(fa, sa);
        float wt = expf(-0.5f * da * da / (1e-14f + pt * pt));
        float w = wr * wt;
        if (w != w) w = 0.f;
        w2[m] = w; s2 += w;
      }
    }
    float as = av[lane] / sum;
#pragma unroll
    for (int m = 0; m < NK_; ++m) {
      c1[((size_t)row * NS_ + lane) * NK_ + m] = as * (w1[m] / s1);
      c2[((size_t)row * NS_ + lane) * NK_ + m] = w2[m] / s2;
    }
  }
}

// ---------------- gather-combine (bf16 proj in) ----------------
template <bool BF16OUT>
__global__ __launch_bounds__(256) void combine_kernel(
    const short* __restrict__ proj, const float* __restrict__ coeff,
    const int* __restrict__ topi, float* __restrict__ outf, short* __restrict__ outb,
    int N, int mshift) {
  int gx = gridDim.x;
  int fid = blockIdx.y * gx + blockIdx.x;
  int wg = xcd_remap(fid, gx * (int)gridDim.y);
  int nb = wg % gx, row = wg / gx;
  int b = row / KOBJ;
  __shared__ int ids[NS_];
  __shared__ float cs[NS_ * NK_];
  int tid = threadIdx.x;
  if (tid < NS_) ids[tid] = topi[(size_t)row * NS_ + tid];
  else if (tid >= 32 && tid < 32 + NS_ * NK_) cs[tid - 32] = coeff[(size_t)row * NS_ * NK_ + (tid - 32)];
  __syncthreads();
  int n = nb * 256 + tid;
  if (n >= N) return;
  int m = n >> mshift;
  float acc = 0.f;
#pragma unroll
  for (int s = 0; s < NS_; ++s)
    acc = fmaf(cs[s * NK_ + m], bf2f(proj[((size_t)b * KOBJ + ids[s]) * N + n]), acc);
  acc = fmaxf(acc, 0.f);
  if (BF16OUT) outb[(size_t)row * N + n] = f2bf(acc);
  else         outf[(size_t)row * N + n] = acc;
}

// ---------------- max over k, then hh = relu(qenc) * g2max (bf16 out) ----------------
__global__ void reduce_hh_kernel(const float* __restrict__ g2, const float* __restrict__ qenc,
                                 short* __restrict__ hhb) {
  int i = blockIdx.x * blockDim.x + threadIdx.x;
  if (i >= B_ * HID_) return;
  int b = i >> 10, n = i & (HID_ - 1);
  const float* p = g2 + (size_t)b * KOBJ * HID_ + n;
  float mx = -INFINITY;
  for (int k = 0; k < KOBJ; ++k) mx = fmaxf(mx, p[(size_t)k * HID_]);
  hhb[i] = f2bf(fmaxf(qenc[i], 0.f) * mx);
}

extern "C" void kernel_launch(void* const* d_in, const int* in_sizes, int n_in,
                              void* d_out, int out_size, void* d_ws, size_t ws_size,
                              hipStream_t stream) {
  const float* question = (const float*)d_in[0];
  const float* image    = (const float*)d_in[1];
  const float* W_lproj  = (const float*)d_in[3];
  const float* b_lproj  = (const float*)d_in[4];
  const float* W_e1     = (const float*)d_in[5];
  const float* b_e1     = (const float*)d_in[6];
  const float* W_e2     = (const float*)d_in[7];
  const float* b_e2     = (const float*)d_in[8];
  const float* conv_w1  = (const float*)d_in[9];
  const float* mr1 = (const float*)d_in[10];
  const float* mt1 = (const float*)d_in[11];
  const float* pr1 = (const float*)d_in[12];
  const float* pt1 = (const float*)d_in[13];
  const float* conv_w2  = (const float*)d_in[14];
  const float* mr2 = (const float*)d_in[15];
  const float* mt2 = (const float*)d_in[16];
  const float* pr2 = (const float*)d_in[17];
  const float* pt2 = (const float*)d_in[18];
  const float* W_o1 = (const float*)d_in[19];
  const float* b_o1 = (const float*)d_in[20];
  const float* W_o2 = (const float*)d_in[21];
  const float* b_o2 = (const float*)d_in[22];

  float* out = (float*)d_out;
  float* logits = out;               // [32,3000]
  float* adj = out + B_ * OUT_;      // [32,100,100]

  char* ws = (char*)d_ws;
  size_t off = 0;
  auto alloc = [&](size_t bytes) { char* p = ws + off; off += (bytes + 255) & ~((size_t)255); return p; };
  float* qenc  = (float*)alloc((size_t)B_ * HID_ * 4);
  short* qh    = (short*)alloc((size_t)B_ * EMB_ * 2);
  short* ql    = (short*)alloc((size_t)B_ * EMB_ * 2);
  short* qeh   = (short*)alloc((size_t)B_ * HID_ * 2);
  short* qel   = (short*)alloc((size_t)B_ * HID_ * 2);
  short* wlph  = (short*)alloc((size_t)EMB_ * HID_ * 2);
  short* wlpl  = (short*)alloc((size_t)EMB_ * HID_ * 2);
  short* we1ah = (short*)alloc((size_t)COMB_ * KP1 * 2);
  short* we1al = (short*)alloc((size_t)COMB_ * KP1 * 2);
  short* we1bh = (short*)alloc((size_t)COMB_ * HID_ * 2);
  short* we1bl = (short*)alloc((size_t)COMB_ * HID_ * 2);
  short* we2h  = (short*)alloc((size_t)COMB_ * COMB_ * 2);
  short* we2l  = (short*)alloc((size_t)COMB_ * COMB_ * 2);
  float* q1    = (float*)alloc((size_t)B_ * COMB_ * 4);
  short* h1h   = (short*)alloc((size_t)B_ * KOBJ * COMB_ * 2);
  short* h1l   = (short*)alloc((size_t)B_ * KOBJ * COMB_ * 2);
  short* h2h   = (short*)alloc((size_t)(B_ * KOBJ + 128) * COMB_ * 2);  // +pad rows for adj over-read
  short* h2l   = (short*)alloc((size_t)(B_ * KOBJ + 128) * COMB_ * 2);
  float* cent  = (float*)alloc((size_t)B_ * KOBJ * 2 * 4);
  int*   topi  = (int*)alloc((size_t)B_ * KOBJ * NS_ * 4);
  float* c1    = (float*)alloc((size_t)B_ * KOBJ * NS_ * NK_ * 4);
  float* c2    = (float*)alloc((size_t)B_ * KOBJ * NS_ * NK_ * 4);
  short* imgb  = (short*)alloc((size_t)B_ * KOBJ * KP1 * 2);
  short* imgl  = (short*)alloc((size_t)B_ * KOBJ * KP1 * 2);
  short* cw1t  = (short*)alloc((size_t)(2 * HID_) * KP1 * 2);
  short* cw2t  = (short*)alloc((size_t)HID_ * KP2 * 2);
  short* proj1b = (short*)alloc((size_t)B_ * KOBJ * 2 * HID_ * 2);
  short* g1b   = (short*)alloc((size_t)B_ * KOBJ * KP2 * 2);
  short* proj2b = (short*)alloc((size_t)B_ * KOBJ * HID_ * 2);
  float* g2    = (float*)alloc((size_t)B_ * KOBJ * HID_ * 4);
  short* hhb   = (short*)alloc((size_t)B_ * HID_ * 2);
  short* wo1t  = (short*)alloc((size_t)NO_P * HID_ * 2);
  short* wo2t  = (short*)alloc((size_t)NO_P * KO2 * 2);
  short* h1ob  = (short*)alloc((size_t)B_ * KO2 * 2);
  float* partE = (float*)alloc((size_t)4 * B_ * KOBJ * COMB_ * 4);  // 26.2 MB, max over users
  (void)ws_size; (void)in_sizes; (void)n_in; (void)out_size;

  dim3 blk(256), blk512(512);

  // ---- independent prep ----
  centres_kernel<<<dim3((B_ * KOBJ + 255) / 256), blk, 0, stream>>>(image, cent);
  {
    int total = B_ * KOBJ * (KP1 / 8);
    cvt_pad_rows<true><<<dim3((total + 255) / 256), blk, 0, stream>>>(image, imgb, imgl, FEAT_, KP1, total);
  }
  {
    int total = B_ * (EMB_ / 8);
    cvt_pad_rows<true><<<dim3((total + 255) / 256), blk, 0, stream>>>(question, qh, ql, EMB_, EMB_, total);
  }
  transpose_bf16<false, true><<<dim3(EMB_ / 64, HID_ / 64), blk, 0, stream>>>(
      W_lproj, wlph, wlpl, EMB_, HID_, EMB_, 0);
  transpose_bf16<false, true><<<dim3(KP1 / 64, COMB_ / 64), blk, 0, stream>>>(
      W_e1, we1ah, we1al, FEAT_, COMB_, KP1, 0);
  transpose_bf16<false, true><<<dim3(HID_ / 64, COMB_ / 64), blk, 0, stream>>>(
      W_e1 + (size_t)FEAT_ * COMB_, we1bh, we1bl, HID_, COMB_, HID_, 0);
  transpose_bf16<false, true><<<dim3(COMB_ / 64, COMB_ / 64), blk, 0, stream>>>(
      W_e2, we2h, we2l, COMB_, COMB_, COMB_, 0);
  transpose_bf16<true, false><<<dim3(KP1 / 64, (2 * HID_) / 64), blk, 0, stream>>>(
      conv_w1, cw1t, nullptr, FEAT_, 2 * HID_, KP1, 2 * HID_ / NK_);
  transpose_bf16<true, false><<<dim3(KP2 / 64, HID_ / 64), blk, 0, stream>>>(
      conv_w2, cw2t, nullptr, 2 * HID_, HID_, KP2, HID_ / NK_);
  transpose_bf16<false, false><<<dim3(HID_ / 64, NO_P / 64), blk, 0, stream>>>(
      W_o1, wo1t, nullptr, HID_, OUT_, HID_, 0);
  transpose_bf16<false, false><<<dim3(KO2 / 64, NO_P / 64), blk, 0, stream>>>(
      W_o2, wo2t, nullptr, OUT_, OUT_, KO2, 0);

  // ---- qenc = question @ W_lproj + b (split, f32) ----
  gemm_mx<32, 64, 2, 2, true, false, true, 0, false><<<dim3(HID_ / 64, 1, 1), blk, 0, stream>>>(
      qh, ql, wlph, wlpl, b_lproj, qenc, nullptr, nullptr, nullptr, 0, B_, HID_, EMB_, HID_, HID_);
  // ---- split qenc for q1 ----
  {
    int total = B_ * (HID_ / 8);
    cvt_pad_rows<true><<<dim3((total + 255) / 256), blk, 0, stream>>>(qenc, qeh, qel, HID_, HID_, total);
  }
  // ---- q1 = qenc @ We1[2052:] (split, no bias) ----
  gemm_mx<32, 64, 2, 2, true, false, false, 0, false><<<dim3(COMB_ / 64, 1, 1), blk, 0, stream>>>(
      qeh, qel, we1bh, we1bl, nullptr, q1, nullptr, nullptr, nullptr, 0, B_, COMB_, HID_, COMB_, COMB_);
  // ---- e1 image part: split-K partials (z=4, KS=576) ----
  gemm_mx<128, 64, 4, 2, true, false, false, 0, true><<<dim3(COMB_ / 64, B_ * KOBJ / 128, 4), blk512, 0, stream>>>(
      imgb, imgl, we1ah, we1al, nullptr, nullptr, nullptr, nullptr, partE, 576,
      B_ * KOBJ, COMB_, KP1, COMB_, COMB_);
  // ---- h1 = relu(sum + q1[bcast] + b_e1), bf16 hi/lo ----
  reduce_split<1, true, true, true><<<dim3(B_ * KOBJ * COMB_ / 256), blk, 0, stream>>>(
      partE, 4, (size_t)B_ * KOBJ * COMB_, b_e1, q1, COMB_, nullptr, h1h, h1l,
      B_ * KOBJ, COMB_, COMB_, COMB_);
  // ---- e2: split-K partials (z=2, KS=256) ----
  gemm_mx<128, 64, 4, 2, true, false, false, 0, true><<<dim3(COMB_ / 64, B_ * KOBJ / 128, 2), blk512, 0, stream>>>(
      h1h, h1l, we2h, we2l, nullptr, nullptr, nullptr, nullptr, partE, 256,
      B_ * KOBJ, COMB_, COMB_, COMB_, COMB_);
  // ---- h2 = relu(sum + b_e2) as bf16 hi/lo (feeds adj MFMA) ----
  reduce_split<1, true, true, false><<<dim3(B_ * KOBJ * COMB_ / 256), blk, 0, stream>>>(
      partE, 2, (size_t)B_ * KOBJ * COMB_, b_e2, nullptr, 0, nullptr, h2h, h2l,
      B_ * KOBJ, COMB_, COMB_, COMB_);
  // ---- adj (split-bf16 MFMA, Gram) + topk ----
  adj_mfma<<<dim3(B_), blk512, 0, stream>>>(h2h, h2l, adj);
  topk_weights_kernel<<<dim3(B_ * KOBJ / 4), blk, 0, stream>>>(
      adj, cent, mr1, mt1, pr1, pt1, mr2, mt2, pr2, pt2, topi, c1, c2);
  // ---- conv path ----
  gemm_mx<128, 128, 2, 4, false, false, false, 2, false><<<dim3(2 * HID_ / 128, B_ * KOBJ / 128, 1), blk512, 0, stream>>>(
      imgb, nullptr, cw1t, nullptr, nullptr, nullptr, proj1b, nullptr, nullptr, 0,
      B_ * KOBJ, 2 * HID_, KP1, 2 * HID_, 2 * HID_);
  combine_kernel<true><<<dim3(2 * HID_ / 256, B_ * KOBJ), blk, 0, stream>>>(
      proj1b, c1, topi, nullptr, g1b, 2 * HID_, 8);
  gemm_mx<128, 64, 2, 4, false, false, false, 2, false><<<dim3(HID_ / 64, B_ * KOBJ / 128, 1), blk512, 0, stream>>>(
      g1b, nullptr, cw2t, nullptr, nullptr, nullptr, proj2b, nullptr, nullptr, 0,
      B_ * KOBJ, HID_, KP2, HID_, HID_);
  combine_kernel<false><<<dim3(HID_ / 256, B_ * KOBJ), blk, 0, stream>>>(
      proj2b, c2, topi, g2, nullptr, HID_, 7);
  // ---- tail ----
  reduce_hh_kernel<<<dim3((B_ * HID_ + 255) / 256), blk, 0, stream>>>(g2, qenc, hhb);
  // o1: split-K z=8, KS=128
  gemm_mx<32, 128, 1, 4, false, false, false, 0, true><<<dim3(NO_P / 128, 1, 8), blk, 0, stream>>>(
      hhb, nullptr, wo1t, nullptr, nullptr, nullptr, nullptr, nullptr, partE, 128,
      B_, OUT_, HID_, KO2, KO2);
  reduce_split<2, true, true, false><<<dim3((B_ * KO2 + 255) / 256), blk, 0, stream>>>(
      partE, 8, (size_t)B_ * KO2, b_o1, nullptr, 0, nullptr, h1ob, nullptr,
      B_, OUT_, KO2, KO2);
  // o2: split-K z=8, KS=384
  gemm_mx<32, 128, 1, 4, false, false, false, 0, true><<<dim3(NO_P / 128, 1, 8), blk, 0, stream>>>(
      h1ob, nullptr, wo2t, nullptr, nullptr, nullptr, nullptr, nullptr, partE, 384,
      B_, OUT_, KO2, KO2, KO2);
  reduce_split<0, false, true, false><<<dim3((B_ * KO2 + 255) / 256), blk, 0, stream>>>(
      partE, 8, (size_t)B_ * KO2, b_o2, nullptr, 0, logits, nullptr, nullptr,
      B_, OUT_, KO2, OUT_);
}

// Round 7
// 371.532 us; speedup vs baseline: 4.0281x; 1.0627x over previous
//
#include <hip/hip_runtime.h>
#include <math.h>
#include <stdint.h>

#define B_    32
#define KOBJ  100
#define NS_   16
#define NK_   8
#define EMB_  1024
#define FEAT_ 2052
#define HID_  1024
#define OUT_  3000
#define COMB_ 512

#define KP1   2112   // FEAT_ padded to 64 (image rows / We1a rows)
#define KP2   2048   // 2*HID_
#define NO_P  3072   // OUT_ padded to 128 (N of o1/o2)
#define KO2   3008   // OUT_ padded to 64 (K of o2)

typedef __attribute__((ext_vector_type(8))) short s16x8;
typedef __attribute__((ext_vector_type(4))) float f32x4;

__device__ inline short f2bf(float f) {
  uint32_t u = __builtin_bit_cast(uint32_t, f);
  u = (u + 0x7fff + ((u >> 16) & 1)) >> 16;  // RNE
  return (short)u;
}
__device__ inline float bf2f(short s) {
  uint32_t u = ((uint32_t)(uint16_t)s) << 16;
  return __builtin_bit_cast(float, u);
}
__device__ inline void gload_lds16(const void* g, void* l) {
  __builtin_amdgcn_global_load_lds(
      (const __attribute__((address_space(1))) void*)g,
      (__attribute__((address_space(3))) void*)l, 16, 0, 0);
}
// XCD-aware bijective remap (m204): consecutive wg cluster on one XCD
__device__ inline int xcd_remap(int fid, int nwg) {
  int q = nwg >> 3, r = nwg & 7;
  int x = fid & 7, l = fid >> 3;
  return (x < r ? x * (q + 1) : r * (q + 1) + (x - r) * q) + l;
}

// ---------------- bb centres ----------------
__global__ void centres_kernel(const float* __restrict__ image, float* __restrict__ cent) {
  int i = blockIdx.x * blockDim.x + threadIdx.x;
  if (i >= B_ * KOBJ) return;
  const float* bb = image + (size_t)i * FEAT_ + (FEAT_ - 4);
  cent[i * 2 + 0] = 0.5f * (bb[0] + bb[2]);
  cent[i * 2 + 1] = 0.5f * (bb[1] + bb[3]);
}

// ---------------- f32 -> bf16 row-major convert with K padding (optional hi/lo split) ----
template <bool SPLIT>
__global__ void cvt_pad_rows(const float* __restrict__ in, short* __restrict__ outh,
                             short* __restrict__ outl, int K, int Kp, int total) {
  int idx = blockIdx.x * 256 + threadIdx.x;
  if (idx >= total) return;
  int row = idx / (Kp / 8), c8 = (idx % (Kp / 8)) * 8;
  float f[8];
  if (c8 + 8 <= K) {
    const float* src = in + (size_t)row * K + c8;
    float4 a = *(const float4*)src;
    float4 b = *(const float4*)(src + 4);
    f[0] = a.x; f[1] = a.y; f[2] = a.z; f[3] = a.w;
    f[4] = b.x; f[5] = b.y; f[6] = b.z; f[7] = b.w;
  } else {
#pragma unroll
    for (int i = 0; i < 8; ++i) {
      int k = c8 + i;
      f[i] = (k < K) ? in[(size_t)row * K + k] : 0.f;
    }
  }
  s16x8 vh, vl;
#pragma unroll
  for (int i = 0; i < 8; ++i) {
    short h = f2bf(f[i]);
    vh[i] = h;
    if (SPLIT) vl[i] = f2bf(f[i] - bf2f(h));
  }
  *(s16x8*)(outh + (size_t)row * Kp + c8) = vh;
  if (SPLIT) *(s16x8*)(outl + (size_t)row * Kp + c8) = vl;
}

// ---------------- transpose-convert weights to Bt[n][kp] bf16 (optional split) ----------
// CONV: in element (k,n) = in[((n/OPM)*K + k)*OPM + (n%OPM)]; else in[k*N + n]
template <bool CONV, bool SPLIT>
__global__ __launch_bounds__(256) void transpose_bf16(
    const float* __restrict__ in, short* __restrict__ outh, short* __restrict__ outl,
    int K, int N, int Kp, int OPM) {
  __shared__ float s[64][65];
  int k0 = blockIdx.x * 64, n0 = blockIdx.y * 64;
  int t = threadIdx.x;
  int rr = t >> 4;             // 0..15
  int c4 = (t & 15) * 4;       // 0..60
  bool fullN = CONV || (n0 + 64 <= N);
#pragma unroll
  for (int p = 0; p < 4; ++p) {
    int row = p * 16 + rr;
    int kg = k0 + row;
    float v0 = 0.f, v1 = 0.f, v2 = 0.f, v3 = 0.f;
    if (kg < K) {
      const float* src = CONV
          ? in + ((size_t)(n0 / OPM) * K + kg) * OPM + (n0 % OPM) + c4
          : in + (size_t)kg * N + n0 + c4;
      if (fullN) {
        float4 v = *(const float4*)src;
        v0 = v.x; v1 = v.y; v2 = v.z; v3 = v.w;
      } else {
        int nb = n0 + c4;
        if (nb + 0 < N) v0 = src[0];
        if (nb + 1 < N) v1 = src[1];
        if (nb + 2 < N) v2 = src[2];
        if (nb + 3 < N) v3 = src[3];
      }
    }
    s[row][c4 + 0] = v0; s[row][c4 + 1] = v1;
    s[row][c4 + 2] = v2; s[row][c4 + 3] = v3;
  }
  __syncthreads();
  int nl = t >> 2, kc = (t & 3) << 4;
#pragma unroll
  for (int half = 0; half < 2; ++half) {
    s16x8 vh, vl;
#pragma unroll
    for (int i = 0; i < 8; ++i) {
      float f = s[kc + half * 8 + i][nl];
      short h = f2bf(f);
      vh[i] = h;
      if (SPLIT) vl[i] = f2bf(f - bf2f(h));
    }
    short* o = outh + (size_t)(n0 + nl) * Kp + k0 + kc + half * 8;
    *(s16x8*)o = vh;
    if (SPLIT) *(s16x8*)(outl + (size_t)(n0 + nl) * Kp + k0 + kc + half * 8) = vl;
  }
}

// ---------------- unified MFMA GEMM ----------------
// C[M][N] = A[M][Kp] @ Bt[N][Kp]^T, bf16 MFMA, WR x WC waves.
// SPLIT: hi/lo 3-product split-f32. SPLITK: blockIdx.z k-chunks of KS -> f32
// partials in part[z][M][ldc] (bias/relu/omode applied later by reduce_split).
// OMODE: 0=f32, 1=bf16 hi/lo pair, 2=bf16. Writes cols [0,Nw), zero for n>=N.
template <int BM, int BN, int WR, int WC, bool SPLIT, bool RELU, bool BIAS, int OMODE, bool SPLITK>
__global__ __launch_bounds__(WR * WC * 64) void gemm_mx(
    const short* __restrict__ Ah, const short* __restrict__ Al,
    const short* __restrict__ Bh, const short* __restrict__ Bl,
    const float* __restrict__ bias,
    float* __restrict__ Cf, short* __restrict__ Ch, short* __restrict__ Cl,
    float* __restrict__ part, int KS,
    int M, int N, int Kp, int ldc, int Nw) {
  constexpr int NWV = WR * WC;
  constexpr int WM = BM / WR, WN = BN / WC;
  constexpr int FM = WM / 16, FN = WN / 16;
  constexpr int ACH = BM / 8, BCH = BN / 8;
  constexpr int NCH = (ACH + BCH) * (SPLIT ? 2 : 1);
  __shared__ short Ash[BM * 64];
  __shared__ short Bsh[BN * 64];
  __shared__ short Asl[SPLIT ? BM * 64 : 64];
  __shared__ short Bsl[SPLIT ? BN * 64 : 64];
  int tid = threadIdx.x, wave = tid >> 6, lane = tid & 63;
  int wr = wave / WC, wc = wave % WC;
  int r16 = lane & 15, kq = lane >> 4;
  int gx = gridDim.x, gy = gridDim.y, gz = gridDim.z;
  int fid = (blockIdx.z * gy + blockIdx.y) * gx + blockIdx.x;
  int wg = xcd_remap(fid, gx * gy * gz);
  int bx = wg % gx, byz = wg / gx;
  int by = byz % gy, bz = byz / gy;
  int m0 = by * BM, n0 = bx * BN;
  int kb = SPLITK ? bz * KS : 0;
  int ke = SPLITK ? (kb + KS < Kp ? kb + KS : Kp) : Kp;
  f32x4 acc[FM][FN] = {};

  for (int k0 = kb; k0 < ke; k0 += 64) {
    __syncthreads();
    for (int c = wave; c < NCH; c += NWV) {
      int cc = c;
      const short* g;
      char* l;
      bool isA;
      if (cc < ACH) { isA = true; g = Ah; l = (char*)Ash; }
      else if (SPLIT && cc < 2 * ACH) { cc -= ACH; isA = true; g = Al; l = (char*)Asl; }
      else {
        cc -= SPLIT ? 2 * ACH : ACH;
        if (cc < BCH) { isA = false; g = Bh; l = (char*)Bsh; }
        else { cc -= BCH; isA = false; g = Bl; l = (char*)Bsl; }
      }
      int Lb = cc * 1024 + lane * 16;
      int row = Lb >> 7;
      int off = (Lb & 127) ^ ((row & 7) << 4);
      const short* gsrc = g + (size_t)((isA ? m0 : n0) + row) * Kp + k0 + (off >> 1);
      gload_lds16(gsrc, l + cc * 1024);
    }
    __syncthreads();  // compiler drains vmcnt before barrier
#pragma unroll
    for (int kk = 0; kk < 2; ++kk) {
      int woff = kk * 64 + kq * 16;
      s16x8 ah[FM], al[FM], bh[FN], bl[FN];
#pragma unroll
      for (int f = 0; f < FM; ++f) {
        int row = wr * WM + f * 16 + r16;
        int o = woff ^ ((row & 7) << 4);
        ah[f] = *(const s16x8*)((const char*)Ash + row * 128 + o);
        if (SPLIT) al[f] = *(const s16x8*)((const char*)Asl + row * 128 + o);
      }
#pragma unroll
      for (int gg = 0; gg < FN; ++gg) {
        int row = wc * WN + gg * 16 + r16;
        int o = woff ^ ((row & 7) << 4);
        bh[gg] = *(const s16x8*)((const char*)Bsh + row * 128 + o);
        if (SPLIT) bl[gg] = *(const s16x8*)((const char*)Bsl + row * 128 + o);
      }
#pragma unroll
      for (int f = 0; f < FM; ++f)
#pragma unroll
        for (int gg = 0; gg < FN; ++gg) {
          acc[f][gg] = __builtin_amdgcn_mfma_f32_16x16x32_bf16(ah[f], bh[gg], acc[f][gg], 0, 0, 0);
          if (SPLIT) {
            acc[f][gg] = __builtin_amdgcn_mfma_f32_16x16x32_bf16(ah[f], bl[gg], acc[f][gg], 0, 0, 0);
            acc[f][gg] = __builtin_amdgcn_mfma_f32_16x16x32_bf16(al[f], bh[gg], acc[f][gg], 0, 0, 0);
          }
        }
    }
  }
#pragma unroll
  for (int f = 0; f < FM; ++f)
#pragma unroll
    for (int gg = 0; gg < FN; ++gg)
#pragma unroll
      for (int r = 0; r < 4; ++r) {
        int m = m0 + wr * WM + f * 16 + (lane >> 4) * 4 + r;
        int n = n0 + wc * WN + gg * 16 + r16;
        if (m >= M || n >= Nw) continue;
        float v = (n < N) ? acc[f][gg][r] : 0.f;
        size_t idx = (size_t)m * ldc + n;
        if (SPLITK) {
          part[(size_t)bz * M * ldc + idx] = v;
        } else {
          if (BIAS && n < N) v += bias[n];
          if (RELU) v = fmaxf(v, 0.f);
          if (OMODE == 0) Cf[idx] = v;
          else if (OMODE == 1) {
            short h = f2bf(v);
            Ch[idx] = h;
            Cl[idx] = f2bf(v - bf2f(h));
          } else {
            Ch[idx] = f2bf(v);
          }
        }
      }
}

// ---------------- split-K reduce (float4-vectorized): out = op(sum_z part[z] ...) ----------
// ldIn, ldOut, N multiples of 4; 4-element groups never straddle a row or the ldOut edge.
template <int OMODE, bool RELU, bool BIAS, bool BCAST>
__global__ void reduce_split(const float* __restrict__ part, int SK, size_t pstride,
                             const float* __restrict__ bias, const float* __restrict__ bcast,
                             int bcols, float* __restrict__ Cf, short* __restrict__ Ch,
                             short* __restrict__ Cl, int M, int N, int ldIn, int ldOut) {
  int idx4 = blockIdx.x * 256 + threadIdx.x;
  int ld4 = ldIn >> 2;
  if (idx4 >= M * ld4) return;
  int m = idx4 / ld4;
  int n = (idx4 - m * ld4) << 2;
  size_t base = (size_t)m * ldIn + n;
  float a[4] = {0.f, 0.f, 0.f, 0.f};
  for (int s = 0; s < SK; ++s) {
    float4 p = *(const float4*)(part + (size_t)s * pstride + base);
    a[0] += p.x; a[1] += p.y; a[2] += p.z; a[3] += p.w;
  }
#pragma unroll
  for (int j = 0; j < 4; ++j) {
    int nn = n + j;
    if (nn < N) {
      if (BCAST) a[j] += bcast[(size_t)(m / KOBJ) * bcols + nn];
      if (BIAS) a[j] += bias[nn];
    }
    if (RELU) a[j] = fmaxf(a[j], 0.f);
  }
  if (n >= ldOut) return;
  size_t o = (size_t)m * ldOut + n;
  if (OMODE == 0) {
    *(float4*)(Cf + o) = make_float4(a[0], a[1], a[2], a[3]);
  } else if (OMODE == 1) {
    short4 hh, ll;
    short* hp = (short*)&hh; short* lp = (short*)&ll;
#pragma unroll
    for (int j = 0; j < 4; ++j) {
      short h = f2bf(a[j]);
      hp[j] = h;
      lp[j] = f2bf(a[j] - bf2f(h));
    }
    *(short4*)(Ch + o) = hh;
    *(short4*)(Cl + o) = ll;
  } else {
    short4 hh;
    short* hp = (short*)&hh;
#pragma unroll
    for (int j = 0; j < 4; ++j) hp[j] = f2bf(a[j]);
    *(short4*)(Ch + o) = hh;
  }
}

// ---------------- adj[b] = h2[b] @ h2[b]^T, split-bf16 MFMA, one block/batch ----------------
__global__ __launch_bounds__(512) void adj_mfma(const short* __restrict__ Hh,
                                                const short* __restrict__ Hl,
                                                float* __restrict__ adj) {
  __shared__ short Ash[128 * 64];
  __shared__ short Asl[128 * 64];
  int tid = threadIdx.x, wave = tid >> 6, lane = tid & 63;
  int wr = wave >> 2, wc = wave & 3;        // 2x4 wave grid: WM=64, WN=32
  int r16 = lane & 15, kq = lane >> 4;
  int b = blockIdx.x;
  const short* baseh = Hh + (size_t)b * KOBJ * COMB_;
  const short* basel = Hl + (size_t)b * KOBJ * COMB_;
  f32x4 acc[4][2] = {};
  for (int k0 = 0; k0 < COMB_; k0 += 64) {
    __syncthreads();
    for (int c = wave; c < 32; c += 8) {    // 16 hi chunks + 16 lo chunks, 1 KB each
      int cc = c & 15;
      bool hi = c < 16;
      int Lb = cc * 1024 + lane * 16;
      int row = Lb >> 7;
      int off = (Lb & 127) ^ ((row & 7) << 4);
      const short* gsrc = (hi ? baseh : basel) + (size_t)row * COMB_ + k0 + (off >> 1);
      gload_lds16(gsrc, (char*)(hi ? Ash : Asl) + cc * 1024);
    }
    __syncthreads();
#pragma unroll
    for (int kk = 0; kk < 2; ++kk) {
      int woff = kk * 64 + kq * 16;
      s16x8 ah[4], al[4], bh[2], bl[2];
#pragma unroll
      for (int f = 0; f < 4; ++f) {
        int row = wr * 64 + f * 16 + r16;
        int o = woff ^ ((row & 7) << 4);
        ah[f] = *(const s16x8*)((const char*)Ash + row * 128 + o);
        al[f] = *(const s16x8*)((const char*)Asl + row * 128 + o);
      }
#pragma unroll
      for (int g = 0; g < 2; ++g) {
        int row = wc * 32 + g * 16 + r16;
        int o = woff ^ ((row & 7) << 4);
        bh[g] = *(const s16x8*)((const char*)Ash + row * 128 + o);
        bl[g] = *(const s16x8*)((const char*)Asl + row * 128 + o);
      }
#pragma unroll
      for (int f = 0; f < 4; ++f)
#pragma unroll
        for (int g = 0; g < 2; ++g) {
          acc[f][g] = __builtin_amdgcn_mfma_f32_16x16x32_bf16(ah[f], bh[g], acc[f][g], 0, 0, 0);
          acc[f][g] = __builtin_amdgcn_mfma_f32_16x16x32_bf16(ah[f], bl[g], acc[f][g], 0, 0, 0);
          acc[f][g] = __builtin_amdgcn_mfma_f32_16x16x32_bf16(al[f], bh[g], acc[f][g], 0, 0, 0);
        }
    }
  }
#pragma unroll
  for (int f = 0; f < 4; ++f)
#pragma unroll
    for (int g = 0; g < 2; ++g)
#pragma unroll
      for (int r = 0; r < 4; ++r) {
        int m = wr * 64 + f * 16 + (lane >> 4) * 4 + r;
        int n = wc * 32 + g * 16 + r16;
        if (m < KOBJ && n < KOBJ)
          adj[((size_t)b * KOBJ + m) * KOBJ + n] = acc[f][g][r];
      }
}

// ---------------- top-k + softmax + gaussian kernel weights ----------------
__global__ __launch_bounds__(256) void topk_weights_kernel(
    const float* __restrict__ adj, const float* __restrict__ cent,
    const float* __restrict__ mr1, const float* __restrict__ mt1,
    const float* __restrict__ pr1, const float* __restrict__ pt1,
    const float* __restrict__ mr2, const float* __restrict__ mt2,
    const float* __restrict__ pr2, const float* __restrict__ pt2,
    int* __restrict__ topi, float* __restrict__ c1, float* __restrict__ c2) {
  int row = blockIdx.x * 4 + (threadIdx.x >> 6);
  int lane = threadIdx.x & 63;
  int b = row / KOBJ, k = row % KOBJ;
  const float* ar = adj + (size_t)row * KOBJ;
  float v0 = (lane < KOBJ) ? ar[lane] : -INFINITY;
  float v1 = (lane + 64 < KOBJ) ? ar[lane + 64] : -INFINITY;
  int i0 = lane, i1 = lane + 64;
  float tv[NS_];
  int ti[NS_];
#pragma unroll
  for (int s = 0; s < NS_; ++s) {
    bool p0 = (v0 > v1) || (v0 == v1 && i0 < i1);
    float bv = p0 ? v0 : v1;
    int bi = p0 ? i0 : i1;
#pragma unroll
    for (int off = 32; off > 0; off >>= 1) {
      float ov = __shfl_xor(bv, off);
      int oi = __shfl_xor(bi, off);
      if (ov > bv || (ov == bv && oi < bi)) { bv = ov; bi = oi; }
    }
    tv[s] = bv; ti[s] = bi;
    if (bi == i0) v0 = -INFINITY;
    if (bi == i1) v1 = -INFINITY;
  }
  float mx = tv[0], sum = 0.f, av[NS_];
#pragma unroll
  for (int s = 0; s < NS_; ++s) { av[s] = expf(tv[s] - mx); sum += av[s]; }
  if (lane < NS_) {
    int j = ti[lane];
    topi[(size_t)row * NS_ + lane] = j;
    float cx = cent[(b * KOBJ + k) * 2 + 0], cy = cent[(b * KOBJ + k) * 2 + 1];
    float dx = cx - cent[(b * KOBJ + j) * 2 + 0];
    float dy = cy - cent[(b * KOBJ + j) * 2 + 1];
    float rho = sqrtf(dx * dx + dy * dy);
    float th = atan2f(dx, dy);
    float w1[NK_], w2[NK_], s1 = 0.f, s2 = 0.f;
#pragma unroll
    for (int m = 0; m < NK_; ++m) {
      {
        float pr = pr1[m], pt = pt1[m], dr = rho - mr1[m];
        float wr = expf(-0.5f * dr * dr / (1e-14f + pr * pr));
        float fa = fabsf(th - mt1[m]);
        float sa = fabsf(6.283185307179586f - fa);
        float da = fminf(fa, sa);
        float wt = expf(-0.5f * da * da / (1e-14f + pt * pt));
        float w = wr * wt;
        if (w != w) w = 0.f;
        w1[m] = w; s1 += w;
      }
      {
        float pr = pr2[m], pt = pt2[m], dr = rho - mr2[m];
        float wr = expf(-0.5f * dr * dr / (1e-14f + pr * pr));
        float fa = fabsf(th - mt2[m]);
        float sa = fabsf(6.283185307179586f - fa);
        float da = fminf(fa, sa);
        float wt = expf(-0.5f * da * da / (1e-14f + pt * pt));
        float w = wr * wt;
        if (w != w) w = 0.f;
        w2[m] = w; s2 += w;
      }
    }
    float as = av[lane] / sum;
#pragma unroll
    for (int m = 0; m < NK_; ++m) {
      c1[((size_t)row * NS_ + lane) * NK_ + m] = as * (w1[m] / s1);
      c2[((size_t)row * NS_ + lane) * NK_ + m] = w2[m] / s2;
    }
  }
}

// ---------------- gather-combine (bf16 proj in), VEC cols/thread, one block/row ----------
// VEC=8 -> s16x8 loads (N=2048); VEC=4 -> short4 (N=1024). VEC-group never crosses an
// m-boundary (group size divides 1<<mshift and n is VEC-aligned).
template <int VEC, bool BF16OUT>
__global__ __launch_bounds__(256) void combine_kernel(
    const short* __restrict__ proj, const float* __restrict__ coeff,
    const int* __restrict__ topi, float* __restrict__ outf, short* __restrict__ outb,
    int N, int mshift) {
  int row = xcd_remap(blockIdx.x, gridDim.x);
  int b = row / KOBJ;
  __shared__ int ids[NS_];
  __shared__ float cs[NS_ * NK_];
  int tid = threadIdx.x;
  if (tid < NS_) ids[tid] = topi[(size_t)row * NS_ + tid];
  else if (tid >= 32 && tid < 32 + NS_ * NK_) cs[tid - 32] = coeff[(size_t)row * NS_ * NK_ + (tid - 32)];
  __syncthreads();
  int n = tid * VEC;
  if (n >= N) return;
  int m = n >> mshift;
  float acc[VEC];
#pragma unroll
  for (int j = 0; j < VEC; ++j) acc[j] = 0.f;
#pragma unroll
  for (int s = 0; s < NS_; ++s) {
    float cc = cs[s * NK_ + m];
    const short* p = proj + ((size_t)b * KOBJ + ids[s]) * N + n;
    if (VEC == 8) {
      s16x8 v = *(const s16x8*)p;
#pragma unroll
      for (int j = 0; j < 8; ++j) acc[j] = fmaf(cc, bf2f(v[j]), acc[j]);
    } else {
      short4 v = *(const short4*)p;
      const short* vp = (const short*)&v;
#pragma unroll
      for (int j = 0; j < 4; ++j) acc[j] = fmaf(cc, bf2f(vp[j]), acc[j]);
    }
  }
#pragma unroll
  for (int j = 0; j < VEC; ++j) acc[j] = fmaxf(acc[j], 0.f);
  if (BF16OUT) {
    if (VEC == 8) {
      s16x8 o;
#pragma unroll
      for (int j = 0; j < 8; ++j) o[j] = f2bf(acc[j]);
      *(s16x8*)(outb + (size_t)row * N + n) = o;
    } else {
      short4 o;
      short* op = (short*)&o;
#pragma unroll
      for (int j = 0; j < 4; ++j) op[j] = f2bf(acc[j]);
      *(short4*)(outb + (size_t)row * N + n) = o;
    }
  } else {
    if (VEC == 4) {
      *(float4*)(outf + (size_t)row * N + n) = make_float4(acc[0], acc[1], acc[2], acc[3]);
    } else {
#pragma unroll
      for (int j = 0; j < VEC; ++j) outf[(size_t)row * N + n + j] = acc[j];
    }
  }
}

// ---------------- max over k, then hh = relu(qenc) * g2max (bf16 out) ----------------
__global__ void reduce_hh_kernel(const float* __restrict__ g2, const float* __restrict__ qenc,
                                 short* __restrict__ hhb) {
  int i = blockIdx.x * blockDim.x + threadIdx.x;
  if (i >= B_ * HID_) return;
  int b = i >> 10, n = i & (HID_ - 1);
  const float* p = g2 + (size_t)b * KOBJ * HID_ + n;
  float mx = -INFINITY;
  for (int k = 0; k < KOBJ; ++k) mx = fmaxf(mx, p[(size_t)k * HID_]);
  hhb[i] = f2bf(fmaxf(qenc[i], 0.f) * mx);
}

extern "C" void kernel_launch(void* const* d_in, const int* in_sizes, int n_in,
                              void* d_out, int out_size, void* d_ws, size_t ws_size,
                              hipStream_t stream) {
  const float* question = (const float*)d_in[0];
  const float* image    = (const float*)d_in[1];
  const float* W_lproj  = (const float*)d_in[3];
  const float* b_lproj  = (const float*)d_in[4];
  const float* W_e1     = (const float*)d_in[5];
  const float* b_e1     = (const float*)d_in[6];
  const float* W_e2     = (const float*)d_in[7];
  const float* b_e2     = (const float*)d_in[8];
  const float* conv_w1  = (const float*)d_in[9];
  const float* mr1 = (const float*)d_in[10];
  const float* mt1 = (const float*)d_in[11];
  const float* pr1 = (const float*)d_in[12];
  const float* pt1 = (const float*)d_in[13];
  const float* conv_w2  = (const float*)d_in[14];
  const float* mr2 = (const float*)d_in[15];
  const float* mt2 = (const float*)d_in[16];
  const float* pr2 = (const float*)d_in[17];
  const float* pt2 = (const float*)d_in[18];
  const float* W_o1 = (const float*)d_in[19];
  const float* b_o1 = (const float*)d_in[20];
  const float* W_o2 = (const float*)d_in[21];
  const float* b_o2 = (const float*)d_in[22];

  float* out = (float*)d_out;
  float* logits = out;               // [32,3000]
  float* adj = out + B_ * OUT_;      // [32,100,100]

  char* ws = (char*)d_ws;
  size_t off = 0;
  auto alloc = [&](size_t bytes) { char* p = ws + off; off += (bytes + 255) & ~((size_t)255); return p; };
  float* qenc  = (float*)alloc((size_t)B_ * HID_ * 4);
  short* qh    = (short*)alloc((size_t)B_ * EMB_ * 2);
  short* ql    = (short*)alloc((size_t)B_ * EMB_ * 2);
  short* qeh   = (short*)alloc((size_t)B_ * HID_ * 2);
  short* qel   = (short*)alloc((size_t)B_ * HID_ * 2);
  short* wlph  = (short*)alloc((size_t)EMB_ * HID_ * 2);
  short* wlpl  = (short*)alloc((size_t)EMB_ * HID_ * 2);
  short* we1ah = (short*)alloc((size_t)COMB_ * KP1 * 2);
  short* we1al = (short*)alloc((size_t)COMB_ * KP1 * 2);
  short* we1bh = (short*)alloc((size_t)COMB_ * HID_ * 2);
  short* we1bl = (short*)alloc((size_t)COMB_ * HID_ * 2);
  short* we2h  = (short*)alloc((size_t)COMB_ * COMB_ * 2);
  short* we2l  = (short*)alloc((size_t)COMB_ * COMB_ * 2);
  float* q1    = (float*)alloc((size_t)B_ * COMB_ * 4);
  short* h1h   = (short*)alloc((size_t)B_ * KOBJ * COMB_ * 2);
  short* h1l   = (short*)alloc((size_t)B_ * KOBJ * COMB_ * 2);
  short* h2h   = (short*)alloc((size_t)(B_ * KOBJ + 128) * COMB_ * 2);  // +pad rows for adj over-read
  short* h2l   = (short*)alloc((size_t)(B_ * KOBJ + 128) * COMB_ * 2);
  float* cent  = (float*)alloc((size_t)B_ * KOBJ * 2 * 4);
  int*   topi  = (int*)alloc((size_t)B_ * KOBJ * NS_ * 4);
  float* c1    = (float*)alloc((size_t)B_ * KOBJ * NS_ * NK_ * 4);
  float* c2    = (float*)alloc((size_t)B_ * KOBJ * NS_ * NK_ * 4);
  short* imgb  = (short*)alloc((size_t)B_ * KOBJ * KP1 * 2);
  short* imgl  = (short*)alloc((size_t)B_ * KOBJ * KP1 * 2);
  short* cw1t  = (short*)alloc((size_t)(2 * HID_) * KP1 * 2);
  short* cw2t  = (short*)alloc((size_t)HID_ * KP2 * 2);
  short* proj1b = (short*)alloc((size_t)B_ * KOBJ * 2 * HID_ * 2);
  short* g1b   = (short*)alloc((size_t)B_ * KOBJ * KP2 * 2);
  short* proj2b = (short*)alloc((size_t)B_ * KOBJ * HID_ * 2);
  float* g2    = (float*)alloc((size_t)B_ * KOBJ * HID_ * 4);
  short* hhb   = (short*)alloc((size_t)B_ * HID_ * 2);
  short* wo1t  = (short*)alloc((size_t)NO_P * HID_ * 2);
  short* wo2t  = (short*)alloc((size_t)NO_P * KO2 * 2);
  short* h1ob  = (short*)alloc((size_t)B_ * KO2 * 2);
  float* partE = (float*)alloc((size_t)4 * B_ * KOBJ * COMB_ * 4);  // 26.2 MB, max over users
  (void)ws_size; (void)in_sizes; (void)n_in; (void)out_size;

  dim3 blk(256), blk512(512);

  // ---- independent prep ----
  centres_kernel<<<dim3((B_ * KOBJ + 255) / 256), blk, 0, stream>>>(image, cent);
  {
    int total = B_ * KOBJ * (KP1 / 8);
    cvt_pad_rows<true><<<dim3((total + 255) / 256), blk, 0, stream>>>(image, imgb, imgl, FEAT_, KP1, total);
  }
  {
    int total = B_ * (EMB_ / 8);
    cvt_pad_rows<true><<<dim3((total + 255) / 256), blk, 0, stream>>>(question, qh, ql, EMB_, EMB_, total);
  }
  transpose_bf16<false, true><<<dim3(EMB_ / 64, HID_ / 64), blk, 0, stream>>>(
      W_lproj, wlph, wlpl, EMB_, HID_, EMB_, 0);
  transpose_bf16<false, true><<<dim3(KP1 / 64, COMB_ / 64), blk, 0, stream>>>(
      W_e1, we1ah, we1al, FEAT_, COMB_, KP1, 0);
  transpose_bf16<false, true><<<dim3(HID_ / 64, COMB_ / 64), blk, 0, stream>>>(
      W_e1 + (size_t)FEAT_ * COMB_, we1bh, we1bl, HID_, COMB_, HID_, 0);
  transpose_bf16<false, true><<<dim3(COMB_ / 64, COMB_ / 64), blk, 0, stream>>>(
      W_e2, we2h, we2l, COMB_, COMB_, COMB_, 0);
  transpose_bf16<true, false><<<dim3(KP1 / 64, (2 * HID_) / 64), blk, 0, stream>>>(
      conv_w1, cw1t, nullptr, FEAT_, 2 * HID_, KP1, 2 * HID_ / NK_);
  transpose_bf16<true, false><<<dim3(KP2 / 64, HID_ / 64), blk, 0, stream>>>(
      conv_w2, cw2t, nullptr, 2 * HID_, HID_, KP2, HID_ / NK_);
  transpose_bf16<false, false><<<dim3(HID_ / 64, NO_P / 64), blk, 0, stream>>>(
      W_o1, wo1t, nullptr, HID_, OUT_, HID_, 0);
  transpose_bf16<false, false><<<dim3(KO2 / 64, NO_P / 64), blk, 0, stream>>>(
      W_o2, wo2t, nullptr, OUT_, OUT_, KO2, 0);

  // ---- qenc = question @ W_lproj + b (split, f32) ----
  gemm_mx<32, 64, 2, 2, true, false, true, 0, false><<<dim3(HID_ / 64, 1, 1), blk, 0, stream>>>(
      qh, ql, wlph, wlpl, b_lproj, qenc, nullptr, nullptr, nullptr, 0, B_, HID_, EMB_, HID_, HID_);
  // ---- split qenc for q1 ----
  {
    int total = B_ * (HID_ / 8);
    cvt_pad_rows<true><<<dim3((total + 255) / 256), blk, 0, stream>>>(qenc, qeh, qel, HID_, HID_, total);
  }
  // ---- q1 = qenc @ We1[2052:] (split, no bias) ----
  gemm_mx<32, 64, 2, 2, true, false, false, 0, false><<<dim3(COMB_ / 64, 1, 1), blk, 0, stream>>>(
      qeh, qel, we1bh, we1bl, nullptr, q1, nullptr, nullptr, nullptr, 0, B_, COMB_, HID_, COMB_, COMB_);
  // ---- e1 image part: split-K partials (z=4, KS=576) ----
  gemm_mx<128, 64, 4, 2, true, false, false, 0, true><<<dim3(COMB_ / 64, B_ * KOBJ / 128, 4), blk512, 0, stream>>>(
      imgb, imgl, we1ah, we1al, nullptr, nullptr, nullptr, nullptr, partE, 576,
      B_ * KOBJ, COMB_, KP1, COMB_, COMB_);
  // ---- h1 = relu(sum + q1[bcast] + b_e1), bf16 hi/lo ----
  reduce_split<1, true, true, true><<<dim3(B_ * KOBJ * COMB_ / 4 / 256), blk, 0, stream>>>(
      partE, 4, (size_t)B_ * KOBJ * COMB_, b_e1, q1, COMB_, nullptr, h1h, h1l,
      B_ * KOBJ, COMB_, COMB_, COMB_);
  // ---- e2: split-K partials (z=4, KS=128) ----
  gemm_mx<128, 64, 4, 2, true, false, false, 0, true><<<dim3(COMB_ / 64, B_ * KOBJ / 128, 4), blk512, 0, stream>>>(
      h1h, h1l, we2h, we2l, nullptr, nullptr, nullptr, nullptr, partE, 128,
      B_ * KOBJ, COMB_, COMB_, COMB_, COMB_);
  // ---- h2 = relu(sum + b_e2) as bf16 hi/lo (feeds adj MFMA) ----
  reduce_split<1, true, true, false><<<dim3(B_ * KOBJ * COMB_ / 4 / 256), blk, 0, stream>>>(
      partE, 4, (size_t)B_ * KOBJ * COMB_, b_e2, nullptr, 0, nullptr, h2h, h2l,
      B_ * KOBJ, COMB_, COMB_, COMB_);
  // ---- adj (split-bf16 MFMA, Gram) + topk ----
  adj_mfma<<<dim3(B_), blk512, 0, stream>>>(h2h, h2l, adj);
  topk_weights_kernel<<<dim3(B_ * KOBJ / 4), blk, 0, stream>>>(
      adj, cent, mr1, mt1, pr1, pt1, mr2, mt2, pr2, pt2, topi, c1, c2);
  // ---- conv path ----
  // proj1: 128x64 tile -> 800 blocks (occupancy; was 400 at 128x128)
  gemm_mx<128, 64, 4, 2, false, false, false, 2, false><<<dim3(2 * HID_ / 64, B_ * KOBJ / 128, 1), blk512, 0, stream>>>(
      imgb, nullptr, cw1t, nullptr, nullptr, nullptr, proj1b, nullptr, nullptr, 0,
      B_ * KOBJ, 2 * HID_, KP1, 2 * HID_, 2 * HID_);
  combine_kernel<8, true><<<dim3(B_ * KOBJ), blk, 0, stream>>>(
      proj1b, c1, topi, nullptr, g1b, 2 * HID_, 8);
  // proj2: 64x64 tile -> 800 blocks
  gemm_mx<64, 64, 2, 2, false, false, false, 2, false><<<dim3(HID_ / 64, B_ * KOBJ / 64, 1), blk, 0, stream>>>(
      g1b, nullptr, cw2t, nullptr, nullptr, nullptr, proj2b, nullptr, nullptr, 0,
      B_ * KOBJ, HID_, KP2, HID_, HID_);
  combine_kernel<4, false><<<dim3(B_ * KOBJ), blk, 0, stream>>>(
      proj2b, c2, topi, g2, nullptr, HID_, 7);
  // ---- tail ----
  reduce_hh_kernel<<<dim3((B_ * HID_ + 255) / 256), blk, 0, stream>>>(g2, qenc, hhb);
  // o1: split-K z=16, KS=64
  gemm_mx<32, 128, 1, 4, false, false, false, 0, true><<<dim3(NO_P / 128, 1, 16), blk, 0, stream>>>(
      hhb, nullptr, wo1t, nullptr, nullptr, nullptr, nullptr, nullptr, partE, 64,
      B_, OUT_, HID_, KO2, KO2);
  reduce_split<2, true, true, false><<<dim3((B_ * KO2 / 4 + 255) / 256), blk, 0, stream>>>(
      partE, 16, (size_t)B_ * KO2, b_o1, nullptr, 0, nullptr, h1ob, nullptr,
      B_, OUT_, KO2, KO2);
  // o2: split-K z=16, KS=192
  gemm_mx<32, 128, 1, 4, false, false, false, 0, true><<<dim3(NO_P / 128, 1, 16), blk, 0, stream>>>(
      h1ob, nullptr, wo2t, nullptr, nullptr, nullptr, nullptr, nullptr, partE, 192,
      B_, OUT_, KO2, KO2, KO2);
  reduce_split<0, false, true, false><<<dim3((B_ * KO2 / 4 + 255) / 256), blk, 0, stream>>>(
      partE, 16, (size_t)B_ * KO2, b_o2, nullptr, 0, logits, nullptr, nullptr,
      B_, OUT_, KO2, OUT_);
}

// Round 8
// 356.618 us; speedup vs baseline: 4.1966x; 1.0418x over previous
//
#include <hip/hip_runtime.h>
#include <math.h>
#include <stdint.h>

#define B_    32
#define KOBJ  100
#define NS_   16
#define NK_   8
#define EMB_  1024
#define FEAT_ 2052
#define HID_  1024
#define OUT_  3000
#define COMB_ 512

#define KP1   2112   // FEAT_ padded to 64 (image rows / We1a rows)
#define KP2   2048   // 2*HID_
#define NO_P  3072   // OUT_ padded to 128 (N of o1/o2)
#define KO2   3008   // OUT_ padded to 64 (K of o2)

typedef __attribute__((ext_vector_type(8))) short s16x8;
typedef __attribute__((ext_vector_type(4))) float f32x4;

__device__ inline short f2bf(float f) {
  uint32_t u = __builtin_bit_cast(uint32_t, f);
  u = (u + 0x7fff + ((u >> 16) & 1)) >> 16;  // RNE
  return (short)u;
}
__device__ inline float bf2f(short s) {
  uint32_t u = ((uint32_t)(uint16_t)s) << 16;
  return __builtin_bit_cast(float, u);
}
__device__ inline void gload_lds16(const void* g, void* l) {
  __builtin_amdgcn_global_load_lds(
      (const __attribute__((address_space(1))) void*)g,
      (__attribute__((address_space(3))) void*)l, 16, 0, 0);
}
// XCD-aware bijective remap (m204): consecutive wg cluster on one XCD
__device__ inline int xcd_remap(int fid, int nwg) {
  int q = nwg >> 3, r = nwg & 7;
  int x = fid & 7, l = fid >> 3;
  return (x < r ? x * (q + 1) : r * (q + 1) + (x - r) * q) + l;
}

// ---------------- fused input prep: image cvt(split) + question cvt(split) + centres ----
#define IMG_CHUNKS (B_ * KOBJ * (KP1 / 8))
#define IMG_BLKS   ((IMG_CHUNKS + 255) / 256)
#define Q_CHUNKS   (B_ * (EMB_ / 8))
#define Q_BLKS     ((Q_CHUNKS + 255) / 256)
#define C_BLKS     ((B_ * KOBJ + 255) / 256)

__device__ inline void cvt8_split(const float* __restrict__ in, short* __restrict__ oh,
                                  short* __restrict__ ol, int K, int Kp, int idx) {
  int row = idx / (Kp / 8), c8 = (idx % (Kp / 8)) * 8;
  float f[8];
  if (c8 + 8 <= K) {
    const float* src = in + (size_t)row * K + c8;
    float4 a = *(const float4*)src;
    float4 b = *(const float4*)(src + 4);
    f[0] = a.x; f[1] = a.y; f[2] = a.z; f[3] = a.w;
    f[4] = b.x; f[5] = b.y; f[6] = b.z; f[7] = b.w;
  } else {
#pragma unroll
    for (int i = 0; i < 8; ++i) {
      int k = c8 + i;
      f[i] = (k < K) ? in[(size_t)row * K + k] : 0.f;
    }
  }
  s16x8 vh, vl;
#pragma unroll
  for (int i = 0; i < 8; ++i) {
    short h = f2bf(f[i]);
    vh[i] = h;
    vl[i] = f2bf(f[i] - bf2f(h));
  }
  *(s16x8*)(oh + (size_t)row * Kp + c8) = vh;
  *(s16x8*)(ol + (size_t)row * Kp + c8) = vl;
}

__global__ __launch_bounds__(256) void prep_inputs(
    const float* __restrict__ image, const float* __restrict__ question,
    short* __restrict__ imgb, short* __restrict__ imgl,
    short* __restrict__ qh, short* __restrict__ ql, float* __restrict__ cent) {
  int bb = blockIdx.x, tid = threadIdx.x;
  if (bb < IMG_BLKS) {
    int idx = bb * 256 + tid;
    if (idx < IMG_CHUNKS) cvt8_split(image, imgb, imgl, FEAT_, KP1, idx);
  } else if (bb < IMG_BLKS + Q_BLKS) {
    int idx = (bb - IMG_BLKS) * 256 + tid;
    if (idx < Q_CHUNKS) cvt8_split(question, qh, ql, EMB_, EMB_, idx);
  } else {
    int i = (bb - IMG_BLKS - Q_BLKS) * 256 + tid;
    if (i < B_ * KOBJ) {
      const float* bbx = image + (size_t)i * FEAT_ + (FEAT_ - 4);
      cent[i * 2 + 0] = 0.5f * (bbx[0] + bbx[2]);
      cent[i * 2 + 1] = 0.5f * (bbx[1] + bbx[3]);
    }
  }
}

// ---------------- f32 -> bf16 split convert (qenc only now) ----------------
__global__ void cvt_pad_rows_split(const float* __restrict__ in, short* __restrict__ outh,
                                   short* __restrict__ outl, int K, int Kp, int total) {
  int idx = blockIdx.x * 256 + threadIdx.x;
  if (idx < total) cvt8_split(in, outh, outl, K, Kp, idx);
}

// ---------------- one-dispatch transpose of all weights ----------------
// For each descriptor: out[n][kp] (bf16, optional lo part) = in(k,n); conv flag selects
// conv_w layout in[((n/OPM)*K + k)*OPM + n%OPM], else in[k*N + n].
struct TD {
  const float* in; short* oh; short* ol;
  int K, N, Kp, OPM, nkt, split, conv, cum;  // cum = exclusive prefix end of tiles
};
struct TDs { TD d[8]; };

__global__ __launch_bounds__(256) void transpose_all(TDs ds) {
  __shared__ float s[64][65];
  int bid = blockIdx.x;
  int i = 0;
  while (i < 7 && bid >= ds.d[i].cum) ++i;
  const TD& d = ds.d[i];
  int local = bid - (i ? ds.d[i - 1].cum : 0);
  int k0 = (local % d.nkt) * 64, n0 = (local / d.nkt) * 64;
  int t = threadIdx.x;
  int rr = t >> 4, c4 = (t & 15) * 4;
  bool fullN = d.conv || (n0 + 64 <= d.N);
#pragma unroll
  for (int p = 0; p < 4; ++p) {
    int row = p * 16 + rr;
    int kg = k0 + row;
    float v0 = 0.f, v1 = 0.f, v2 = 0.f, v3 = 0.f;
    if (kg < d.K) {
      const float* src = d.conv
          ? d.in + ((size_t)(n0 / d.OPM) * d.K + kg) * d.OPM + (n0 % d.OPM) + c4
          : d.in + (size_t)kg * d.N + n0 + c4;
      if (fullN) {
        float4 v = *(const float4*)src;
        v0 = v.x; v1 = v.y; v2 = v.z; v3 = v.w;
      } else {
        int nb = n0 + c4;
        if (nb + 0 < d.N) v0 = src[0];
        if (nb + 1 < d.N) v1 = src[1];
        if (nb + 2 < d.N) v2 = src[2];
        if (nb + 3 < d.N) v3 = src[3];
      }
    }
    s[row][c4 + 0] = v0; s[row][c4 + 1] = v1;
    s[row][c4 + 2] = v2; s[row][c4 + 3] = v3;
  }
  __syncthreads();
  int nl = t >> 2, kc = (t & 3) << 4;
#pragma unroll
  for (int half = 0; half < 2; ++half) {
    s16x8 vh, vl;
#pragma unroll
    for (int j = 0; j < 8; ++j) {
      float f = s[kc + half * 8 + j][nl];
      short h = f2bf(f);
      vh[j] = h;
      vl[j] = f2bf(f - bf2f(h));
    }
    size_t o = (size_t)(n0 + nl) * d.Kp + k0 + kc + half * 8;
    *(s16x8*)(d.oh + o) = vh;
    if (d.split) *(s16x8*)(d.ol + o) = vl;
  }
}

// ---------------- unified MFMA GEMM ----------------
template <int BM, int BN, int WR, int WC, bool SPLIT, bool RELU, bool BIAS, int OMODE, bool SPLITK>
__global__ __launch_bounds__(WR * WC * 64) void gemm_mx(
    const short* __restrict__ Ah, const short* __restrict__ Al,
    const short* __restrict__ Bh, const short* __restrict__ Bl,
    const float* __restrict__ bias,
    float* __restrict__ Cf, short* __restrict__ Ch, short* __restrict__ Cl,
    float* __restrict__ part, int KS,
    int M, int N, int Kp, int ldc, int Nw) {
  constexpr int NWV = WR * WC;
  constexpr int WM = BM / WR, WN = BN / WC;
  constexpr int FM = WM / 16, FN = WN / 16;
  constexpr int ACH = BM / 8, BCH = BN / 8;
  constexpr int NCH = (ACH + BCH) * (SPLIT ? 2 : 1);
  __shared__ short Ash[BM * 64];
  __shared__ short Bsh[BN * 64];
  __shared__ short Asl[SPLIT ? BM * 64 : 64];
  __shared__ short Bsl[SPLIT ? BN * 64 : 64];
  int tid = threadIdx.x, wave = tid >> 6, lane = tid & 63;
  int wr = wave / WC, wc = wave % WC;
  int r16 = lane & 15, kq = lane >> 4;
  int gx = gridDim.x, gy = gridDim.y, gz = gridDim.z;
  int fid = (blockIdx.z * gy + blockIdx.y) * gx + blockIdx.x;
  int wg = xcd_remap(fid, gx * gy * gz);
  int bx = wg % gx, byz = wg / gx;
  int by = byz % gy, bz = byz / gy;
  int m0 = by * BM, n0 = bx * BN;
  int kb = SPLITK ? bz * KS : 0;
  int ke = SPLITK ? (kb + KS < Kp ? kb + KS : Kp) : Kp;
  f32x4 acc[FM][FN] = {};

  for (int k0 = kb; k0 < ke; k0 += 64) {
    __syncthreads();
    for (int c = wave; c < NCH; c += NWV) {
      int cc = c;
      const short* g;
      char* l;
      bool isA;
      if (cc < ACH) { isA = true; g = Ah; l = (char*)Ash; }
      else if (SPLIT && cc < 2 * ACH) { cc -= ACH; isA = true; g = Al; l = (char*)Asl; }
      else {
        cc -= SPLIT ? 2 * ACH : ACH;
        if (cc < BCH) { isA = false; g = Bh; l = (char*)Bsh; }
        else { cc -= BCH; isA = false; g = Bl; l = (char*)Bsl; }
      }
      int Lb = cc * 1024 + lane * 16;
      int row = Lb >> 7;
      int off = (Lb & 127) ^ ((row & 7) << 4);
      const short* gsrc = g + (size_t)((isA ? m0 : n0) + row) * Kp + k0 + (off >> 1);
      gload_lds16(gsrc, l + cc * 1024);
    }
    __syncthreads();  // compiler drains vmcnt before barrier
#pragma unroll
    for (int kk = 0; kk < 2; ++kk) {
      int woff = kk * 64 + kq * 16;
      s16x8 ah[FM], al[FM], bh[FN], bl[FN];
#pragma unroll
      for (int f = 0; f < FM; ++f) {
        int row = wr * WM + f * 16 + r16;
        int o = woff ^ ((row & 7) << 4);
        ah[f] = *(const s16x8*)((const char*)Ash + row * 128 + o);
        if (SPLIT) al[f] = *(const s16x8*)((const char*)Asl + row * 128 + o);
      }
#pragma unroll
      for (int gg = 0; gg < FN; ++gg) {
        int row = wc * WN + gg * 16 + r16;
        int o = woff ^ ((row & 7) << 4);
        bh[gg] = *(const s16x8*)((const char*)Bsh + row * 128 + o);
        if (SPLIT) bl[gg] = *(const s16x8*)((const char*)Bsl + row * 128 + o);
      }
#pragma unroll
      for (int f = 0; f < FM; ++f)
#pragma unroll
        for (int gg = 0; gg < FN; ++gg) {
          acc[f][gg] = __builtin_amdgcn_mfma_f32_16x16x32_bf16(ah[f], bh[gg], acc[f][gg], 0, 0, 0);
          if (SPLIT) {
            acc[f][gg] = __builtin_amdgcn_mfma_f32_16x16x32_bf16(ah[f], bl[gg], acc[f][gg], 0, 0, 0);
            acc[f][gg] = __builtin_amdgcn_mfma_f32_16x16x32_bf16(al[f], bh[gg], acc[f][gg], 0, 0, 0);
          }
        }
    }
  }
#pragma unroll
  for (int f = 0; f < FM; ++f)
#pragma unroll
    for (int gg = 0; gg < FN; ++gg)
#pragma unroll
      for (int r = 0; r < 4; ++r) {
        int m = m0 + wr * WM + f * 16 + (lane >> 4) * 4 + r;
        int n = n0 + wc * WN + gg * 16 + r16;
        if (m >= M || n >= Nw) continue;
        float v = (n < N) ? acc[f][gg][r] : 0.f;
        size_t idx = (size_t)m * ldc + n;
        if (SPLITK) {
          part[(size_t)bz * M * ldc + idx] = v;
        } else {
          if (BIAS && n < N) v += bias[n];
          if (RELU) v = fmaxf(v, 0.f);
          if (OMODE == 0) Cf[idx] = v;
          else if (OMODE == 1) {
            short h = f2bf(v);
            Ch[idx] = h;
            Cl[idx] = f2bf(v - bf2f(h));
          } else {
            Ch[idx] = f2bf(v);
          }
        }
      }
}

// ---------------- split-K reduce (float4-vectorized) ----------------
template <int OMODE, bool RELU, bool BIAS, bool BCAST>
__global__ void reduce_split(const float* __restrict__ part, int SK, size_t pstride,
                             const float* __restrict__ bias, const float* __restrict__ bcast,
                             int bcols, float* __restrict__ Cf, short* __restrict__ Ch,
                             short* __restrict__ Cl, int M, int N, int ldIn, int ldOut) {
  int idx4 = blockIdx.x * 256 + threadIdx.x;
  int ld4 = ldIn >> 2;
  if (idx4 >= M * ld4) return;
  int m = idx4 / ld4;
  int n = (idx4 - m * ld4) << 2;
  size_t base = (size_t)m * ldIn + n;
  float a[4] = {0.f, 0.f, 0.f, 0.f};
  for (int s = 0; s < SK; ++s) {
    float4 p = *(const float4*)(part + (size_t)s * pstride + base);
    a[0] += p.x; a[1] += p.y; a[2] += p.z; a[3] += p.w;
  }
#pragma unroll
  for (int j = 0; j < 4; ++j) {
    int nn = n + j;
    if (nn < N) {
      if (BCAST) a[j] += bcast[(size_t)(m / KOBJ) * bcols + nn];
      if (BIAS) a[j] += bias[nn];
    }
    if (RELU) a[j] = fmaxf(a[j], 0.f);
  }
  if (n >= ldOut) return;
  size_t o = (size_t)m * ldOut + n;
  if (OMODE == 0) {
    *(float4*)(Cf + o) = make_float4(a[0], a[1], a[2], a[3]);
  } else if (OMODE == 1) {
    short4 hh, ll;
    short* hp = (short*)&hh; short* lp = (short*)&ll;
#pragma unroll
    for (int j = 0; j < 4; ++j) {
      short h = f2bf(a[j]);
      hp[j] = h;
      lp[j] = f2bf(a[j] - bf2f(h));
    }
    *(short4*)(Ch + o) = hh;
    *(short4*)(Cl + o) = ll;
  } else {
    short4 hh;
    short* hp = (short*)&hh;
#pragma unroll
    for (int j = 0; j < 4; ++j) hp[j] = f2bf(a[j]);
    *(short4*)(Ch + o) = hh;
  }
}

// ---------------- adj[b] = h2[b] @ h2[b]^T, split-bf16 MFMA, one block/batch ----------------
__global__ __launch_bounds__(512) void adj_mfma(const short* __restrict__ Hh,
                                                const short* __restrict__ Hl,
                                                float* __restrict__ adj) {
  __shared__ short Ash[128 * 64];
  __shared__ short Asl[128 * 64];
  int tid = threadIdx.x, wave = tid >> 6, lane = tid & 63;
  int wr = wave >> 2, wc = wave & 3;        // 2x4 wave grid: WM=64, WN=32
  int r16 = lane & 15, kq = lane >> 4;
  int b = blockIdx.x;
  const short* baseh = Hh + (size_t)b * KOBJ * COMB_;
  const short* basel = Hl + (size_t)b * KOBJ * COMB_;
  f32x4 acc[4][2] = {};
  for (int k0 = 0; k0 < COMB_; k0 += 64) {
    __syncthreads();
    for (int c = wave; c < 32; c += 8) {
      int cc = c & 15;
      bool hi = c < 16;
      int Lb = cc * 1024 + lane * 16;
      int row = Lb >> 7;
      int off = (Lb & 127) ^ ((row & 7) << 4);
      const short* gsrc = (hi ? baseh : basel) + (size_t)row * COMB_ + k0 + (off >> 1);
      gload_lds16(gsrc, (char*)(hi ? Ash : Asl) + cc * 1024);
    }
    __syncthreads();
#pragma unroll
    for (int kk = 0; kk < 2; ++kk) {
      int woff = kk * 64 + kq * 16;
      s16x8 ah[4], al[4], bh[2], bl[2];
#pragma unroll
      for (int f = 0; f < 4; ++f) {
        int row = wr * 64 + f * 16 + r16;
        int o = woff ^ ((row & 7) << 4);
        ah[f] = *(const s16x8*)((const char*)Ash + row * 128 + o);
        al[f] = *(const s16x8*)((const char*)Asl + row * 128 + o);
      }
#pragma unroll
      for (int g = 0; g < 2; ++g) {
        int row = wc * 32 + g * 16 + r16;
        int o = woff ^ ((row & 7) << 4);
        bh[g] = *(const s16x8*)((const char*)Ash + row * 128 + o);
        bl[g] = *(const s16x8*)((const char*)Asl + row * 128 + o);
      }
#pragma unroll
      for (int f = 0; f < 4; ++f)
#pragma unroll
        for (int g = 0; g < 2; ++g) {
          acc[f][g] = __builtin_amdgcn_mfma_f32_16x16x32_bf16(ah[f], bh[g], acc[f][g], 0, 0, 0);
          acc[f][g] = __builtin_amdgcn_mfma_f32_16x16x32_bf16(ah[f], bl[g], acc[f][g], 0, 0, 0);
          acc[f][g] = __builtin_amdgcn_mfma_f32_16x16x32_bf16(al[f], bh[g], acc[f][g], 0, 0, 0);
        }
    }
  }
#pragma unroll
  for (int f = 0; f < 4; ++f)
#pragma unroll
    for (int g = 0; g < 2; ++g)
#pragma unroll
      for (int r = 0; r < 4; ++r) {
        int m = wr * 64 + f * 16 + (lane >> 4) * 4 + r;
        int n = wc * 32 + g * 16 + r16;
        if (m < KOBJ && n < KOBJ)
          adj[((size_t)b * KOBJ + m) * KOBJ + n] = acc[f][g][r];
      }
}

// ---------------- top-k + softmax + gaussian kernel weights ----------------
__global__ __launch_bounds__(256) void topk_weights_kernel(
    const float* __restrict__ adj, const float* __restrict__ cent,
    const float* __restrict__ mr1, const float* __restrict__ mt1,
    const float* __restrict__ pr1, const float* __restrict__ pt1,
    const float* __restrict__ mr2, const float* __restrict__ mt2,
    const float* __restrict__ pr2, const float* __restrict__ pt2,
    int* __restrict__ topi, float* __restrict__ c1, float* __restrict__ c2) {
  int row = blockIdx.x * 4 + (threadIdx.x >> 6);
  int lane = threadIdx.x & 63;
  int b = row / KOBJ, k = row % KOBJ;
  const float* ar = adj + (size_t)row * KOBJ;
  float v0 = (lane < KOBJ) ? ar[lane] : -INFINITY;
  float v1 = (lane + 64 < KOBJ) ? ar[lane + 64] : -INFINITY;
  int i0 = lane, i1 = lane + 64;
  float tv[NS_];
  int ti[NS_];
#pragma unroll
  for (int s = 0; s < NS_; ++s) {
    bool p0 = (v0 > v1) || (v0 == v1 && i0 < i1);
    float bv = p0 ? v0 : v1;
    int bi = p0 ? i0 : i1;
#pragma unroll
    for (int off = 32; off > 0; off >>= 1) {
      float ov = __shfl_xor(bv, off);
      int oi = __shfl_xor(bi, off);
      if (ov > bv || (ov == bv && oi < bi)) { bv = ov; bi = oi; }
    }
    tv[s] = bv; ti[s] = bi;
    if (bi == i0) v0 = -INFINITY;
    if (bi == i1) v1 = -INFINITY;
  }
  float mx = tv[0], sum = 0.f, av[NS_];
#pragma unroll
  for (int s = 0; s < NS_; ++s) { av[s] = expf(tv[s] - mx); sum += av[s]; }
  if (lane < NS_) {
    int j = ti[lane];
    topi[(size_t)row * NS_ + lane] = j;
    float cx = cent[(b * KOBJ + k) * 2 + 0], cy = cent[(b * KOBJ + k) * 2 + 1];
    float dx = cx - cent[(b * KOBJ + j) * 2 + 0];
    float dy = cy - cent[(b * KOBJ + j) * 2 + 1];
    float rho = sqrtf(dx * dx + dy * dy);
    float th = atan2f(dx, dy);
    float w1[NK_], w2[NK_], s1 = 0.f, s2 = 0.f;
#pragma unroll
    for (int m = 0; m < NK_; ++m) {
      {
        float pr = pr1[m], pt = pt1[m], dr = rho - mr1[m];
        float wr = expf(-0.5f * dr * dr / (1e-14f + pr * pr));
        float fa = fabsf(th - mt1[m]);
        float sa = fabsf(6.283185307179586f - fa);
        float da = fminf(fa, sa);
        float wt = expf(-0.5f * da * da / (1e-14f + pt * pt));
        float w = wr * wt;
        if (w != w) w = 0.f;
        w1[m] = w; s1 += w;
      }
      {
        float pr = pr2[m], pt = pt2[m], dr = rho - mr2[m];
        float wr = expf(-0.5f * dr * dr / (1e-14f + pr * pr));
        float fa = fabsf(th - mt2[m]);
        float sa = fabsf(6.283185307179586f - fa);
        float da = fminf(fa, sa);
        float wt = expf(-0.5f * da * da / (1e-14f + pt * pt));
        float w = wr * wt;
        if (w != w) w = 0.f;
        w2[m] = w; s2 += w;
      }
    }
    float as = av[lane] / sum;
#pragma unroll
    for (int m = 0; m < NK_; ++m) {
      c1[((size_t)row * NS_ + lane) * NK_ + m] = as * (w1[m] / s1);
      c2[((size_t)row * NS_ + lane) * NK_ + m] = w2[m] / s2;
    }
  }
}

// ---------------- gather-combine (bf16 proj in), VEC cols/thread, one block/row ----------
template <int VEC, bool BF16OUT>
__global__ __launch_bounds__(256) void combine_kernel(
    const short* __restrict__ proj, const float* __restrict__ coeff,
    const int* __restrict__ topi, float* __restrict__ outf, short* __restrict__ outb,
    int N, int mshift) {
  int row = xcd_remap(blockIdx.x, gridDim.x);
  int b = row / KOBJ;
  __shared__ int ids[NS_];
  __shared__ float cs[NS_ * NK_];
  int tid = threadIdx.x;
  if (tid < NS_) ids[tid] = topi[(size_t)row * NS_ + tid];
  else if (tid >= 32 && tid < 32 + NS_ * NK_) cs[tid - 32] = coeff[(size_t)row * NS_ * NK_ + (tid - 32)];
  __syncthreads();
  int n = tid * VEC;
  if (n >= N) return;
  int m = n >> mshift;
  float acc[VEC];
#pragma unroll
  for (int j = 0; j < VEC; ++j) acc[j] = 0.f;
#pragma unroll
  for (int s = 0; s < NS_; ++s) {
    float cc = cs[s * NK_ + m];
    const short* p = proj + ((size_t)b * KOBJ + ids[s]) * N + n;
    if (VEC == 8) {
      s16x8 v = *(const s16x8*)p;
#pragma unroll
      for (int j = 0; j < 8; ++j) acc[j] = fmaf(cc, bf2f(v[j]), acc[j]);
    } else {
      short4 v = *(const short4*)p;
      const short* vp = (const short*)&v;
#pragma unroll
      for (int j = 0; j < 4; ++j) acc[j] = fmaf(cc, bf2f(vp[j]), acc[j]);
    }
  }
#pragma unroll
  for (int j = 0; j < VEC; ++j) acc[j] = fmaxf(acc[j], 0.f);
  if (BF16OUT) {
    if (VEC == 8) {
      s16x8 o;
#pragma unroll
      for (int j = 0; j < 8; ++j) o[j] = f2bf(acc[j]);
      *(s16x8*)(outb + (size_t)row * N + n) = o;
    } else {
      short4 o;
      short* op = (short*)&o;
#pragma unroll
      for (int j = 0; j < 4; ++j) op[j] = f2bf(acc[j]);
      *(short4*)(outb + (size_t)row * N + n) = o;
    }
  } else {
    if (VEC == 4) {
      *(float4*)(outf + (size_t)row * N + n) = make_float4(acc[0], acc[1], acc[2], acc[3]);
    } else {
#pragma unroll
      for (int j = 0; j < VEC; ++j) outf[(size_t)row * N + n + j] = acc[j];
    }
  }
}

// ---------------- max over k, then hh = relu(qenc) * g2max (bf16 out) ----------------
__global__ void reduce_hh_kernel(const float* __restrict__ g2, const float* __restrict__ qenc,
                                 short* __restrict__ hhb) {
  int i = blockIdx.x * blockDim.x + threadIdx.x;
  if (i >= B_ * HID_) return;
  int b = i >> 10, n = i & (HID_ - 1);
  const float* p = g2 + (size_t)b * KOBJ * HID_ + n;
  float mx = -INFINITY;
  for (int k = 0; k < KOBJ; ++k) mx = fmaxf(mx, p[(size_t)k * HID_]);
  hhb[i] = f2bf(fmaxf(qenc[i], 0.f) * mx);
}

extern "C" void kernel_launch(void* const* d_in, const int* in_sizes, int n_in,
                              void* d_out, int out_size, void* d_ws, size_t ws_size,
                              hipStream_t stream) {
  const float* question = (const float*)d_in[0];
  const float* image    = (const float*)d_in[1];
  const float* W_lproj  = (const float*)d_in[3];
  const float* b_lproj  = (const float*)d_in[4];
  const float* W_e1     = (const float*)d_in[5];
  const float* b_e1     = (const float*)d_in[6];
  const float* W_e2     = (const float*)d_in[7];
  const float* b_e2     = (const float*)d_in[8];
  const float* conv_w1  = (const float*)d_in[9];
  const float* mr1 = (const float*)d_in[10];
  const float* mt1 = (const float*)d_in[11];
  const float* pr1 = (const float*)d_in[12];
  const float* pt1 = (const float*)d_in[13];
  const float* conv_w2  = (const float*)d_in[14];
  const float* mr2 = (const float*)d_in[15];
  const float* mt2 = (const float*)d_in[16];
  const float* pr2 = (const float*)d_in[17];
  const float* pt2 = (const float*)d_in[18];
  const float* W_o1 = (const float*)d_in[19];
  const float* b_o1 = (const float*)d_in[20];
  const float* W_o2 = (const float*)d_in[21];
  const float* b_o2 = (const float*)d_in[22];

  float* out = (float*)d_out;
  float* logits = out;               // [32,3000]
  float* adj = out + B_ * OUT_;      // [32,100,100]

  char* ws = (char*)d_ws;
  size_t off = 0;
  auto alloc = [&](size_t bytes) { char* p = ws + off; off += (bytes + 255) & ~((size_t)255); return p; };
  float* qenc  = (float*)alloc((size_t)B_ * HID_ * 4);
  short* qh    = (short*)alloc((size_t)B_ * EMB_ * 2);
  short* ql    = (short*)alloc((size_t)B_ * EMB_ * 2);
  short* qeh   = (short*)alloc((size_t)B_ * HID_ * 2);
  short* qel   = (short*)alloc((size_t)B_ * HID_ * 2);
  short* wlph  = (short*)alloc((size_t)EMB_ * HID_ * 2);
  short* wlpl  = (short*)alloc((size_t)EMB_ * HID_ * 2);
  short* we1ah = (short*)alloc((size_t)COMB_ * KP1 * 2);
  short* we1al = (short*)alloc((size_t)COMB_ * KP1 * 2);
  short* we1bh = (short*)alloc((size_t)COMB_ * HID_ * 2);
  short* we1bl = (short*)alloc((size_t)COMB_ * HID_ * 2);
  short* we2h  = (short*)alloc((size_t)COMB_ * COMB_ * 2);
  short* we2l  = (short*)alloc((size_t)COMB_ * COMB_ * 2);
  float* q1    = (float*)alloc((size_t)B_ * COMB_ * 4);
  short* h1h   = (short*)alloc((size_t)B_ * KOBJ * COMB_ * 2);
  short* h1l   = (short*)alloc((size_t)B_ * KOBJ * COMB_ * 2);
  short* h2h   = (short*)alloc((size_t)(B_ * KOBJ + 128) * COMB_ * 2);  // +pad rows for adj over-read
  short* h2l   = (short*)alloc((size_t)(B_ * KOBJ + 128) * COMB_ * 2);
  float* cent  = (float*)alloc((size_t)B_ * KOBJ * 2 * 4);
  int*   topi  = (int*)alloc((size_t)B_ * KOBJ * NS_ * 4);
  float* c1    = (float*)alloc((size_t)B_ * KOBJ * NS_ * NK_ * 4);
  float* c2    = (float*)alloc((size_t)B_ * KOBJ * NS_ * NK_ * 4);
  short* imgb  = (short*)alloc((size_t)B_ * KOBJ * KP1 * 2);
  short* imgl  = (short*)alloc((size_t)B_ * KOBJ * KP1 * 2);
  short* cw1t  = (short*)alloc((size_t)(2 * HID_) * KP1 * 2);
  short* cw2t  = (short*)alloc((size_t)HID_ * KP2 * 2);
  short* proj1b = (short*)alloc((size_t)B_ * KOBJ * 2 * HID_ * 2);
  short* g1b   = (short*)alloc((size_t)B_ * KOBJ * KP2 * 2);
  short* proj2b = (short*)alloc((size_t)B_ * KOBJ * HID_ * 2);
  float* g2    = (float*)alloc((size_t)B_ * KOBJ * HID_ * 4);
  short* hhb   = (short*)alloc((size_t)B_ * HID_ * 2);
  short* wo1t  = (short*)alloc((size_t)NO_P * HID_ * 2);
  short* wo2t  = (short*)alloc((size_t)NO_P * KO2 * 2);
  short* h1ob  = (short*)alloc((size_t)B_ * KO2 * 2);
  float* partE = (float*)alloc((size_t)2 * B_ * KOBJ * 2 * HID_ * 4);  // 52.4 MB (proj1 z=2 largest)
  (void)ws_size; (void)in_sizes; (void)n_in; (void)out_size;

  dim3 blk(256), blk512(512);

  // ---- fused input prep (image cvt + question cvt + centres) ----
  prep_inputs<<<dim3(IMG_BLKS + Q_BLKS + C_BLKS), blk, 0, stream>>>(
      image, question, imgb, imgl, qh, ql, cent);

  // ---- all weight transposes in ONE dispatch ----
  {
    TDs ds;
    int cum = 0;
    auto set = [&](int i, const float* in, short* oh, short* ol, int K, int N, int Kp,
                   int OPM, int nnt, int split, int conv) {
      int nkt = Kp / 64;
      cum += nkt * nnt;
      ds.d[i] = TD{in, oh, ol, K, N, Kp, OPM, nkt, split, conv, cum};
    };
    set(0, W_lproj, wlph, wlpl, EMB_, HID_, EMB_, 0, HID_ / 64, 1, 0);
    set(1, W_e1, we1ah, we1al, FEAT_, COMB_, KP1, 0, COMB_ / 64, 1, 0);
    set(2, W_e1 + (size_t)FEAT_ * COMB_, we1bh, we1bl, HID_, COMB_, HID_, 0, COMB_ / 64, 1, 0);
    set(3, W_e2, we2h, we2l, COMB_, COMB_, COMB_, 0, COMB_ / 64, 1, 0);
    set(4, conv_w1, cw1t, nullptr, FEAT_, 2 * HID_, KP1, 2 * HID_ / NK_, 2 * HID_ / 64, 0, 1);
    set(5, conv_w2, cw2t, nullptr, 2 * HID_, HID_, KP2, HID_ / NK_, HID_ / 64, 0, 1);
    set(6, W_o1, wo1t, nullptr, HID_, OUT_, HID_, 0, NO_P / 64, 0, 0);
    set(7, W_o2, wo2t, nullptr, OUT_, OUT_, KO2, 0, NO_P / 64, 0, 0);
    transpose_all<<<dim3(cum), blk, 0, stream>>>(ds);
  }

  // ---- qenc = question @ W_lproj + b (split, f32) ----
  gemm_mx<32, 64, 2, 2, true, false, true, 0, false><<<dim3(HID_ / 64, 1, 1), blk, 0, stream>>>(
      qh, ql, wlph, wlpl, b_lproj, qenc, nullptr, nullptr, nullptr, 0, B_, HID_, EMB_, HID_, HID_);
  // ---- split qenc for q1 ----
  {
    int total = B_ * (HID_ / 8);
    cvt_pad_rows_split<<<dim3((total + 255) / 256), blk, 0, stream>>>(qenc, qeh, qel, HID_, HID_, total);
  }
  // ---- q1 = qenc @ We1[2052:] (split, no bias) ----
  gemm_mx<32, 64, 2, 2, true, false, false, 0, false><<<dim3(COMB_ / 64, 1, 1), blk, 0, stream>>>(
      qeh, qel, we1bh, we1bl, nullptr, q1, nullptr, nullptr, nullptr, 0, B_, COMB_, HID_, COMB_, COMB_);
  // ---- e1 image part: split-K partials (z=4, KS=576) ----
  gemm_mx<128, 64, 4, 2, true, false, false, 0, true><<<dim3(COMB_ / 64, B_ * KOBJ / 128, 4), blk512, 0, stream>>>(
      imgb, imgl, we1ah, we1al, nullptr, nullptr, nullptr, nullptr, partE, 576,
      B_ * KOBJ, COMB_, KP1, COMB_, COMB_);
  // ---- h1 = relu(sum + q1[bcast] + b_e1), bf16 hi/lo ----
  reduce_split<1, true, true, true><<<dim3(B_ * KOBJ * COMB_ / 4 / 256), blk, 0, stream>>>(
      partE, 4, (size_t)B_ * KOBJ * COMB_, b_e1, q1, COMB_, nullptr, h1h, h1l,
      B_ * KOBJ, COMB_, COMB_, COMB_);
  // ---- e2: split-K partials (z=4, KS=128) ----
  gemm_mx<128, 64, 4, 2, true, false, false, 0, true><<<dim3(COMB_ / 64, B_ * KOBJ / 128, 4), blk512, 0, stream>>>(
      h1h, h1l, we2h, we2l, nullptr, nullptr, nullptr, nullptr, partE, 128,
      B_ * KOBJ, COMB_, COMB_, COMB_, COMB_);
  // ---- h2 = relu(sum + b_e2) as bf16 hi/lo (feeds adj MFMA) ----
  reduce_split<1, true, true, false><<<dim3(B_ * KOBJ * COMB_ / 4 / 256), blk, 0, stream>>>(
      partE, 4, (size_t)B_ * KOBJ * COMB_, b_e2, nullptr, 0, nullptr, h2h, h2l,
      B_ * KOBJ, COMB_, COMB_, COMB_);
  // ---- adj (split-bf16 MFMA, Gram) + topk ----
  adj_mfma<<<dim3(B_), blk512, 0, stream>>>(h2h, h2l, adj);
  topk_weights_kernel<<<dim3(B_ * KOBJ / 4), blk, 0, stream>>>(
      adj, cent, mr1, mt1, pr1, pt1, mr2, mt2, pr2, pt2, topi, c1, c2);
  // ---- conv path ----
  // proj1: 128x128 tile (full intensity) + split-K z=2 -> 800 blocks
  gemm_mx<128, 128, 2, 4, false, false, false, 0, true><<<dim3(2 * HID_ / 128, B_ * KOBJ / 128, 2), blk512, 0, stream>>>(
      imgb, nullptr, cw1t, nullptr, nullptr, nullptr, nullptr, nullptr, partE, 1056,
      B_ * KOBJ, 2 * HID_, KP1, 2 * HID_, 2 * HID_);
  reduce_split<2, false, false, false><<<dim3(B_ * KOBJ * 2 * HID_ / 4 / 256), blk, 0, stream>>>(
      partE, 2, (size_t)B_ * KOBJ * 2 * HID_, nullptr, nullptr, 0, nullptr, proj1b, nullptr,
      B_ * KOBJ, 2 * HID_, 2 * HID_, 2 * HID_);
  combine_kernel<8, true><<<dim3(B_ * KOBJ), blk, 0, stream>>>(
      proj1b, c1, topi, nullptr, g1b, 2 * HID_, 8);
  // proj2: 64x64 tile -> 800 blocks
  gemm_mx<64, 64, 2, 2, false, false, false, 2, false><<<dim3(HID_ / 64, B_ * KOBJ / 64, 1), blk, 0, stream>>>(
      g1b, nullptr, cw2t, nullptr, nullptr, nullptr, proj2b, nullptr, nullptr, 0,
      B_ * KOBJ, HID_, KP2, HID_, HID_);
  combine_kernel<4, false><<<dim3(B_ * KOBJ), blk, 0, stream>>>(
      proj2b, c2, topi, g2, nullptr, HID_, 7);
  // ---- tail ----
  reduce_hh_kernel<<<dim3((B_ * HID_ + 255) / 256), blk, 0, stream>>>(g2, qenc, hhb);
  // o1: split-K z=16, KS=64
  gemm_mx<32, 128, 1, 4, false, false, false, 0, true><<<dim3(NO_P / 128, 1, 16), blk, 0, stream>>>(
      hhb, nullptr, wo1t, nullptr, nullptr, nullptr, nullptr, nullptr, partE, 64,
      B_, OUT_, HID_, KO2, KO2);
  reduce_split<2, true, true, false><<<dim3((B_ * KO2 / 4 + 255) / 256), blk, 0, stream>>>(
      partE, 16, (size_t)B_ * KO2, b_o1, nullptr, 0, nullptr, h1ob, nullptr,
      B_, OUT_, KO2, KO2);
  // o2: split-K z=16, KS=192
  gemm_mx<32, 128, 1, 4, false, false, false, 0, true><<<dim3(NO_P / 128, 1, 16), blk, 0, stream>>>(
      h1ob, nullptr, wo2t, nullptr, nullptr, nullptr, nullptr, nullptr, partE, 192,
      B_, OUT_, KO2, KO2, KO2);
  reduce_split<0, false, true, false><<<dim3((B_ * KO2 / 4 + 255) / 256), blk, 0, stream>>>(
      partE, 16, (size_t)B_ * KO2, b_o2, nullptr, 0, logits, nullptr, nullptr,
      B_, OUT_, KO2, OUT_);
}

// Round 9
// 345.141 us; speedup vs baseline: 4.3361x; 1.0333x over previous
//
#include <hip/hip_runtime.h>
#include <math.h>
#include <stdint.h>

#define B_    32
#define KOBJ  100
#define NS_   16
#define NK_   8
#define EMB_  1024
#define FEAT_ 2052
#define HID_  1024
#define OUT_  3000
#define COMB_ 512

#define KP1   2112   // FEAT_ padded to 64 (image rows / We1a rows)
#define KP2   2048   // 2*HID_
#define NO_P  3072   // OUT_ padded to 128 (N of o1/o2)
#define KO2   3008   // OUT_ padded to 64 (K of o2)

typedef __attribute__((ext_vector_type(8))) short s16x8;
typedef __attribute__((ext_vector_type(4))) float f32x4;

__device__ inline short f2bf(float f) {
  uint32_t u = __builtin_bit_cast(uint32_t, f);
  u = (u + 0x7fff + ((u >> 16) & 1)) >> 16;  // RNE
  return (short)u;
}
__device__ inline float bf2f(short s) {
  uint32_t u = ((uint32_t)(uint16_t)s) << 16;
  return __builtin_bit_cast(float, u);
}
__device__ inline void gload_lds16(const void* g, void* l) {
  __builtin_amdgcn_global_load_lds(
      (const __attribute__((address_space(1))) void*)g,
      (__attribute__((address_space(3))) void*)l, 16, 0, 0);
}
// XCD-aware bijective remap (m204): consecutive wg cluster on one XCD
__device__ inline int xcd_remap(int fid, int nwg) {
  int q = nwg >> 3, r = nwg & 7;
  int x = fid & 7, l = fid >> 3;
  return (x < r ? x * (q + 1) : r * (q + 1) + (x - r) * q) + l;
}

// ---------------- fused input prep: image cvt(split) + question cvt(split) + centres ----
#define IMG_CHUNKS (B_ * KOBJ * (KP1 / 8))
#define IMG_BLKS   ((IMG_CHUNKS + 255) / 256)
#define Q_CHUNKS   (B_ * (EMB_ / 8))
#define Q_BLKS     ((Q_CHUNKS + 255) / 256)
#define C_BLKS     ((B_ * KOBJ + 255) / 256)

__device__ inline void cvt8_split(const float* __restrict__ in, short* __restrict__ oh,
                                  short* __restrict__ ol, int K, int Kp, int idx) {
  int row = idx / (Kp / 8), c8 = (idx % (Kp / 8)) * 8;
  float f[8];
  if (c8 + 8 <= K) {
    const float* src = in + (size_t)row * K + c8;
    float4 a = *(const float4*)src;
    float4 b = *(const float4*)(src + 4);
    f[0] = a.x; f[1] = a.y; f[2] = a.z; f[3] = a.w;
    f[4] = b.x; f[5] = b.y; f[6] = b.z; f[7] = b.w;
  } else {
#pragma unroll
    for (int i = 0; i < 8; ++i) {
      int k = c8 + i;
      f[i] = (k < K) ? in[(size_t)row * K + k] : 0.f;
    }
  }
  s16x8 vh, vl;
#pragma unroll
  for (int i = 0; i < 8; ++i) {
    short h = f2bf(f[i]);
    vh[i] = h;
    vl[i] = f2bf(f[i] - bf2f(h));
  }
  *(s16x8*)(oh + (size_t)row * Kp + c8) = vh;
  *(s16x8*)(ol + (size_t)row * Kp + c8) = vl;
}

__global__ __launch_bounds__(256) void prep_inputs(
    const float* __restrict__ image, const float* __restrict__ question,
    short* __restrict__ imgb, short* __restrict__ imgl,
    short* __restrict__ qh, short* __restrict__ ql, float* __restrict__ cent) {
  int bb = blockIdx.x, tid = threadIdx.x;
  if (bb < IMG_BLKS) {
    int idx = bb * 256 + tid;
    if (idx < IMG_CHUNKS) cvt8_split(image, imgb, imgl, FEAT_, KP1, idx);
  } else if (bb < IMG_BLKS + Q_BLKS) {
    int idx = (bb - IMG_BLKS) * 256 + tid;
    if (idx < Q_CHUNKS) cvt8_split(question, qh, ql, EMB_, EMB_, idx);
  } else {
    int i = (bb - IMG_BLKS - Q_BLKS) * 256 + tid;
    if (i < B_ * KOBJ) {
      const float* bbx = image + (size_t)i * FEAT_ + (FEAT_ - 4);
      cent[i * 2 + 0] = 0.5f * (bbx[0] + bbx[2]);
      cent[i * 2 + 1] = 0.5f * (bbx[1] + bbx[3]);
    }
  }
}

// ---------------- one-dispatch transpose of all weights ----------------
struct TD {
  const float* in; short* oh; short* ol;
  int K, N, Kp, OPM, nkt, split, conv, cum;  // cum = exclusive prefix end of tiles
};
struct TDs { TD d[8]; };

__global__ __launch_bounds__(256) void transpose_all(TDs ds) {
  __shared__ float s[64][65];
  int bid = blockIdx.x;
  int i = 0;
  while (i < 7 && bid >= ds.d[i].cum) ++i;
  const TD& d = ds.d[i];
  int local = bid - (i ? ds.d[i - 1].cum : 0);
  int k0 = (local % d.nkt) * 64, n0 = (local / d.nkt) * 64;
  int t = threadIdx.x;
  int rr = t >> 4, c4 = (t & 15) * 4;
  bool fullN = d.conv || (n0 + 64 <= d.N);
#pragma unroll
  for (int p = 0; p < 4; ++p) {
    int row = p * 16 + rr;
    int kg = k0 + row;
    float v0 = 0.f, v1 = 0.f, v2 = 0.f, v3 = 0.f;
    if (kg < d.K) {
      const float* src = d.conv
          ? d.in + ((size_t)(n0 / d.OPM) * d.K + kg) * d.OPM + (n0 % d.OPM) + c4
          : d.in + (size_t)kg * d.N + n0 + c4;
      if (fullN) {
        float4 v = *(const float4*)src;
        v0 = v.x; v1 = v.y; v2 = v.z; v3 = v.w;
      } else {
        int nb = n0 + c4;
        if (nb + 0 < d.N) v0 = src[0];
        if (nb + 1 < d.N) v1 = src[1];
        if (nb + 2 < d.N) v2 = src[2];
        if (nb + 3 < d.N) v3 = src[3];
      }
    }
    s[row][c4 + 0] = v0; s[row][c4 + 1] = v1;
    s[row][c4 + 2] = v2; s[row][c4 + 3] = v3;
  }
  __syncthreads();
  int nl = t >> 2, kc = (t & 3) << 4;
#pragma unroll
  for (int half = 0; half < 2; ++half) {
    s16x8 vh, vl;
#pragma unroll
    for (int j = 0; j < 8; ++j) {
      float f = s[kc + half * 8 + j][nl];
      short h = f2bf(f);
      vh[j] = h;
      vl[j] = f2bf(f - bf2f(h));
    }
    size_t o = (size_t)(n0 + nl) * d.Kp + k0 + kc + half * 8;
    *(s16x8*)(d.oh + o) = vh;
    if (d.split) *(s16x8*)(d.ol + o) = vl;
  }
}

// ---------------- unified MFMA GEMM ----------------
// OMODE: 0=f32, 1=bf16 hi/lo pair, 2=bf16, 3=f32 AND bf16 hi/lo pair.
// SPLITK: z-chunks -> partials (f32 in part, or bf16 in partb when PB16).
template <int BM, int BN, int WR, int WC, bool SPLIT, bool RELU, bool BIAS, int OMODE,
          bool SPLITK, bool PB16>
__global__ __launch_bounds__(WR * WC * 64) void gemm_mx(
    const short* __restrict__ Ah, const short* __restrict__ Al,
    const short* __restrict__ Bh, const short* __restrict__ Bl,
    const float* __restrict__ bias,
    float* __restrict__ Cf, short* __restrict__ Ch, short* __restrict__ Cl,
    float* __restrict__ part, short* __restrict__ partb, int KS,
    int M, int N, int Kp, int ldc, int Nw) {
  constexpr int NWV = WR * WC;
  constexpr int WM = BM / WR, WN = BN / WC;
  constexpr int FM = WM / 16, FN = WN / 16;
  constexpr int ACH = BM / 8, BCH = BN / 8;
  constexpr int NCH = (ACH + BCH) * (SPLIT ? 2 : 1);
  __shared__ short Ash[BM * 64];
  __shared__ short Bsh[BN * 64];
  __shared__ short Asl[SPLIT ? BM * 64 : 64];
  __shared__ short Bsl[SPLIT ? BN * 64 : 64];
  int tid = threadIdx.x, wave = tid >> 6, lane = tid & 63;
  int wr = wave / WC, wc = wave % WC;
  int r16 = lane & 15, kq = lane >> 4;
  int gx = gridDim.x, gy = gridDim.y, gz = gridDim.z;
  int fid = (blockIdx.z * gy + blockIdx.y) * gx + blockIdx.x;
  int wg = xcd_remap(fid, gx * gy * gz);
  int bx = wg % gx, byz = wg / gx;
  int by = byz % gy, bz = byz / gy;
  int m0 = by * BM, n0 = bx * BN;
  int kb = SPLITK ? bz * KS : 0;
  int ke = SPLITK ? (kb + KS < Kp ? kb + KS : Kp) : Kp;
  f32x4 acc[FM][FN] = {};

  for (int k0 = kb; k0 < ke; k0 += 64) {
    __syncthreads();
    for (int c = wave; c < NCH; c += NWV) {
      int cc = c;
      const short* g;
      char* l;
      bool isA;
      if (cc < ACH) { isA = true; g = Ah; l = (char*)Ash; }
      else if (SPLIT && cc < 2 * ACH) { cc -= ACH; isA = true; g = Al; l = (char*)Asl; }
      else {
        cc -= SPLIT ? 2 * ACH : ACH;
        if (cc < BCH) { isA = false; g = Bh; l = (char*)Bsh; }
        else { cc -= BCH; isA = false; g = Bl; l = (char*)Bsl; }
      }
      int Lb = cc * 1024 + lane * 16;
      int row = Lb >> 7;
      int off = (Lb & 127) ^ ((row & 7) << 4);
      const short* gsrc = g + (size_t)((isA ? m0 : n0) + row) * Kp + k0 + (off >> 1);
      gload_lds16(gsrc, l + cc * 1024);
    }
    __syncthreads();  // compiler drains vmcnt before barrier
#pragma unroll
    for (int kk = 0; kk < 2; ++kk) {
      int woff = kk * 64 + kq * 16;
      s16x8 ah[FM], al[FM], bh[FN], bl[FN];
#pragma unroll
      for (int f = 0; f < FM; ++f) {
        int row = wr * WM + f * 16 + r16;
        int o = woff ^ ((row & 7) << 4);
        ah[f] = *(const s16x8*)((const char*)Ash + row * 128 + o);
        if (SPLIT) al[f] = *(const s16x8*)((const char*)Asl + row * 128 + o);
      }
#pragma unroll
      for (int gg = 0; gg < FN; ++gg) {
        int row = wc * WN + gg * 16 + r16;
        int o = woff ^ ((row & 7) << 4);
        bh[gg] = *(const s16x8*)((const char*)Bsh + row * 128 + o);
        if (SPLIT) bl[gg] = *(const s16x8*)((const char*)Bsl + row * 128 + o);
      }
#pragma unroll
      for (int f = 0; f < FM; ++f)
#pragma unroll
        for (int gg = 0; gg < FN; ++gg) {
          acc[f][gg] = __builtin_amdgcn_mfma_f32_16x16x32_bf16(ah[f], bh[gg], acc[f][gg], 0, 0, 0);
          if (SPLIT) {
            acc[f][gg] = __builtin_amdgcn_mfma_f32_16x16x32_bf16(ah[f], bl[gg], acc[f][gg], 0, 0, 0);
            acc[f][gg] = __builtin_amdgcn_mfma_f32_16x16x32_bf16(al[f], bh[gg], acc[f][gg], 0, 0, 0);
          }
        }
    }
  }
#pragma unroll
  for (int f = 0; f < FM; ++f)
#pragma unroll
    for (int gg = 0; gg < FN; ++gg)
#pragma unroll
      for (int r = 0; r < 4; ++r) {
        int m = m0 + wr * WM + f * 16 + (lane >> 4) * 4 + r;
        int n = n0 + wc * WN + gg * 16 + r16;
        if (m >= M || n >= Nw) continue;
        float v = (n < N) ? acc[f][gg][r] : 0.f;
        size_t idx = (size_t)m * ldc + n;
        if (SPLITK) {
          size_t pidx = (size_t)bz * M * ldc + idx;
          if (PB16) partb[pidx] = f2bf(v);
          else      part[pidx] = v;
        } else {
          if (BIAS && n < N) v += bias[n];
          if (RELU) v = fmaxf(v, 0.f);
          if (OMODE == 0) Cf[idx] = v;
          else if (OMODE == 1) {
            short h = f2bf(v);
            Ch[idx] = h;
            Cl[idx] = f2bf(v - bf2f(h));
          } else if (OMODE == 2) {
            Ch[idx] = f2bf(v);
          } else {  // OMODE 3: f32 + bf16 hi/lo
            Cf[idx] = v;
            short h = f2bf(v);
            Ch[idx] = h;
            Cl[idx] = f2bf(v - bf2f(h));
          }
        }
      }
}

// ---------------- split-K reduce (float4/short4-vectorized) ----------------
template <int OMODE, bool RELU, bool BIAS, bool BCAST, bool PB16>
__global__ void reduce_split(const float* __restrict__ part, const short* __restrict__ partb,
                             int SK, size_t pstride,
                             const float* __restrict__ bias, const float* __restrict__ bcast,
                             int bcols, float* __restrict__ Cf, short* __restrict__ Ch,
                             short* __restrict__ Cl, int M, int N, int ldIn, int ldOut) {
  int idx4 = blockIdx.x * 256 + threadIdx.x;
  int ld4 = ldIn >> 2;
  if (idx4 >= M * ld4) return;
  int m = idx4 / ld4;
  int n = (idx4 - m * ld4) << 2;
  size_t base = (size_t)m * ldIn + n;
  float a[4] = {0.f, 0.f, 0.f, 0.f};
  for (int s = 0; s < SK; ++s) {
    if (PB16) {
      short4 p = *(const short4*)(partb + (size_t)s * pstride + base);
      const short* pp = (const short*)&p;
#pragma unroll
      for (int j = 0; j < 4; ++j) a[j] += bf2f(pp[j]);
    } else {
      float4 p = *(const float4*)(part + (size_t)s * pstride + base);
      a[0] += p.x; a[1] += p.y; a[2] += p.z; a[3] += p.w;
    }
  }
#pragma unroll
  for (int j = 0; j < 4; ++j) {
    int nn = n + j;
    if (nn < N) {
      if (BCAST) a[j] += bcast[(size_t)(m / KOBJ) * bcols + nn];
      if (BIAS) a[j] += bias[nn];
    }
    if (RELU) a[j] = fmaxf(a[j], 0.f);
  }
  if (n >= ldOut) return;
  size_t o = (size_t)m * ldOut + n;
  if (OMODE == 0) {
    *(float4*)(Cf + o) = make_float4(a[0], a[1], a[2], a[3]);
  } else if (OMODE == 1) {
    short4 hh, ll;
    short* hp = (short*)&hh; short* lp = (short*)&ll;
#pragma unroll
    for (int j = 0; j < 4; ++j) {
      short h = f2bf(a[j]);
      hp[j] = h;
      lp[j] = f2bf(a[j] - bf2f(h));
    }
    *(short4*)(Ch + o) = hh;
    *(short4*)(Cl + o) = ll;
  } else {
    short4 hh;
    short* hp = (short*)&hh;
#pragma unroll
    for (int j = 0; j < 4; ++j) hp[j] = f2bf(a[j]);
    *(short4*)(Ch + o) = hh;
  }
}

// ---------------- adj[b] = h2[b] @ h2[b]^T, split-bf16 MFMA, one block/batch ----------------
__global__ __launch_bounds__(512) void adj_mfma(const short* __restrict__ Hh,
                                                const short* __restrict__ Hl,
                                                float* __restrict__ adj) {
  __shared__ short Ash[128 * 64];
  __shared__ short Asl[128 * 64];
  int tid = threadIdx.x, wave = tid >> 6, lane = tid & 63;
  int wr = wave >> 2, wc = wave & 3;        // 2x4 wave grid: WM=64, WN=32
  int r16 = lane & 15, kq = lane >> 4;
  int b = blockIdx.x;
  const short* baseh = Hh + (size_t)b * KOBJ * COMB_;
  const short* basel = Hl + (size_t)b * KOBJ * COMB_;
  f32x4 acc[4][2] = {};
  for (int k0 = 0; k0 < COMB_; k0 += 64) {
    __syncthreads();
    for (int c = wave; c < 32; c += 8) {
      int cc = c & 15;
      bool hi = c < 16;
      int Lb = cc * 1024 + lane * 16;
      int row = Lb >> 7;
      int off = (Lb & 127) ^ ((row & 7) << 4);
      const short* gsrc = (hi ? baseh : basel) + (size_t)row * COMB_ + k0 + (off >> 1);
      gload_lds16(gsrc, (char*)(hi ? Ash : Asl) + cc * 1024);
    }
    __syncthreads();
#pragma unroll
    for (int kk = 0; kk < 2; ++kk) {
      int woff = kk * 64 + kq * 16;
      s16x8 ah[4], al[4], bh[2], bl[2];
#pragma unroll
      for (int f = 0; f < 4; ++f) {
        int row = wr * 64 + f * 16 + r16;
        int o = woff ^ ((row & 7) << 4);
        ah[f] = *(const s16x8*)((const char*)Ash + row * 128 + o);
        al[f] = *(const s16x8*)((const char*)Asl + row * 128 + o);
      }
#pragma unroll
      for (int g = 0; g < 2; ++g) {
        int row = wc * 32 + g * 16 + r16;
        int o = woff ^ ((row & 7) << 4);
        bh[g] = *(const s16x8*)((const char*)Ash + row * 128 + o);
        bl[g] = *(const s16x8*)((const char*)Asl + row * 128 + o);
      }
#pragma unroll
      for (int f = 0; f < 4; ++f)
#pragma unroll
        for (int g = 0; g < 2; ++g) {
          acc[f][g] = __builtin_amdgcn_mfma_f32_16x16x32_bf16(ah[f], bh[g], acc[f][g], 0, 0, 0);
          acc[f][g] = __builtin_amdgcn_mfma_f32_16x16x32_bf16(ah[f], bl[g], acc[f][g], 0, 0, 0);
          acc[f][g] = __builtin_amdgcn_mfma_f32_16x16x32_bf16(al[f], bh[g], acc[f][g], 0, 0, 0);
        }
    }
  }
#pragma unroll
  for (int f = 0; f < 4; ++f)
#pragma unroll
    for (int g = 0; g < 2; ++g)
#pragma unroll
      for (int r = 0; r < 4; ++r) {
        int m = wr * 64 + f * 16 + (lane >> 4) * 4 + r;
        int n = wc * 32 + g * 16 + r16;
        if (m < KOBJ && n < KOBJ)
          adj[((size_t)b * KOBJ + m) * KOBJ + n] = acc[f][g][r];
      }
}

// ---------------- top-k + softmax + gaussian kernel weights ----------------
__global__ __launch_bounds__(256) void topk_weights_kernel(
    const float* __restrict__ adj, const float* __restrict__ cent,
    const float* __restrict__ mr1, const float* __restrict__ mt1,
    const float* __restrict__ pr1, const float* __restrict__ pt1,
    const float* __restrict__ mr2, const float* __restrict__ mt2,
    const float* __restrict__ pr2, const float* __restrict__ pt2,
    int* __restrict__ topi, float* __restrict__ c1, float* __restrict__ c2) {
  int row = blockIdx.x * 4 + (threadIdx.x >> 6);
  int lane = threadIdx.x & 63;
  int b = row / KOBJ, k = row % KOBJ;
  const float* ar = adj + (size_t)row * KOBJ;
  float v0 = (lane < KOBJ) ? ar[lane] : -INFINITY;
  float v1 = (lane + 64 < KOBJ) ? ar[lane + 64] : -INFINITY;
  int i0 = lane, i1 = lane + 64;
  float tv[NS_];
  int ti[NS_];
#pragma unroll
  for (int s = 0; s < NS_; ++s) {
    bool p0 = (v0 > v1) || (v0 == v1 && i0 < i1);
    float bv = p0 ? v0 : v1;
    int bi = p0 ? i0 : i1;
#pragma unroll
    for (int off = 32; off > 0; off >>= 1) {
      float ov = __shfl_xor(bv, off);
      int oi = __shfl_xor(bi, off);
      if (ov > bv || (ov == bv && oi < bi)) { bv = ov; bi = oi; }
    }
    tv[s] = bv; ti[s] = bi;
    if (bi == i0) v0 = -INFINITY;
    if (bi == i1) v1 = -INFINITY;
  }
  float mx = tv[0], sum = 0.f, av[NS_];
#pragma unroll
  for (int s = 0; s < NS_; ++s) { av[s] = expf(tv[s] - mx); sum += av[s]; }
  if (lane < NS_) {
    int j = ti[lane];
    topi[(size_t)row * NS_ + lane] = j;
    float cx = cent[(b * KOBJ + k) * 2 + 0], cy = cent[(b * KOBJ + k) * 2 + 1];
    float dx = cx - cent[(b * KOBJ + j) * 2 + 0];
    float dy = cy - cent[(b * KOBJ + j) * 2 + 1];
    float rho = sqrtf(dx * dx + dy * dy);
    float th = atan2f(dx, dy);
    float w1[NK_], w2[NK_], s1 = 0.f, s2 = 0.f;
#pragma unroll
    for (int m = 0; m < NK_; ++m) {
      {
        float pr = pr1[m], pt = pt1[m], dr = rho - mr1[m];
        float wr = expf(-0.5f * dr * dr / (1e-14f + pr * pr));
        float fa = fabsf(th - mt1[m]);
        float sa = fabsf(6.283185307179586f - fa);
        float da = fminf(fa, sa);
        float wt = expf(-0.5f * da * da / (1e-14f + pt * pt));
        float w = wr * wt;
        if (w != w) w = 0.f;
        w1[m] = w; s1 += w;
      }
      {
        float pr = pr2[m], pt = pt2[m], dr = rho - mr2[m];
        float wr = expf(-0.5f * dr * dr / (1e-14f + pr * pr));
        float fa = fabsf(th - mt2[m]);
        float sa = fabsf(6.283185307179586f - fa);
        float da = fminf(fa, sa);
        float wt = expf(-0.5f * da * da / (1e-14f + pt * pt));
        float w = wr * wt;
        if (w != w) w = 0.f;
        w2[m] = w; s2 += w;
      }
    }
    float as = av[lane] / sum;
#pragma unroll
    for (int m = 0; m < NK_; ++m) {
      c1[((size_t)row * NS_ + lane) * NK_ + m] = as * (w1[m] / s1);
      c2[((size_t)row * NS_ + lane) * NK_ + m] = w2[m] / s2;
    }
  }
}

// ---------------- gather-combine (bf16 proj in), VEC cols/thread, one block/row ----------
template <int VEC, bool BF16OUT>
__global__ __launch_bounds__(256) void combine_kernel(
    const short* __restrict__ proj, const float* __restrict__ coeff,
    const int* __restrict__ topi, float* __restrict__ outf, short* __restrict__ outb,
    int N, int mshift) {
  int row = xcd_remap(blockIdx.x, gridDim.x);
  int b = row / KOBJ;
  __shared__ int ids[NS_];
  __shared__ float cs[NS_ * NK_];
  int tid = threadIdx.x;
  if (tid < NS_) ids[tid] = topi[(size_t)row * NS_ + tid];
  else if (tid >= 32 && tid < 32 + NS_ * NK_) cs[tid - 32] = coeff[(size_t)row * NS_ * NK_ + (tid - 32)];
  __syncthreads();
  int n = tid * VEC;
  if (n >= N) return;
  int m = n >> mshift;
  float acc[VEC];
#pragma unroll
  for (int j = 0; j < VEC; ++j) acc[j] = 0.f;
#pragma unroll
  for (int s = 0; s < NS_; ++s) {
    float cc = cs[s * NK_ + m];
    const short* p = proj + ((size_t)b * KOBJ + ids[s]) * N + n;
    if (VEC == 8) {
      s16x8 v = *(const s16x8*)p;
#pragma unroll
      for (int j = 0; j < 8; ++j) acc[j] = fmaf(cc, bf2f(v[j]), acc[j]);
    } else {
      short4 v = *(const short4*)p;
      const short* vp = (const short*)&v;
#pragma unroll
      for (int j = 0; j < 4; ++j) acc[j] = fmaf(cc, bf2f(vp[j]), acc[j]);
    }
  }
#pragma unroll
  for (int j = 0; j < VEC; ++j) acc[j] = fmaxf(acc[j], 0.f);
  if (BF16OUT) {
    if (VEC == 8) {
      s16x8 o;
#pragma unroll
      for (int j = 0; j < 8; ++j) o[j] = f2bf(acc[j]);
      *(s16x8*)(outb + (size_t)row * N + n) = o;
    } else {
      short4 o;
      short* op = (short*)&o;
#pragma unroll
      for (int j = 0; j < 4; ++j) op[j] = f2bf(acc[j]);
      *(short4*)(outb + (size_t)row * N + n) = o;
    }
  } else {
    if (VEC == 4) {
      *(float4*)(outf + (size_t)row * N + n) = make_float4(acc[0], acc[1], acc[2], acc[3]);
    } else {
#pragma unroll
      for (int j = 0; j < VEC; ++j) outf[(size_t)row * N + n + j] = acc[j];
    }
  }
}

// ---------------- max over k, then hh = relu(qenc) * g2max (bf16 out) ----------------
__global__ void reduce_hh_kernel(const float* __restrict__ g2, const float* __restrict__ qenc,
                                 short* __restrict__ hhb) {
  int i = blockIdx.x * blockDim.x + threadIdx.x;
  if (i >= B_ * HID_) return;
  int b = i >> 10, n = i & (HID_ - 1);
  const float* p = g2 + (size_t)b * KOBJ * HID_ + n;
  float mx = -INFINITY;
  for (int k = 0; k < KOBJ; ++k) mx = fmaxf(mx, p[(size_t)k * HID_]);
  hhb[i] = f2bf(fmaxf(qenc[i], 0.f) * mx);
}

extern "C" void kernel_launch(void* const* d_in, const int* in_sizes, int n_in,
                              void* d_out, int out_size, void* d_ws, size_t ws_size,
                              hipStream_t stream) {
  const float* question = (const float*)d_in[0];
  const float* image    = (const float*)d_in[1];
  const float* W_lproj  = (const float*)d_in[3];
  const float* b_lproj  = (const float*)d_in[4];
  const float* W_e1     = (const float*)d_in[5];
  const float* b_e1     = (const float*)d_in[6];
  const float* W_e2     = (const float*)d_in[7];
  const float* b_e2     = (const float*)d_in[8];
  const float* conv_w1  = (const float*)d_in[9];
  const float* mr1 = (const float*)d_in[10];
  const float* mt1 = (const float*)d_in[11];
  const float* pr1 = (const float*)d_in[12];
  const float* pt1 = (const float*)d_in[13];
  const float* conv_w2  = (const float*)d_in[14];
  const float* mr2 = (const float*)d_in[15];
  const float* mt2 = (const float*)d_in[16];
  const float* pr2 = (const float*)d_in[17];
  const float* pt2 = (const float*)d_in[18];
  const float* W_o1 = (const float*)d_in[19];
  const float* b_o1 = (const float*)d_in[20];
  const float* W_o2 = (const float*)d_in[21];
  const float* b_o2 = (const float*)d_in[22];

  float* out = (float*)d_out;
  float* logits = out;               // [32,3000]
  float* adj = out + B_ * OUT_;      // [32,100,100]

  char* ws = (char*)d_ws;
  size_t off = 0;
  auto alloc = [&](size_t bytes) { char* p = ws + off; off += (bytes + 255) & ~((size_t)255); return p; };
  float* qenc  = (float*)alloc((size_t)B_ * HID_ * 4);
  short* qh    = (short*)alloc((size_t)B_ * EMB_ * 2);
  short* ql    = (short*)alloc((size_t)B_ * EMB_ * 2);
  short* qeh   = (short*)alloc((size_t)B_ * HID_ * 2);
  short* qel   = (short*)alloc((size_t)B_ * HID_ * 2);
  short* wlph  = (short*)alloc((size_t)EMB_ * HID_ * 2);
  short* wlpl  = (short*)alloc((size_t)EMB_ * HID_ * 2);
  short* we1ah = (short*)alloc((size_t)COMB_ * KP1 * 2);
  short* we1al = (short*)alloc((size_t)COMB_ * KP1 * 2);
  short* we1bh = (short*)alloc((size_t)COMB_ * HID_ * 2);
  short* we1bl = (short*)alloc((size_t)COMB_ * HID_ * 2);
  short* we2h  = (short*)alloc((size_t)COMB_ * COMB_ * 2);
  short* we2l  = (short*)alloc((size_t)COMB_ * COMB_ * 2);
  float* q1    = (float*)alloc((size_t)B_ * COMB_ * 4);
  short* h1h   = (short*)alloc((size_t)B_ * KOBJ * COMB_ * 2);
  short* h1l   = (short*)alloc((size_t)B_ * KOBJ * COMB_ * 2);
  short* h2h   = (short*)alloc((size_t)(B_ * KOBJ + 128) * COMB_ * 2);  // +pad rows for adj over-read
  short* h2l   = (short*)alloc((size_t)(B_ * KOBJ + 128) * COMB_ * 2);
  float* cent  = (float*)alloc((size_t)B_ * KOBJ * 2 * 4);
  int*   topi  = (int*)alloc((size_t)B_ * KOBJ * NS_ * 4);
  float* c1    = (float*)alloc((size_t)B_ * KOBJ * NS_ * NK_ * 4);
  float* c2    = (float*)alloc((size_t)B_ * KOBJ * NS_ * NK_ * 4);
  short* imgb  = (short*)alloc((size_t)B_ * KOBJ * KP1 * 2);
  short* imgl  = (short*)alloc((size_t)B_ * KOBJ * KP1 * 2);
  short* cw1t  = (short*)alloc((size_t)(2 * HID_) * KP1 * 2);
  short* cw2t  = (short*)alloc((size_t)HID_ * KP2 * 2);
  short* proj1b = (short*)alloc((size_t)B_ * KOBJ * 2 * HID_ * 2);
  short* g1b   = (short*)alloc((size_t)B_ * KOBJ * KP2 * 2);
  short* proj2b = (short*)alloc((size_t)B_ * KOBJ * HID_ * 2);
  float* g2    = (float*)alloc((size_t)B_ * KOBJ * HID_ * 4);
  short* hhb   = (short*)alloc((size_t)B_ * HID_ * 2);
  short* wo1t  = (short*)alloc((size_t)NO_P * HID_ * 2);
  short* wo2t  = (short*)alloc((size_t)NO_P * KO2 * 2);
  short* h1ob  = (short*)alloc((size_t)B_ * KO2 * 2);
  // partials: f32 users max = e1 (4 x 3200x512x4 = 26.2 MB); bf16 users = proj1/proj2 (26.2 MB)
  float* partE = (float*)alloc((size_t)4 * B_ * KOBJ * COMB_ * 4);
  short* partS = (short*)partE;
  (void)ws_size; (void)in_sizes; (void)n_in; (void)out_size;

  dim3 blk(256), blk512(512);

  // ---- fused input prep (image cvt + question cvt + centres) ----
  prep_inputs<<<dim3(IMG_BLKS + Q_BLKS + C_BLKS), blk, 0, stream>>>(
      image, question, imgb, imgl, qh, ql, cent);

  // ---- all weight transposes in ONE dispatch ----
  {
    TDs ds;
    int cum = 0;
    auto set = [&](int i, const float* in, short* oh, short* ol, int K, int N, int Kp,
                   int OPM, int nnt, int split, int conv) {
      int nkt = Kp / 64;
      cum += nkt * nnt;
      ds.d[i] = TD{in, oh, ol, K, N, Kp, OPM, nkt, split, conv, cum};
    };
    set(0, W_lproj, wlph, wlpl, EMB_, HID_, EMB_, 0, HID_ / 64, 1, 0);
    set(1, W_e1, we1ah, we1al, FEAT_, COMB_, KP1, 0, COMB_ / 64, 1, 0);
    set(2, W_e1 + (size_t)FEAT_ * COMB_, we1bh, we1bl, HID_, COMB_, HID_, 0, COMB_ / 64, 1, 0);
    set(3, W_e2, we2h, we2l, COMB_, COMB_, COMB_, 0, COMB_ / 64, 1, 0);
    set(4, conv_w1, cw1t, nullptr, FEAT_, 2 * HID_, KP1, 2 * HID_ / NK_, 2 * HID_ / 64, 0, 1);
    set(5, conv_w2, cw2t, nullptr, 2 * HID_, HID_, KP2, HID_ / NK_, HID_ / 64, 0, 1);
    set(6, W_o1, wo1t, nullptr, HID_, OUT_, HID_, 0, NO_P / 64, 0, 0);
    set(7, W_o2, wo2t, nullptr, OUT_, OUT_, KO2, 0, NO_P / 64, 0, 0);
    transpose_all<<<dim3(cum), blk, 0, stream>>>(ds);
  }

  // ---- qenc = question @ W_lproj + b (split; OMODE 3: f32 + bf16 hi/lo fused) ----
  gemm_mx<32, 64, 2, 2, true, false, true, 3, false, false><<<dim3(HID_ / 64, 1, 1), blk, 0, stream>>>(
      qh, ql, wlph, wlpl, b_lproj, qenc, qeh, qel, nullptr, nullptr, 0, B_, HID_, EMB_, HID_, HID_);
  // ---- q1 = qenc @ We1[2052:] (split, no bias) ----
  gemm_mx<32, 64, 2, 2, true, false, false, 0, false, false><<<dim3(COMB_ / 64, 1, 1), blk, 0, stream>>>(
      qeh, qel, we1bh, we1bl, nullptr, q1, nullptr, nullptr, nullptr, nullptr, 0, B_, COMB_, HID_, COMB_, COMB_);
  // ---- e1 image part: split-K partials f32 (z=4, KS=576) ----
  gemm_mx<128, 64, 4, 2, true, false, false, 0, true, false><<<dim3(COMB_ / 64, B_ * KOBJ / 128, 4), blk512, 0, stream>>>(
      imgb, imgl, we1ah, we1al, nullptr, nullptr, nullptr, nullptr, partE, nullptr, 576,
      B_ * KOBJ, COMB_, KP1, COMB_, COMB_);
  // ---- h1 = relu(sum + q1[bcast] + b_e1), bf16 hi/lo ----
  reduce_split<1, true, true, true, false><<<dim3(B_ * KOBJ * COMB_ / 4 / 256), blk, 0, stream>>>(
      partE, nullptr, 4, (size_t)B_ * KOBJ * COMB_, b_e1, q1, COMB_, nullptr, h1h, h1l,
      B_ * KOBJ, COMB_, COMB_, COMB_);
  // ---- e2: split-K partials f32 (z=4, KS=128) ----
  gemm_mx<128, 64, 4, 2, true, false, false, 0, true, false><<<dim3(COMB_ / 64, B_ * KOBJ / 128, 4), blk512, 0, stream>>>(
      h1h, h1l, we2h, we2l, nullptr, nullptr, nullptr, nullptr, partE, nullptr, 128,
      B_ * KOBJ, COMB_, COMB_, COMB_, COMB_);
  // ---- h2 = relu(sum + b_e2) as bf16 hi/lo (feeds adj MFMA) ----
  reduce_split<1, true, true, false, false><<<dim3(B_ * KOBJ * COMB_ / 4 / 256), blk, 0, stream>>>(
      partE, nullptr, 4, (size_t)B_ * KOBJ * COMB_, b_e2, nullptr, 0, nullptr, h2h, h2l,
      B_ * KOBJ, COMB_, COMB_, COMB_);
  // ---- adj (split-bf16 MFMA, Gram) + topk ----
  adj_mfma<<<dim3(B_), blk512, 0, stream>>>(h2h, h2l, adj);
  topk_weights_kernel<<<dim3(B_ * KOBJ / 4), blk, 0, stream>>>(
      adj, cent, mr1, mt1, pr1, pt1, mr2, mt2, pr2, pt2, topi, c1, c2);
  // ---- conv path ----
  // proj1: 128x128 full-intensity tile + split-K z=2 with BF16 partials -> 800 blocks
  gemm_mx<128, 128, 2, 4, false, false, false, 0, true, true><<<dim3(2 * HID_ / 128, B_ * KOBJ / 128, 2), blk512, 0, stream>>>(
      imgb, nullptr, cw1t, nullptr, nullptr, nullptr, nullptr, nullptr, nullptr, partS, 1056,
      B_ * KOBJ, 2 * HID_, KP1, 2 * HID_, 2 * HID_);
  reduce_split<2, false, false, false, true><<<dim3(B_ * KOBJ * 2 * HID_ / 4 / 256), blk, 0, stream>>>(
      nullptr, partS, 2, (size_t)B_ * KOBJ * 2 * HID_, nullptr, nullptr, 0, nullptr, proj1b, nullptr,
      B_ * KOBJ, 2 * HID_, 2 * HID_, 2 * HID_);
  combine_kernel<8, true><<<dim3(B_ * KOBJ), blk, 0, stream>>>(
      proj1b, c1, topi, nullptr, g1b, 2 * HID_, 8);
  // proj2: 128x128 tile + split-K z=4 with BF16 partials -> 800 blocks
  gemm_mx<128, 128, 2, 4, false, false, false, 0, true, true><<<dim3(HID_ / 128, B_ * KOBJ / 128, 4), blk512, 0, stream>>>(
      g1b, nullptr, cw2t, nullptr, nullptr, nullptr, nullptr, nullptr, nullptr, partS, 512,
      B_ * KOBJ, HID_, KP2, HID_, HID_);
  reduce_split<2, false, false, false, true><<<dim3(B_ * KOBJ * HID_ / 4 / 256), blk, 0, stream>>>(
      nullptr, partS, 4, (size_t)B_ * KOBJ * HID_, nullptr, nullptr, 0, nullptr, proj2b, nullptr,
      B_ * KOBJ, HID_, HID_, HID_);
  combine_kernel<4, false><<<dim3(B_ * KOBJ), blk, 0, stream>>>(
      proj2b, c2, topi, g2, nullptr, HID_, 7);
  // ---- tail ----
  reduce_hh_kernel<<<dim3((B_ * HID_ + 255) / 256), blk, 0, stream>>>(g2, qenc, hhb);
  // o1: split-K z=16, KS=64 (f32 partials, small)
  gemm_mx<32, 128, 1, 4, false, false, false, 0, true, false><<<dim3(NO_P / 128, 1, 16), blk, 0, stream>>>(
      hhb, nullptr, wo1t, nullptr, nullptr, nullptr, nullptr, nullptr, partE, nullptr, 64,
      B_, OUT_, HID_, KO2, KO2);
  reduce_split<2, true, true, false, false><<<dim3((B_ * KO2 / 4 + 255) / 256), blk, 0, stream>>>(
      partE, nullptr, 16, (size_t)B_ * KO2, b_o1, nullptr, 0, nullptr, h1ob, nullptr,
      B_, OUT_, KO2, KO2);
  // o2: split-K z=16, KS=192
  gemm_mx<32, 128, 1, 4, false, false, false, 0, true, false><<<dim3(NO_P / 128, 1, 16), blk, 0, stream>>>(
      h1ob, nullptr, wo2t, nullptr, nullptr, nullptr, nullptr, nullptr, partE, nullptr, 192,
      B_, OUT_, KO2, KO2, KO2);
  reduce_split<0, false, true, false, false><<<dim3((B_ * KO2 / 4 + 255) / 256), blk, 0, stream>>>(
      partE, nullptr, 16, (size_t)B_ * KO2, b_o2, nullptr, 0, logits, nullptr, nullptr,
      B_, OUT_, KO2, OUT_);
}